// Round 2
// baseline (9138.597 us; speedup 1.0000x reference)
//
#include <hip/hip_runtime.h>
#include <hip/hip_bf16.h>

typedef unsigned short ushort_t;
typedef unsigned int uint_t;

#define DD   128
#define G4   512
#define BT   16
#define GP   516   // padded gates row (floats)
#define NB   128   // B windows
#define NV   32    // N variables

__device__ __forceinline__ float bf2f(ushort_t u) {
    union { uint_t i; float f; } x; x.i = ((uint_t)u) << 16; return x.f;
}
__device__ __forceinline__ float bflo(uint_t u) {
    union { uint_t i; float f; } x; x.i = u << 16; return x.f;
}
__device__ __forceinline__ float bfhi(uint_t u) {
    union { uint_t i; float f; } x; x.i = u & 0xffff0000u; return x.f;
}
__device__ __forceinline__ ushort_t f2bf(float f) {
    __hip_bfloat16 h = __float2bfloat16(f);
    return *(ushort_t*)&h;
}
__device__ __forceinline__ float sigmoid_f(float x) {
    return 1.f / (1.f + __expf(-x));
}
__device__ __forceinline__ float tanh_f(float x) {
    float e = __expf(2.f * x);
    return 1.f - 2.f / (e + 1.f);
}
__device__ __forceinline__ void store_out(void* out, long idx, float v, int bf) {
    if (bf) ((ushort_t*)out)[idx] = f2bf(v);
    else    ((float*)out)[idx]    = v;
}

// ---------------- dtype probe: flags[i]=1 if input i looks like bf16 ----------------
struct Ptr19 { const void* p[19]; int e[19]; };

__global__ __launch_bounds__(64) void probe_kernel(Ptr19 a, int* __restrict__ flags) {
    int t = threadIdx.x;
    for (int i = 0; i < 19; i++) {
        int cap = a.e[i] < 2048 ? a.e[i] : 2048;
        int cnt = 0, tot = 0;
        const ushort_t* p = (const ushort_t*)a.p[i];
        for (int j = t; j < cap; j += 64) {
            ushort_t u = p[j];
            float af = fabsf(bf2f(u));
            tot++;
            if (u == 0 || (af > 1e-7f && af < 100.f)) cnt++;
        }
        #pragma unroll
        for (int off = 32; off >= 1; off >>= 1) {
            cnt += __shfl_xor(cnt, off);
            tot += __shfl_xor(tot, off);
        }
        if (t == 0) flags[i] = (cnt * 10 >= tot * 9) ? 1 : 0;
    }
}

// ---------------- canonicalizers ----------------
__global__ __launch_bounds__(256) void conv_f32(const void* __restrict__ src,
                                                const int* __restrict__ flags, int fi,
                                                float* __restrict__ dst, int E) {
    int i = blockIdx.x * 256 + threadIdx.x;
    if (i >= E) return;
    int bf = flags[fi];
    dst[i] = bf ? bf2f(((const ushort_t*)src)[i]) : ((const float*)src)[i];
}
__global__ __launch_bounds__(256) void conv_bf16(const void* __restrict__ src,
                                                 const int* __restrict__ flags, int fi,
                                                 ushort_t* __restrict__ dst, int E) {
    int i = blockIdx.x * 256 + threadIdx.x;
    if (i >= E) return;
    int bf = flags[fi];
    dst[i] = bf ? ((const ushort_t*)src)[i] : f2bf(((const float*)src)[i]);
}

// ---------------- transpose (N,512,128) -> (N,128,512), any src dtype -> bf16 ----------------
__global__ __launch_bounds__(256) void transpose_whh(const void* __restrict__ W,
                                                     const int* __restrict__ flags, int fi,
                                                     ushort_t* __restrict__ WT) {
    __shared__ ushort_t t[32][33];
    int bf = flags[fi];
    int n  = blockIdx.y;
    int tg = blockIdx.x & 15;
    int td = blockIdx.x >> 4;
    int c  = threadIdx.x & 31, r8 = threadIdx.x >> 5;
    #pragma unroll
    for (int k = 0; k < 4; k++) {
        int gl = r8 + k * 8;
        int idx = n * G4 * DD + (tg * 32 + gl) * DD + td * 32 + c;
        ushort_t v = bf ? ((const ushort_t*)W)[idx] : f2bf(((const float*)W)[idx]);
        t[gl][c] = v;
    }
    __syncthreads();
    ushort_t* dst = WT + n * DD * G4;
    #pragma unroll
    for (int k = 0; k < 4; k++) {
        int dl = r8 + k * 8;
        dst[(td * 32 + dl) * G4 + tg * 32 + c] = t[c][dl];
    }
}

// ---------------- encoder recurrence + online softmax pool ----------------
__global__ __launch_bounds__(256) void enc_kernel(
    const void* __restrict__ Xraw, const int* __restrict__ flags,
    const float* __restrict__ Wih, const float* __restrict__ bvec,
    const float* __restrict__ pw, const float* __restrict__ pb,
    const ushort_t* __restrict__ WT, float* __restrict__ Cout)
{
    const int n    = blockIdx.y;
    const int b0   = blockIdx.x * BT;
    const int tid  = threadIdx.x;
    const int lane = tid & 63;
    const int wave = tid >> 6;
    const int xbf  = flags[0];
    const ushort_t* Xu = (const ushort_t*)Xraw;
    const float*    Xf = (const float*)Xraw;

    __shared__ float hT[DD][BT];
    __shared__ float gates[BT][GP];

    for (int i = tid; i < DD * BT; i += 256) ((float*)hT)[i] = 0.f;

    float wih_r[8], b_r[8];
    #pragma unroll
    for (int j = 0; j < 4; j++)
        #pragma unroll
        for (int p = 0; p < 2; p++) {
            int g = 128 * j + 2 * lane + p;
            wih_r[j * 2 + p] = Wih[n * G4 + g];
            b_r[j * 2 + p]   = bvec[n * G4 + g];
        }

    const int bb_c = tid >> 4;
    const int d0_c = (tid & 15) * 8;
    float c_r[8], Cacc[8], pw_r[8];
    #pragma unroll
    for (int jj = 0; jj < 8; jj++) {
        c_r[jj] = 0.f; Cacc[jj] = 0.f;
        pw_r[jj] = pw[n * DD + d0_c + jj];
    }
    float m_r = 0.f, l_r = 0.f;
    const float pb_r = pb[n];

    const ushort_t* WTn = WT + n * DD * G4;

    float xq[4];
    #pragma unroll
    for (int i = 0; i < 4; i++) {
        int idx = (b0 + 4 * wave + i) * 4096 + n;
        xq[i] = xbf ? bf2f(Xu[idx]) : Xf[idx];
    }

    __syncthreads();

    for (int t = 0; t < 127; t++) {
        float xn[4];
        #pragma unroll
        for (int i = 0; i < 4; i++) {
            int idx = (b0 + 4 * wave + i) * 4096 + (t + 1) * 32 + n;  // t+1<=127 in-bounds
            xn[i] = xbf ? bf2f(Xu[idx]) : Xf[idx];
        }

        float acc[4][8];
        #pragma unroll
        for (int i = 0; i < 4; i++)
            #pragma unroll
            for (int e = 0; e < 8; e++)
                acc[i][e] = xq[i] * wih_r[e] + b_r[e];

        #pragma unroll 8
        for (int d = 0; d < DD; d++) {
            const float4 hv = *(const float4*)&hT[d][4 * wave];
            const uint_t* wrow = (const uint_t*)WTn + d * 256;
            #pragma unroll
            for (int j = 0; j < 4; j++) {
                uint_t u = wrow[64 * j + lane];
                float w0 = bflo(u), w1 = bfhi(u);
                acc[0][2*j]   += hv.x * w0; acc[0][2*j+1] += hv.x * w1;
                acc[1][2*j]   += hv.y * w0; acc[1][2*j+1] += hv.y * w1;
                acc[2][2*j]   += hv.z * w0; acc[2][2*j+1] += hv.z * w1;
                acc[3][2*j]   += hv.w * w0; acc[3][2*j+1] += hv.w * w1;
            }
        }

        #pragma unroll
        for (int i = 0; i < 4; i++) {
            float* grow = &gates[4 * wave + i][0];
            #pragma unroll
            for (int j = 0; j < 4; j++)
                *(float2*)&grow[128 * j + 2 * lane] =
                    make_float2(acc[i][2 * j], acc[i][2 * j + 1]);
        }
        __syncthreads();

        float gi[8], gf[8], gg[8], go[8];
        *(float4*)&gi[0] = *(float4*)&gates[bb_c][d0_c + 0];
        *(float4*)&gi[4] = *(float4*)&gates[bb_c][d0_c + 4];
        *(float4*)&gf[0] = *(float4*)&gates[bb_c][DD + d0_c + 0];
        *(float4*)&gf[4] = *(float4*)&gates[bb_c][DD + d0_c + 4];
        *(float4*)&gg[0] = *(float4*)&gates[bb_c][2 * DD + d0_c + 0];
        *(float4*)&gg[4] = *(float4*)&gates[bb_c][2 * DD + d0_c + 4];
        *(float4*)&go[0] = *(float4*)&gates[bb_c][3 * DD + d0_c + 0];
        *(float4*)&go[4] = *(float4*)&gates[bb_c][3 * DD + d0_c + 4];

        float hnew[8];
        float sp = 0.f;
        #pragma unroll
        for (int jj = 0; jj < 8; jj++) {
            float ii = sigmoid_f(gi[jj]);
            float ff = sigmoid_f(gf[jj]);
            float g2 = tanh_f(gg[jj]);
            float oo = sigmoid_f(go[jj]);
            float cc = ff * c_r[jj] + ii * g2;
            c_r[jj] = cc;
            float hh = oo * tanh_f(cc);
            hnew[jj] = hh;
            hT[d0_c + jj][bb_c] = hh;
            sp += hh * pw_r[jj];
        }
        #pragma unroll
        for (int off = 8; off >= 1; off >>= 1)
            sp += __shfl_xor(sp, off);
        float s = sp + pb_r;

        if (t == 0) {
            m_r = s; l_r = 1.f;
            #pragma unroll
            for (int jj = 0; jj < 8; jj++) Cacc[jj] = hnew[jj];
        } else {
            float mnew  = fmaxf(m_r, s);
            float scale = __expf(m_r - mnew);
            float e     = __expf(s - mnew);
            l_r = l_r * scale + e;
            #pragma unroll
            for (int jj = 0; jj < 8; jj++)
                Cacc[jj] = Cacc[jj] * scale + e * hnew[jj];
            m_r = mnew;
        }

        #pragma unroll
        for (int i = 0; i < 4; i++) xq[i] = xn[i];
        __syncthreads();
    }

    float inv = 1.f / l_r;
    #pragma unroll
    for (int jj = 0; jj < 8; jj++)
        Cout[(b0 + bb_c) * (NV * DD) + n * DD + d0_c + jj] = Cacc[jj] * inv;
}

// ---------------- QKV projection ----------------
__global__ __launch_bounds__(128) void qkv_kernel(
    const float* __restrict__ C, const float* __restrict__ inw,
    const float* __restrict__ inb,
    float* __restrict__ q, float* __restrict__ k, float* __restrict__ v)
{
    int b = blockIdx.x, p = blockIdx.y, j = threadIdx.x;
    __shared__ float Cb[NV * DD];
    for (int i = j; i < NV * DD; i += 128) Cb[i] = C[b * (NV * DD) + i];
    __syncthreads();

    const float* wrow = inw + (p * DD + j) * DD;
    float bias = inb[p * DD + j];
    float acc[NV];
    #pragma unroll
    for (int nn = 0; nn < NV; nn++) acc[nn] = bias;

    for (int dc = 0; dc < DD; dc += 8) {
        float4 w0 = *(const float4*)&wrow[dc];
        float4 w1 = *(const float4*)&wrow[dc + 4];
        #pragma unroll
        for (int nn = 0; nn < NV; nn++) {
            float4 c0 = *(float4*)&Cb[nn * DD + dc];
            float4 c1 = *(float4*)&Cb[nn * DD + dc + 4];
            acc[nn] += c0.x * w0.x + c0.y * w0.y + c0.z * w0.z + c0.w * w0.w
                     + c1.x * w1.x + c1.y * w1.y + c1.z * w1.z + c1.w * w1.w;
        }
    }
    float* dst = (p == 0) ? q : (p == 1) ? k : v;
    for (int nn = 0; nn < NV; nn++) dst[b * (NV * DD) + nn * DD + j] = acc[nn];
}

// ---------------- cross-attention over lags + out-proj + residual ----------------
__global__ __launch_bounds__(256) void attn_kernel(
    const float* __restrict__ q, const float* __restrict__ k, const float* __restrict__ v,
    const float* __restrict__ C, const float* __restrict__ outw,
    const float* __restrict__ outb, const int* __restrict__ flags,
    float* __restrict__ Cstar, void* __restrict__ dout)
{
    int b = blockIdx.x, tid = threadIdx.x;
    int obf = flags[0];
    __shared__ float Qs[NV * DD], Ks[NV * DD], Vs[NV * DD];
    float* Os = Ks;  // reused after last Ks read (sync-separated)
    for (int i = tid; i < NV * DD; i += 256) Qs[i] = q[b * (NV * DD) + i];
    __syncthreads();

    int hh = tid >> 5, qi = tid & 31;
    float qreg[16];
    #pragma unroll
    for (int u = 0; u < 4; u++) {
        float4 t4 = *(float4*)&Qs[qi * DD + hh * 16 + 4 * u];
        qreg[4*u] = t4.x; qreg[4*u+1] = t4.y; qreg[4*u+2] = t4.z; qreg[4*u+3] = t4.w;
    }

    float Oacc[16];
    #pragma unroll
    for (int u = 0; u < 16; u++) Oacc[u] = 0.f;
    float wsum = 0.f;
    int tmax = (b < 5) ? b : 5;

    for (int tau = 1; tau <= tmax; tau++) {
        __syncthreads();
        for (int i = tid; i < NV * DD; i += 256) {
            Ks[i] = k[(b - tau) * (NV * DD) + i];
            Vs[i] = v[(b - tau) * (NV * DD) + i];
        }
        __syncthreads();

        float s[NV];
        #pragma unroll
        for (int kk = 0; kk < NV; kk++) {
            float a = 0.f;
            #pragma unroll
            for (int u = 0; u < 4; u++) {
                float4 kv = *(float4*)&Ks[kk * DD + hh * 16 + 4 * u];
                a += qreg[4*u] * kv.x + qreg[4*u+1] * kv.y
                   + qreg[4*u+2] * kv.z + qreg[4*u+3] * kv.w;
            }
            s[kk] = a * 0.25f;   // 1/sqrt(16)
        }
        float mm = s[0];
        #pragma unroll
        for (int kk = 1; kk < NV; kk++) mm = fmaxf(mm, s[kk]);
        float ssum = 0.f;
        #pragma unroll
        for (int kk = 0; kk < NV; kk++) { s[kk] = __expf(s[kk] - mm); ssum += s[kk]; }
        float w  = __expf(-0.7f * (float)(tau - 1));
        wsum += w;
        float wr = w / ssum;
        #pragma unroll
        for (int u = 0; u < 4; u++) {
            float ax = 0.f, ay = 0.f, az = 0.f, aw = 0.f;
            #pragma unroll
            for (int kk = 0; kk < NV; kk++) {
                float4 vv = *(float4*)&Vs[kk * DD + hh * 16 + 4 * u];
                ax += s[kk] * vv.x; ay += s[kk] * vv.y;
                az += s[kk] * vv.z; aw += s[kk] * vv.w;
            }
            Oacc[4*u] += wr * ax; Oacc[4*u+1] += wr * ay;
            Oacc[4*u+2] += wr * az; Oacc[4*u+3] += wr * aw;
        }
    }

    __syncthreads();
    float winv = (b > 0) ? 1.f / wsum : 0.f;
    #pragma unroll
    for (int u = 0; u < 16; u++)
        Os[qi * DD + hh * 16 + u] = Oacc[u] * winv;
    __syncthreads();

    int j = tid & 127, ng = tid >> 7;
    const float* wrow = outw + j * DD;
    float obias = outb[j];
    for (int nn = ng * 16; nn < ng * 16 + 16; nn++) {
        float a = (b > 0) ? obias : 0.f;
        for (int dc = 0; dc < DD; dc += 8) {
            float4 w0 = *(const float4*)&wrow[dc];
            float4 w1 = *(const float4*)&wrow[dc + 4];
            float4 o0 = *(float4*)&Os[nn * DD + dc];
            float4 o1 = *(float4*)&Os[nn * DD + dc + 4];
            a += o0.x*w0.x + o0.y*w0.y + o0.z*w0.z + o0.w*w0.w
               + o1.x*w1.x + o1.y*w1.y + o1.z*w1.z + o1.w*w1.w;
        }
        float cs = C[b * (NV * DD) + nn * DD + j] + a;
        Cstar[b * (NV * DD) + nn * DD + j] = cs;
        store_out(dout, 524288 + b * (NV * DD) + nn * DD + j, cs, obf);
    }
}

// ---------------- decoder init ----------------
__global__ __launch_bounds__(256) void dec_init(
    const float* __restrict__ Cstar,
    const ushort_t* __restrict__ iHw, const float* __restrict__ iHb,
    const ushort_t* __restrict__ iCw, const float* __restrict__ iCb,
    float* __restrict__ h0, float* __restrict__ c0)
{
    int b = blockIdx.x, n = blockIdx.y, tid = threadIdx.x;
    __shared__ float cs[DD];
    if (tid < DD) cs[tid] = Cstar[b * (NV * DD) + n * DD + tid];
    __syncthreads();
    int e = tid & 127, mat = tid >> 7;
    const uint_t* wrow = (const uint_t*)((mat ? iCw : iHw) + (n * DD + e) * DD);
    float acc = (mat ? iCb : iHb)[n * DD + e];
    for (int dc = 0; dc < DD; dc += 8) {
        float wf[8];
        #pragma unroll
        for (int u = 0; u < 4; u++) {
            uint_t x = wrow[dc / 2 + u];
            wf[2*u] = bflo(x); wf[2*u+1] = bfhi(x);
        }
        float4 c0v = *(float4*)&cs[dc];
        float4 c1v = *(float4*)&cs[dc + 4];
        acc += c0v.x*wf[0] + c0v.y*wf[1] + c0v.z*wf[2] + c0v.w*wf[3]
             + c1v.x*wf[4] + c1v.y*wf[5] + c1v.z*wf[6] + c1v.w*wf[7];
    }
    float r = tanh_f(acc);
    (mat ? c0 : h0)[(n * NB + b) * DD + e] = r;
}

// ---------------- decoder recurrence -> recon/pred ----------------
__global__ __launch_bounds__(256) void dec_kernel(
    const float* __restrict__ h0, const float* __restrict__ c0,
    const float* __restrict__ bih, const float* __restrict__ bhh,
    const float* __restrict__ ow, const float* __restrict__ ob,
    const ushort_t* __restrict__ WT, const int* __restrict__ flags,
    void* __restrict__ out)
{
    const int n    = blockIdx.y;
    const int b0   = blockIdx.x * BT;
    const int tid  = threadIdx.x;
    const int lane = tid & 63;
    const int wave = tid >> 6;
    const int obf  = flags[0];

    __shared__ float hT[DD][BT];
    __shared__ float gates[BT][GP];

    float b_r[8];
    #pragma unroll
    for (int j = 0; j < 4; j++)
        #pragma unroll
        for (int p = 0; p < 2; p++) {
            int g = 128 * j + 2 * lane + p;
            b_r[j * 2 + p] = bih[n * G4 + g] + bhh[n * G4 + g];
        }

    const int bb_c = tid >> 4;
    const int d0_c = (tid & 15) * 8;
    float c_r[8], ow_r[8];
    #pragma unroll
    for (int jj = 0; jj < 8; jj++) {
        int d = d0_c + jj;
        hT[d][bb_c] = h0[(n * NB + b0 + bb_c) * DD + d];
        c_r[jj]     = c0[(n * NB + b0 + bb_c) * DD + d];
        ow_r[jj]    = ow[n * DD + d];
    }
    const float ob_r = ob[n];
    const ushort_t* WTn = WT + n * DD * G4;

    __syncthreads();

    for (int t = 0; t < 128; t++) {
        float acc[4][8];
        #pragma unroll
        for (int i = 0; i < 4; i++)
            #pragma unroll
            for (int e = 0; e < 8; e++)
                acc[i][e] = b_r[e];

        #pragma unroll 8
        for (int d = 0; d < DD; d++) {
            const float4 hv = *(const float4*)&hT[d][4 * wave];
            const uint_t* wrow = (const uint_t*)WTn + d * 256;
            #pragma unroll
            for (int j = 0; j < 4; j++) {
                uint_t u = wrow[64 * j + lane];
                float w0 = bflo(u), w1 = bfhi(u);
                acc[0][2*j]   += hv.x * w0; acc[0][2*j+1] += hv.x * w1;
                acc[1][2*j]   += hv.y * w0; acc[1][2*j+1] += hv.y * w1;
                acc[2][2*j]   += hv.z * w0; acc[2][2*j+1] += hv.z * w1;
                acc[3][2*j]   += hv.w * w0; acc[3][2*j+1] += hv.w * w1;
            }
        }

        #pragma unroll
        for (int i = 0; i < 4; i++) {
            float* grow = &gates[4 * wave + i][0];
            #pragma unroll
            for (int j = 0; j < 4; j++)
                *(float2*)&grow[128 * j + 2 * lane] =
                    make_float2(acc[i][2 * j], acc[i][2 * j + 1]);
        }
        __syncthreads();

        float gi[8], gf[8], gg[8], go[8];
        *(float4*)&gi[0] = *(float4*)&gates[bb_c][d0_c + 0];
        *(float4*)&gi[4] = *(float4*)&gates[bb_c][d0_c + 4];
        *(float4*)&gf[0] = *(float4*)&gates[bb_c][DD + d0_c + 0];
        *(float4*)&gf[4] = *(float4*)&gates[bb_c][DD + d0_c + 4];
        *(float4*)&gg[0] = *(float4*)&gates[bb_c][2 * DD + d0_c + 0];
        *(float4*)&gg[4] = *(float4*)&gates[bb_c][2 * DD + d0_c + 4];
        *(float4*)&go[0] = *(float4*)&gates[bb_c][3 * DD + d0_c + 0];
        *(float4*)&go[4] = *(float4*)&gates[bb_c][3 * DD + d0_c + 4];

        float sp = 0.f;
        #pragma unroll
        for (int jj = 0; jj < 8; jj++) {
            float ii = sigmoid_f(gi[jj]);
            float ff = sigmoid_f(gf[jj]);
            float g2 = tanh_f(gg[jj]);
            float oo = sigmoid_f(go[jj]);
            float cc = ff * c_r[jj] + ii * g2;
            c_r[jj] = cc;
            float hh = oo * tanh_f(cc);
            hT[d0_c + jj][bb_c] = hh;
            sp += hh * ow_r[jj];
        }
        #pragma unroll
        for (int off = 8; off >= 1; off >>= 1)
            sp += __shfl_xor(sp, off);
        float o = sp + ob_r;

        if ((tid & 15) == 0) {
            int b = b0 + bb_c;
            if (t < 127) store_out(out, b * (127 * NV) + t * NV + n, o, obf);
            else         store_out(out, 520192 + b * NV + n, o, obf);
        }
        __syncthreads();
    }
}

extern "C" void kernel_launch(void* const* d_in, const int* in_sizes, int n_in,
                              void* d_out, int out_size, void* d_ws, size_t ws_size,
                              hipStream_t stream) {
    char* ws = (char*)d_ws;
    ushort_t* WT     = (ushort_t*)(ws + 0);                       // 4 MB (enc then dec)
    float*    Wih_f  = (float*)(ws + (4u<<20) + 0);
    float*    eb_f   = (float*)(ws + (4u<<20) + (64u<<10));
    float*    pw_f   = (float*)(ws + (4u<<20) + (128u<<10));
    float*    pb_f   = (float*)(ws + (4u<<20) + (144u<<10));
    float*    inw_f  = (float*)(ws + (4u<<20) + (160u<<10));
    float*    inb_f  = (float*)(ws + (4u<<20) + (352u<<10));
    float*    outw_f = (float*)(ws + (4u<<20) + (356u<<10));
    float*    outb_f = (float*)(ws + (4u<<20) + (420u<<10));
    float*    iHb_f  = (float*)(ws + (4u<<20) + (424u<<10));
    float*    iCb_f  = (float*)(ws + (4u<<20) + (440u<<10));
    float*    dbih_f = (float*)(ws + (4u<<20) + (456u<<10));
    float*    dbhh_f = (float*)(ws + (4u<<20) + (520u<<10));
    float*    dow_f  = (float*)(ws + (4u<<20) + (584u<<10));
    float*    dob_f  = (float*)(ws + (4u<<20) + (600u<<10));
    ushort_t* iHw_bf = (ushort_t*)(ws + (5u<<20));                // 1 MB
    ushort_t* iCw_bf = (ushort_t*)(ws + (6u<<20));                // 1 MB
    float*    C      = (float*)(ws + (7u<<20));                   // 2 MB
    float*    qb     = (float*)(ws + (9u<<20));
    float*    kb     = (float*)(ws + (11u<<20));
    float*    vb     = (float*)(ws + (13u<<20));
    float*    Cst    = (float*)(ws + (15u<<20));                  // 2 MB
    float*    h0     = (float*)(ws + (9u<<20));                   // reuse q after attn
    float*    c0     = (float*)(ws + (11u<<20));                  // reuse k after attn
    int*      flags  = (int*)(ws + (17u<<20));

    Ptr19 a;
    for (int i = 0; i < 19; i++) { a.p[i] = d_in[i]; a.e[i] = in_sizes[i]; }
    probe_kernel<<<1, 64, 0, stream>>>(a, flags);

    #define CONV_F32(idx, dst, E) conv_f32<<<((E)+255)/256, 256, 0, stream>>>(d_in[idx], flags, idx, dst, E)
    CONV_F32(1,  Wih_f,  16384);
    CONV_F32(3,  eb_f,   16384);
    CONV_F32(4,  pw_f,   4096);
    CONV_F32(5,  pb_f,   32);
    CONV_F32(6,  inw_f,  49152);
    CONV_F32(7,  inb_f,  384);
    CONV_F32(8,  outw_f, 16384);
    CONV_F32(9,  outb_f, 128);
    CONV_F32(11, iHb_f,  4096);
    CONV_F32(13, iCb_f,  4096);
    CONV_F32(15, dbih_f, 16384);
    CONV_F32(16, dbhh_f, 16384);
    CONV_F32(17, dow_f,  4096);
    CONV_F32(18, dob_f,  32);
    conv_bf16<<<(524288+255)/256, 256, 0, stream>>>(d_in[10], flags, 10, iHw_bf, 524288);
    conv_bf16<<<(524288+255)/256, 256, 0, stream>>>(d_in[12], flags, 12, iCw_bf, 524288);

    transpose_whh<<<dim3(64, 32), 256, 0, stream>>>(d_in[2], flags, 2, WT);
    enc_kernel<<<dim3(8, 32), 256, 0, stream>>>(d_in[0], flags, Wih_f, eb_f, pw_f, pb_f, WT, C);
    qkv_kernel<<<dim3(128, 3), 128, 0, stream>>>(C, inw_f, inb_f, qb, kb, vb);
    attn_kernel<<<dim3(128), 256, 0, stream>>>(qb, kb, vb, C, outw_f, outb_f, flags, Cst, d_out);
    transpose_whh<<<dim3(64, 32), 256, 0, stream>>>(d_in[14], flags, 14, WT);  // after enc: WT reused
    dec_init<<<dim3(128, 32), 256, 0, stream>>>(Cst, iHw_bf, iHb_f, iCw_bf, iCb_f, h0, c0);
    dec_kernel<<<dim3(8, 32), 256, 0, stream>>>(h0, c0, dbih_f, dbhh_f, dow_f, dob_f, WT, flags, d_out);
}

// Round 3
// 1003.621 us; speedup vs baseline: 9.1056x; 9.1056x over previous
//
#include <hip/hip_runtime.h>
#include <hip/hip_bf16.h>

typedef unsigned short ushort_t;
typedef unsigned int uint_t;

#define DD   128
#define G4   512
#define BT   16
#define NB   128
#define NV   32

// param block offsets (floats)
#define OFF_WIH   0
#define OFF_EB    16384
#define OFF_PW    32768
#define OFF_PB    36864
#define OFF_INW   36896
#define OFF_INB   86048
#define OFF_OUTW  86432
#define OFF_OUTB  102816
#define OFF_IHB   102944
#define OFF_ICB   107040
#define OFF_DBIH  111136
#define OFF_DBHH  127520
#define OFF_DOW   143904
#define OFF_DOB   148000
#define P_TOTAL   148032

typedef __attribute__((ext_vector_type(8))) short bf16x8;
typedef __attribute__((ext_vector_type(4))) float f32x4;

__device__ __forceinline__ float bf2f(ushort_t u) {
    union { uint_t i; float f; } x; x.i = ((uint_t)u) << 16; return x.f;
}
__device__ __forceinline__ float bflo(uint_t u) {
    union { uint_t i; float f; } x; x.i = u << 16; return x.f;
}
__device__ __forceinline__ float bfhi(uint_t u) {
    union { uint_t i; float f; } x; x.i = u & 0xffff0000u; return x.f;
}
__device__ __forceinline__ ushort_t f2bf(float f) {
    __hip_bfloat16 h = __float2bfloat16(f);
    return *(ushort_t*)&h;
}
__device__ __forceinline__ float sigmoid_f(float x) {
    return 1.f / (1.f + __expf(-x));
}
__device__ __forceinline__ float tanh_f(float x) {
    float e = __expf(2.f * x);
    return 1.f - 2.f / (e + 1.f);
}
__device__ __forceinline__ void store_out(void* out, long idx, float v, int bf) {
    if (bf) ((ushort_t*)out)[idx] = f2bf(v);
    else    ((float*)out)[idx]    = v;
}

// ---------------- dtype probe ----------------
struct Ptr19 { const void* p[19]; int e[19]; };

__global__ __launch_bounds__(64) void probe_kernel(Ptr19 a, int* __restrict__ flags) {
    int t = threadIdx.x;
    for (int i = 0; i < 19; i++) {
        int cap = a.e[i] < 2048 ? a.e[i] : 2048;
        int cnt = 0, tot = 0;
        const ushort_t* p = (const ushort_t*)a.p[i];
        for (int j = t; j < cap; j += 64) {
            ushort_t u = p[j];
            float af = fabsf(bf2f(u));
            tot++;
            if (u == 0 || (af > 1e-7f && af < 100.f)) cnt++;
        }
        #pragma unroll
        for (int off = 32; off >= 1; off >>= 1) {
            cnt += __shfl_xor(cnt, off);
            tot += __shfl_xor(tot, off);
        }
        if (t == 0) flags[i] = (cnt * 10 >= tot * 9) ? 1 : 0;
    }
}

// ---------------- merged param canonicalizer -> fp32 block P ----------------
__global__ __launch_bounds__(256) void conv_merged(Ptr19 a, const int* __restrict__ flags,
                                                   float* __restrict__ P) {
    int i = blockIdx.x * 256 + threadIdx.x;
    if (i >= P_TOTAL) return;
    int src, off;
    if      (i < OFF_EB)   { src = 1;  off = i - OFF_WIH; }
    else if (i < OFF_PW)   { src = 3;  off = i - OFF_EB; }
    else if (i < OFF_PB)   { src = 4;  off = i - OFF_PW; }
    else if (i < OFF_INW)  { src = 5;  off = i - OFF_PB; }
    else if (i < OFF_INB)  { src = 6;  off = i - OFF_INW; }
    else if (i < OFF_OUTW) { src = 7;  off = i - OFF_INB; }
    else if (i < OFF_OUTB) { src = 8;  off = i - OFF_OUTW; }
    else if (i < OFF_IHB)  { src = 9;  off = i - OFF_OUTB; }
    else if (i < OFF_ICB)  { src = 11; off = i - OFF_IHB; }
    else if (i < OFF_DBIH) { src = 13; off = i - OFF_ICB; }
    else if (i < OFF_DBHH) { src = 15; off = i - OFF_DBIH; }
    else if (i < OFF_DOW)  { src = 16; off = i - OFF_DBHH; }
    else if (i < OFF_DOB)  { src = 17; off = i - OFF_DOW; }
    else                   { src = 18; off = i - OFF_DOB; }
    int bf = flags[src];
    P[i] = bf ? bf2f(((const ushort_t*)a.p[src])[off]) : ((const float*)a.p[src])[off];
}

// ===================== encoder: MFMA recurrence + online softmax pool =====================
// grid (8, 32), 256 threads. Weights persistent in registers (32 KB/wave).
__global__ __launch_bounds__(256, 1) void enc_kernel(
    const void* __restrict__ Xraw, const void* __restrict__ Wraw,
    const int* __restrict__ flags, const float* __restrict__ P,
    float* __restrict__ Cout)
{
    const int n = blockIdx.y, b0 = blockIdx.x * BT;
    const int tid = threadIdx.x;
    const int w = tid >> 6, lane = tid & 63;
    const int l15 = lane & 15, quad = lane >> 4;
    const int xbf = flags[0], wbf = flags[2];
    const ushort_t* Xu = (const ushort_t*)Xraw;
    const float*    Xf = (const float*)Xraw;

    __shared__ alignas(16) ushort_t hSh[2][16 * 136];
    __shared__ alignas(16) ushort_t hSl[2][16 * 136];
    __shared__ alignas(16) float wP[2][16][4];

    for (int i = tid; i < 16 * 136; i += 256) { hSh[0][i] = 0; hSl[0][i] = 0; }

    // B-fragments: bfrag[typ*2+s][kc]; lane holds B[k=32kc+8quad+j][g = typ*128+32w+16s+l15]
    bf16x8 bfrag[8][4];
    #pragma unroll
    for (int ts = 0; ts < 8; ts++) {
        const int typ = ts >> 1, s = ts & 1;
        const int g = typ * 128 + 32 * w + 16 * s + l15;
        #pragma unroll
        for (int kc = 0; kc < 4; kc++) {
            const int base = (n * G4 + g) * DD + 32 * kc + 8 * quad;
            if (wbf) {
                bfrag[ts][kc] = *(const bf16x8*)((const ushort_t*)Wraw + base);
            } else {
                const float* fp = (const float*)Wraw + base;
                bf16x8 tmp;
                #pragma unroll
                for (int j = 0; j < 8; j++) tmp[j] = (short)f2bf(fp[j]);
                bfrag[ts][kc] = tmp;
            }
        }
    }

    float bias[8], wih[8];
    #pragma unroll
    for (int ts = 0; ts < 8; ts++) {
        const int typ = ts >> 1, s = ts & 1;
        const int g = typ * 128 + 32 * w + 16 * s + l15;
        bias[ts] = P[OFF_EB + n * G4 + g];
        wih[ts]  = P[OFF_WIH + n * G4 + g];
    }
    float pwv[2];
    #pragma unroll
    for (int s = 0; s < 2; s++) pwv[s] = P[OFF_PW + n * DD + 32 * w + 16 * s + l15];
    const float pb_r = P[OFF_PB + n];

    float cst[8], hprev[8], Cacc[8], mR[4], lR[4];
    #pragma unroll
    for (int i = 0; i < 8; i++) { cst[i] = 0.f; hprev[i] = 0.f; Cacc[i] = 0.f; }
    #pragma unroll
    for (int r = 0; r < 4; r++) { mR[r] = -1e30f; lR[r] = 0.f; }

    float xq[4];
    #pragma unroll
    for (int r = 0; r < 4; r++) {
        int idx = (b0 + 4 * quad + r) * 4096 + n;
        xq[r] = xbf ? bf2f(Xu[idx]) : Xf[idx];
    }

    for (int t = 0; t < 127; t++) {
        const int rb = t & 1, wb = rb ^ 1;
        __syncthreads();

        if (t > 0) {   // fold step t-1 into online softmax (hprev = h_{t-1})
            #pragma unroll
            for (int r = 0; r < 4; r++) {
                f32x4 v = *(const f32x4*)&wP[rb][4 * quad + r][0];
                float s_b = v.x + v.y + v.z + v.w + pb_r;
                float mnew = fmaxf(mR[r], s_b);
                float sc = __expf(mR[r] - mnew);
                float e  = __expf(s_b - mnew);
                lR[r] = lR[r] * sc + e;
                Cacc[r]     = Cacc[r]     * sc + e * hprev[r];
                Cacc[4 + r] = Cacc[4 + r] * sc + e * hprev[4 + r];
                mR[r] = mnew;
            }
        }

        bf16x8 ah[4], al[4];
        #pragma unroll
        for (int kc = 0; kc < 4; kc++) {
            ah[kc] = *(const bf16x8*)&hSh[rb][l15 * 136 + 32 * kc + 8 * quad];
            al[kc] = *(const bf16x8*)&hSl[rb][l15 * 136 + 32 * kc + 8 * quad];
        }

        f32x4 acc[8];
        #pragma unroll
        for (int ts = 0; ts < 8; ts++) {
            f32x4 a;
            a.x = bias[ts] + xq[0] * wih[ts];
            a.y = bias[ts] + xq[1] * wih[ts];
            a.z = bias[ts] + xq[2] * wih[ts];
            a.w = bias[ts] + xq[3] * wih[ts];
            acc[ts] = a;
        }

        if (t < 126) {   // prefetch x_{t+1}
            #pragma unroll
            for (int r = 0; r < 4; r++) {
                int idx = (b0 + 4 * quad + r) * 4096 + (t + 1) * 32 + n;
                xq[r] = xbf ? bf2f(Xu[idx]) : Xf[idx];
            }
        }

        #pragma unroll
        for (int kc = 0; kc < 4; kc++)
            #pragma unroll
            for (int ts = 0; ts < 8; ts++) {
                acc[ts] = __builtin_amdgcn_mfma_f32_16x16x32_bf16(al[kc], bfrag[ts][kc], acc[ts], 0, 0, 0);
                acc[ts] = __builtin_amdgcn_mfma_f32_16x16x32_bf16(ah[kc], bfrag[ts][kc], acc[ts], 0, 0, 0);
            }

        float hn[8];
        #pragma unroll
        for (int s = 0; s < 2; s++)
            #pragma unroll
            for (int r = 0; r < 4; r++) {
                float gi = acc[0 + s][r];
                float gf = acc[2 + s][r];
                float gg = acc[4 + s][r];
                float go = acc[6 + s][r];
                float ii = sigmoid_f(gi), ff = sigmoid_f(gf);
                float g2 = tanh_f(gg),    oo = sigmoid_f(go);
                float cc = ff * cst[s * 4 + r] + ii * g2;
                cst[s * 4 + r] = cc;
                hn[s * 4 + r] = oo * tanh_f(cc);
            }

        #pragma unroll
        for (int s = 0; s < 2; s++)
            #pragma unroll
            for (int r = 0; r < 4; r++) {
                float hh = hn[s * 4 + r];
                ushort_t hi = f2bf(hh);
                int addr = (4 * quad + r) * 136 + 32 * w + 16 * s + l15;
                hSh[wb][addr] = hi;
                hSl[wb][addr] = f2bf(hh - bf2f(hi));
            }

        float pr[4];
        #pragma unroll
        for (int r = 0; r < 4; r++)
            pr[r] = hn[r] * pwv[0] + hn[4 + r] * pwv[1];
        #pragma unroll
        for (int r = 0; r < 4; r++) {
            #pragma unroll
            for (int m = 1; m < 16; m <<= 1)
                pr[r] += __shfl_xor(pr[r], m, 16);
        }
        if (l15 == 0) {
            #pragma unroll
            for (int r = 0; r < 4; r++)
                wP[wb][4 * quad + r][w] = pr[r];
        }

        #pragma unroll
        for (int i = 0; i < 8; i++) hprev[i] = hn[i];
    }

    __syncthreads();
    #pragma unroll
    for (int r = 0; r < 4; r++) {   // fold final step t=126 (rb of t=127 is 1)
        f32x4 v = *(const f32x4*)&wP[1][4 * quad + r][0];
        float s_b = v.x + v.y + v.z + v.w + pb_r;
        float mnew = fmaxf(mR[r], s_b);
        float sc = __expf(mR[r] - mnew);
        float e  = __expf(s_b - mnew);
        lR[r] = lR[r] * sc + e;
        Cacc[r]     = Cacc[r]     * sc + e * hprev[r];
        Cacc[4 + r] = Cacc[4 + r] * sc + e * hprev[4 + r];
    }
    #pragma unroll
    for (int s = 0; s < 2; s++)
        #pragma unroll
        for (int r = 0; r < 4; r++) {
            int b = b0 + 4 * quad + r;
            int d = 32 * w + 16 * s + l15;
            Cout[b * (NV * DD) + n * DD + d] = Cacc[s * 4 + r] / lR[r];
        }
}

// Note: acc index mapping — acc[typ*2+s]: gi uses ts = 0*2+s = s, gf ts=2+s, gg ts=4+s, go ts=6+s. OK.

// ---------------- QKV projection ----------------
__global__ __launch_bounds__(128) void qkv_kernel(
    const float* __restrict__ C, const float* __restrict__ P,
    float* __restrict__ q, float* __restrict__ k, float* __restrict__ v)
{
    int b = blockIdx.x, p = blockIdx.y, j = threadIdx.x;
    __shared__ float Cb[NV * DD];
    for (int i = j; i < NV * DD; i += 128) Cb[i] = C[b * (NV * DD) + i];
    __syncthreads();

    const float* wrow = P + OFF_INW + (p * DD + j) * DD;
    float bias = P[OFF_INB + p * DD + j];
    float acc[NV];
    #pragma unroll
    for (int nn = 0; nn < NV; nn++) acc[nn] = bias;

    for (int dc = 0; dc < DD; dc += 8) {
        float4 w0 = *(const float4*)&wrow[dc];
        float4 w1 = *(const float4*)&wrow[dc + 4];
        #pragma unroll
        for (int nn = 0; nn < NV; nn++) {
            float4 c0 = *(float4*)&Cb[nn * DD + dc];
            float4 c1 = *(float4*)&Cb[nn * DD + dc + 4];
            acc[nn] += c0.x * w0.x + c0.y * w0.y + c0.z * w0.z + c0.w * w0.w
                     + c1.x * w1.x + c1.y * w1.y + c1.z * w1.z + c1.w * w1.w;
        }
    }
    float* dst = (p == 0) ? q : (p == 1) ? k : v;
    for (int nn = 0; nn < NV; nn++) dst[b * (NV * DD) + nn * DD + j] = acc[nn];
}

// ---------------- cross-attention + out-proj + residual ----------------
__global__ __launch_bounds__(256) void attn_kernel(
    const float* __restrict__ q, const float* __restrict__ k, const float* __restrict__ v,
    const float* __restrict__ C, const float* __restrict__ P,
    const int* __restrict__ flags, float* __restrict__ Cstar, void* __restrict__ dout)
{
    int b = blockIdx.x, tid = threadIdx.x;
    int obf = flags[0];
    __shared__ float Qs[NV * DD], Ks[NV * DD], Vs[NV * DD];
    float* Os = Ks;
    for (int i = tid; i < NV * DD; i += 256) Qs[i] = q[b * (NV * DD) + i];
    __syncthreads();

    int hh = tid >> 5, qi = tid & 31;
    float qreg[16];
    #pragma unroll
    for (int u = 0; u < 4; u++) {
        float4 t4 = *(float4*)&Qs[qi * DD + hh * 16 + 4 * u];
        qreg[4*u] = t4.x; qreg[4*u+1] = t4.y; qreg[4*u+2] = t4.z; qreg[4*u+3] = t4.w;
    }

    float Oacc[16];
    #pragma unroll
    for (int u = 0; u < 16; u++) Oacc[u] = 0.f;
    float wsum = 0.f;
    int tmax = (b < 5) ? b : 5;

    for (int tau = 1; tau <= tmax; tau++) {
        __syncthreads();
        for (int i = tid; i < NV * DD; i += 256) {
            Ks[i] = k[(b - tau) * (NV * DD) + i];
            Vs[i] = v[(b - tau) * (NV * DD) + i];
        }
        __syncthreads();

        float s[NV];
        #pragma unroll
        for (int kk = 0; kk < NV; kk++) {
            float a = 0.f;
            #pragma unroll
            for (int u = 0; u < 4; u++) {
                float4 kv = *(float4*)&Ks[kk * DD + hh * 16 + 4 * u];
                a += qreg[4*u] * kv.x + qreg[4*u+1] * kv.y
                   + qreg[4*u+2] * kv.z + qreg[4*u+3] * kv.w;
            }
            s[kk] = a * 0.25f;
        }
        float mm = s[0];
        #pragma unroll
        for (int kk = 1; kk < NV; kk++) mm = fmaxf(mm, s[kk]);
        float ssum = 0.f;
        #pragma unroll
        for (int kk = 0; kk < NV; kk++) { s[kk] = __expf(s[kk] - mm); ssum += s[kk]; }
        float w  = __expf(-0.7f * (float)(tau - 1));
        wsum += w;
        float wr = w / ssum;
        #pragma unroll
        for (int u = 0; u < 4; u++) {
            float ax = 0.f, ay = 0.f, az = 0.f, aw = 0.f;
            #pragma unroll
            for (int kk = 0; kk < NV; kk++) {
                float4 vv = *(float4*)&Vs[kk * DD + hh * 16 + 4 * u];
                ax += s[kk] * vv.x; ay += s[kk] * vv.y;
                az += s[kk] * vv.z; aw += s[kk] * vv.w;
            }
            Oacc[4*u] += wr * ax; Oacc[4*u+1] += wr * ay;
            Oacc[4*u+2] += wr * az; Oacc[4*u+3] += wr * aw;
        }
    }

    __syncthreads();
    float winv = (b > 0) ? 1.f / wsum : 0.f;
    #pragma unroll
    for (int u = 0; u < 16; u++)
        Os[qi * DD + hh * 16 + u] = Oacc[u] * winv;
    __syncthreads();

    int j = tid & 127, ng = tid >> 7;
    const float* wrow = P + OFF_OUTW + j * DD;
    float obias = P[OFF_OUTB + j];
    for (int nn = ng * 16; nn < ng * 16 + 16; nn++) {
        float a = (b > 0) ? obias : 0.f;
        for (int dc = 0; dc < DD; dc += 8) {
            float4 w0 = *(const float4*)&wrow[dc];
            float4 w1 = *(const float4*)&wrow[dc + 4];
            float4 o0 = *(float4*)&Os[nn * DD + dc];
            float4 o1 = *(float4*)&Os[nn * DD + dc + 4];
            a += o0.x*w0.x + o0.y*w0.y + o0.z*w0.z + o0.w*w0.w
               + o1.x*w1.x + o1.y*w1.y + o1.z*w1.z + o1.w*w1.w;
        }
        float cs = C[b * (NV * DD) + nn * DD + j] + a;
        Cstar[b * (NV * DD) + nn * DD + j] = cs;
        store_out(dout, 524288 + b * (NV * DD) + nn * DD + j, cs, obf);
    }
}

// ---------------- decoder init ----------------
__global__ __launch_bounds__(256) void dec_init(
    const float* __restrict__ Cstar,
    const void* __restrict__ iHw, const void* __restrict__ iCw,
    const int* __restrict__ flags, const float* __restrict__ P,
    float* __restrict__ h0, float* __restrict__ c0)
{
    int b = blockIdx.x, nn = blockIdx.y, tid = threadIdx.x;
    __shared__ float cs[DD];
    if (tid < DD) cs[tid] = Cstar[b * (NV * DD) + nn * DD + tid];
    __syncthreads();
    int e = tid & 127, mat = tid >> 7;
    const void* Wp = mat ? iCw : iHw;
    int wf = flags[mat ? 12 : 10];
    float acc = P[(mat ? OFF_ICB : OFF_IHB) + nn * DD + e];
    if (wf) {
        const uint_t* wrow = (const uint_t*)Wp + (((nn * DD + e) * DD) >> 1);
        for (int dc = 0; dc < DD; dc += 8) {
            float wf8[8];
            #pragma unroll
            for (int u = 0; u < 4; u++) {
                uint_t x = wrow[dc / 2 + u];
                wf8[2*u] = bflo(x); wf8[2*u+1] = bfhi(x);
            }
            float4 c0v = *(float4*)&cs[dc];
            float4 c1v = *(float4*)&cs[dc + 4];
            acc += c0v.x*wf8[0] + c0v.y*wf8[1] + c0v.z*wf8[2] + c0v.w*wf8[3]
                 + c1v.x*wf8[4] + c1v.y*wf8[5] + c1v.z*wf8[6] + c1v.w*wf8[7];
        }
    } else {
        const float* wrow = (const float*)Wp + (nn * DD + e) * DD;
        for (int dc = 0; dc < DD; dc += 8) {
            float4 w0 = *(const float4*)&wrow[dc];
            float4 w1 = *(const float4*)&wrow[dc + 4];
            float4 c0v = *(float4*)&cs[dc];
            float4 c1v = *(float4*)&cs[dc + 4];
            acc += c0v.x*w0.x + c0v.y*w0.y + c0v.z*w0.z + c0v.w*w0.w
                 + c1v.x*w1.x + c1v.y*w1.y + c1v.z*w1.z + c1v.w*w1.w;
        }
    }
    (mat ? c0 : h0)[(nn * NB + b) * DD + e] = tanh_f(acc);
}

// ===================== decoder: MFMA recurrence -> recon/pred =====================
__global__ __launch_bounds__(256, 1) void dec_kernel(
    const float* __restrict__ h0, const float* __restrict__ c0,
    const void* __restrict__ Wraw, const int* __restrict__ flags,
    const float* __restrict__ P, void* __restrict__ out)
{
    const int n = blockIdx.y, b0 = blockIdx.x * BT;
    const int tid = threadIdx.x;
    const int w = tid >> 6, lane = tid & 63;
    const int l15 = lane & 15, quad = lane >> 4;
    const int wbf = flags[14], obf = flags[0];

    __shared__ alignas(16) ushort_t hSh[2][16 * 136];
    __shared__ alignas(16) ushort_t hSl[2][16 * 136];
    __shared__ alignas(16) float wP[2][16][4];

    bf16x8 bfrag[8][4];
    #pragma unroll
    for (int ts = 0; ts < 8; ts++) {
        const int typ = ts >> 1, s = ts & 1;
        const int g = typ * 128 + 32 * w + 16 * s + l15;
        #pragma unroll
        for (int kc = 0; kc < 4; kc++) {
            const int base = (n * G4 + g) * DD + 32 * kc + 8 * quad;
            if (wbf) {
                bfrag[ts][kc] = *(const bf16x8*)((const ushort_t*)Wraw + base);
            } else {
                const float* fp = (const float*)Wraw + base;
                bf16x8 tmp;
                #pragma unroll
                for (int j = 0; j < 8; j++) tmp[j] = (short)f2bf(fp[j]);
                bfrag[ts][kc] = tmp;
            }
        }
    }

    float bias[8];
    #pragma unroll
    for (int ts = 0; ts < 8; ts++) {
        const int typ = ts >> 1, s = ts & 1;
        const int g = typ * 128 + 32 * w + 16 * s + l15;
        bias[ts] = P[OFF_DBIH + n * G4 + g] + P[OFF_DBHH + n * G4 + g];
    }
    float owv[2];
    #pragma unroll
    for (int s = 0; s < 2; s++) owv[s] = P[OFF_DOW + n * DD + 32 * w + 16 * s + l15];
    const float ob_r = P[OFF_DOB + n];

    float cst[8];
    #pragma unroll
    for (int s = 0; s < 2; s++)
        #pragma unroll
        for (int r = 0; r < 4; r++) {
            int b = b0 + 4 * quad + r;
            int d = 32 * w + 16 * s + l15;
            float hv = h0[(n * NB + b) * DD + d];
            cst[s * 4 + r] = c0[(n * NB + b) * DD + d];
            int addr = (4 * quad + r) * 136 + d;
            ushort_t hi = f2bf(hv);
            hSh[0][addr] = hi;
            hSl[0][addr] = f2bf(hv - bf2f(hi));
        }

    for (int t = 0; t < 128; t++) {
        const int rb = t & 1, wb = rb ^ 1;
        __syncthreads();

        if (t > 0 && w == 0) {   // emit o(t-1)
            #pragma unroll
            for (int r = 0; r < 4; r++) {
                f32x4 v = *(const f32x4*)&wP[rb][4 * quad + r][0];
                float o = v.x + v.y + v.z + v.w + ob_r;
                if (l15 == 0) {
                    long b = b0 + 4 * quad + r;
                    store_out(out, b * 4064 + (long)(t - 1) * NV + n, o, obf);
                }
            }
        }

        bf16x8 ah[4], al[4];
        #pragma unroll
        for (int kc = 0; kc < 4; kc++) {
            ah[kc] = *(const bf16x8*)&hSh[rb][l15 * 136 + 32 * kc + 8 * quad];
            al[kc] = *(const bf16x8*)&hSl[rb][l15 * 136 + 32 * kc + 8 * quad];
        }

        f32x4 acc[8];
        #pragma unroll
        for (int ts = 0; ts < 8; ts++) {
            f32x4 a;
            a.x = bias[ts]; a.y = bias[ts]; a.z = bias[ts]; a.w = bias[ts];
            acc[ts] = a;
        }

        #pragma unroll
        for (int kc = 0; kc < 4; kc++)
            #pragma unroll
            for (int ts = 0; ts < 8; ts++) {
                acc[ts] = __builtin_amdgcn_mfma_f32_16x16x32_bf16(al[kc], bfrag[ts][kc], acc[ts], 0, 0, 0);
                acc[ts] = __builtin_amdgcn_mfma_f32_16x16x32_bf16(ah[kc], bfrag[ts][kc], acc[ts], 0, 0, 0);
            }

        float hn[8];
        #pragma unroll
        for (int s = 0; s < 2; s++)
            #pragma unroll
            for (int r = 0; r < 4; r++) {
                float gi = acc[0 + s][r];
                float gf = acc[2 + s][r];
                float gg = acc[4 + s][r];
                float go = acc[6 + s][r];
                float ii = sigmoid_f(gi), ff = sigmoid_f(gf);
                float g2 = tanh_f(gg),    oo = sigmoid_f(go);
                float cc = ff * cst[s * 4 + r] + ii * g2;
                cst[s * 4 + r] = cc;
                hn[s * 4 + r] = oo * tanh_f(cc);
            }

        #pragma unroll
        for (int s = 0; s < 2; s++)
            #pragma unroll
            for (int r = 0; r < 4; r++) {
                float hh = hn[s * 4 + r];
                ushort_t hi = f2bf(hh);
                int addr = (4 * quad + r) * 136 + 32 * w + 16 * s + l15;
                hSh[wb][addr] = hi;
                hSl[wb][addr] = f2bf(hh - bf2f(hi));
            }

        float pr[4];
        #pragma unroll
        for (int r = 0; r < 4; r++)
            pr[r] = hn[r] * owv[0] + hn[4 + r] * owv[1];
        #pragma unroll
        for (int r = 0; r < 4; r++) {
            #pragma unroll
            for (int m = 1; m < 16; m <<= 1)
                pr[r] += __shfl_xor(pr[r], m, 16);
        }
        if (l15 == 0) {
            #pragma unroll
            for (int r = 0; r < 4; r++)
                wP[wb][4 * quad + r][w] = pr[r];
        }
    }

    __syncthreads();
    if (w == 0) {   // emit pred o(127); rb for t=128 is 0
        #pragma unroll
        for (int r = 0; r < 4; r++) {
            f32x4 v = *(const f32x4*)&wP[0][4 * quad + r][0];
            float o = v.x + v.y + v.z + v.w + ob_r;
            if (l15 == 0) {
                long b = b0 + 4 * quad + r;
                store_out(out, 520192 + b * NV + n, o, obf);
            }
        }
    }
}

extern "C" void kernel_launch(void* const* d_in, const int* in_sizes, int n_in,
                              void* d_out, int out_size, void* d_ws, size_t ws_size,
                              hipStream_t stream) {
    char* ws = (char*)d_ws;
    float* P    = (float*)(ws + 0);              // 592 KB
    float* C    = (float*)(ws + (1u << 20));     // 2 MB
    float* qb   = (float*)(ws + (3u << 20));
    float* kb   = (float*)(ws + (5u << 20));
    float* vb   = (float*)(ws + (7u << 20));
    float* Cst  = (float*)(ws + (9u << 20));
    float* h0   = (float*)(ws + (11u << 20));
    float* c0   = (float*)(ws + (13u << 20));
    int*   flags = (int*)(ws + (15u << 20));

    Ptr19 a;
    for (int i = 0; i < 19; i++) { a.p[i] = d_in[i]; a.e[i] = in_sizes[i]; }
    probe_kernel<<<1, 64, 0, stream>>>(a, flags);
    conv_merged<<<(P_TOTAL + 255) / 256, 256, 0, stream>>>(a, flags, P);

    enc_kernel<<<dim3(8, 32), 256, 0, stream>>>(d_in[0], d_in[2], flags, P, C);
    qkv_kernel<<<dim3(128, 3), 128, 0, stream>>>(C, P, qb, kb, vb);
    attn_kernel<<<dim3(128), 256, 0, stream>>>(qb, kb, vb, C, P, flags, Cst, d_out);
    dec_init<<<dim3(128, 32), 256, 0, stream>>>(Cst, d_in[10], d_in[12], flags, P, h0, c0);
    dec_kernel<<<dim3(8, 32), 256, 0, stream>>>(h0, c0, d_in[14], flags, P, d_out);
}

// Round 4
// 836.991 us; speedup vs baseline: 10.9184x; 1.1991x over previous
//
#include <hip/hip_runtime.h>
#include <hip/hip_bf16.h>

typedef unsigned short ushort_t;
typedef unsigned int uint_t;

#define DD   128
#define G4   512
#define BT   16
#define NB   128
#define NV   32

// param block offsets (floats)
#define OFF_WIH   0
#define OFF_EB    16384
#define OFF_PW    32768
#define OFF_PB    36864
#define OFF_INW   36896
#define OFF_INB   86048
#define OFF_OUTW  86432
#define OFF_OUTB  102816
#define OFF_IHB   102944
#define OFF_ICB   107040
#define OFF_DBIH  111136
#define OFF_DBHH  127520
#define OFF_DOW   143904
#define OFF_DOB   148000
#define P_TOTAL   148032

typedef __attribute__((ext_vector_type(8))) short bf16x8;
typedef __attribute__((ext_vector_type(4))) float f32x4;

__device__ __forceinline__ float bf2f(ushort_t u) {
    union { uint_t i; float f; } x; x.i = ((uint_t)u) << 16; return x.f;
}
__device__ __forceinline__ float bflo(uint_t u) {
    union { uint_t i; float f; } x; x.i = u << 16; return x.f;
}
__device__ __forceinline__ float bfhi(uint_t u) {
    union { uint_t i; float f; } x; x.i = u & 0xffff0000u; return x.f;
}
__device__ __forceinline__ ushort_t f2bf(float f) {
    __hip_bfloat16 h = __float2bfloat16(f);
    return *(ushort_t*)&h;
}
__device__ __forceinline__ uint_t f2u(float f) {
    union { float f; uint_t i; } x; x.f = f; return x.i;
}
__device__ __forceinline__ float u2f(uint_t u) {
    union { uint_t i; float f; } x; x.i = u; return x.f;
}
__device__ __forceinline__ float sigmoid_f(float x) {
    return 1.f / (1.f + __expf(-x));
}
__device__ __forceinline__ float tanh_f(float x) {
    float e = __expf(2.f * x);
    return 1.f - 2.f / (e + 1.f);
}
__device__ __forceinline__ void store_out(void* out, long idx, float v, int bf) {
    if (bf) ((ushort_t*)out)[idx] = f2bf(v);
    else    ((float*)out)[idx]    = v;
}

// ---------------- dtype probe (one block per input) ----------------
struct Ptr19 { const void* p[19]; int e[19]; };

__global__ __launch_bounds__(64) void probe_kernel(Ptr19 a, int* __restrict__ flags) {
    int i = blockIdx.x;
    int t = threadIdx.x;
    int cap = a.e[i] < 2048 ? a.e[i] : 2048;
    int cnt = 0, tot = 0;
    const ushort_t* p = (const ushort_t*)a.p[i];
    for (int j = t; j < cap; j += 64) {
        ushort_t u = p[j];
        float af = fabsf(bf2f(u));
        tot++;
        if (u == 0 || (af > 1e-7f && af < 100.f)) cnt++;
    }
    #pragma unroll
    for (int off = 32; off >= 1; off >>= 1) {
        cnt += __shfl_xor(cnt, off);
        tot += __shfl_xor(tot, off);
    }
    if (t == 0) flags[i] = (cnt * 10 >= tot * 9) ? 1 : 0;
}

// ---------------- merged param canonicalizer -> fp32 block P ----------------
__global__ __launch_bounds__(256) void conv_merged(Ptr19 a, const int* __restrict__ flags,
                                                   float* __restrict__ P) {
    int i = blockIdx.x * 256 + threadIdx.x;
    if (i >= P_TOTAL) return;
    int src, off;
    if      (i < OFF_EB)   { src = 1;  off = i - OFF_WIH; }
    else if (i < OFF_PW)   { src = 3;  off = i - OFF_EB; }
    else if (i < OFF_PB)   { src = 4;  off = i - OFF_PW; }
    else if (i < OFF_INW)  { src = 5;  off = i - OFF_PB; }
    else if (i < OFF_INB)  { src = 6;  off = i - OFF_INW; }
    else if (i < OFF_OUTW) { src = 7;  off = i - OFF_INB; }
    else if (i < OFF_OUTB) { src = 8;  off = i - OFF_OUTW; }
    else if (i < OFF_IHB)  { src = 9;  off = i - OFF_OUTB; }
    else if (i < OFF_ICB)  { src = 11; off = i - OFF_IHB; }
    else if (i < OFF_DBIH) { src = 13; off = i - OFF_ICB; }
    else if (i < OFF_DBHH) { src = 15; off = i - OFF_DBIH; }
    else if (i < OFF_DOW)  { src = 16; off = i - OFF_DBHH; }
    else if (i < OFF_DOB)  { src = 17; off = i - OFF_DOW; }
    else                   { src = 18; off = i - OFF_DOB; }
    int bf = flags[src];
    P[i] = bf ? bf2f(((const ushort_t*)a.p[src])[off]) : ((const float*)a.p[src])[off];
}

// ---------------- X transpose: (B,L,N) -> bf16 [t][n][b] ----------------
__global__ __launch_bounds__(256) void conv_X(const void* __restrict__ src,
                                              const int* __restrict__ flags,
                                              ushort_t* __restrict__ Xc) {
    int i = blockIdx.x * 256 + threadIdx.x;   // output index [t][n][b]
    if (i >= NB * 128 * NV) return;
    int b = i & 127, nn = (i >> 7) & 31, t = i >> 12;
    int si = b * 4096 + t * 32 + nn;
    int bf = flags[0];
    Xc[i] = bf ? ((const ushort_t*)src)[si] : f2bf(((const float*)src)[si]);
}

// ===================== encoder: 8-wave MFMA recurrence + online softmax pool =====================
// grid (8, 32), 512 threads. Wave w owns d-slice [16w, 16w+16); one B-fragment per gate type.
__global__ __launch_bounds__(512, 2) void enc_kernel(
    const ushort_t* __restrict__ Xc, const void* __restrict__ Wraw,
    const int* __restrict__ flags, const float* __restrict__ P,
    float* __restrict__ Cout)
{
    const int n = blockIdx.y, b0 = blockIdx.x * BT;
    const int tid = threadIdx.x;
    const int w = tid >> 6, lane = tid & 63;
    const int l15 = lane & 15, quad = lane >> 4;
    const int wbf = flags[2];
    const int d_own = 16 * w + l15;

    __shared__ alignas(16) ushort_t hSh[2][16 * 136];
    __shared__ alignas(16) ushort_t hSl[2][16 * 136];
    __shared__ alignas(16) float wP[2][16][8];

    for (int i = tid; i < 16 * 136; i += 512) { hSh[0][i] = 0; hSl[0][i] = 0; }

    // B-fragments: bfrag[typ][kc]; lane holds B[k=32kc+8quad+j][g = typ*128 + d_own]
    bf16x8 bfrag[4][4];
    #pragma unroll
    for (int typ = 0; typ < 4; typ++) {
        const int g = typ * 128 + d_own;
        #pragma unroll
        for (int kc = 0; kc < 4; kc++) {
            const int base = (n * G4 + g) * DD + 32 * kc + 8 * quad;
            if (wbf) {
                bfrag[typ][kc] = *(const bf16x8*)((const ushort_t*)Wraw + base);
            } else {
                const float* fp = (const float*)Wraw + base;
                bf16x8 tmp;
                #pragma unroll
                for (int j = 0; j < 8; j++) tmp[j] = (short)f2bf(fp[j]);
                bfrag[typ][kc] = tmp;
            }
        }
    }

    float bias[4], wih[4];
    #pragma unroll
    for (int typ = 0; typ < 4; typ++) {
        bias[typ] = P[OFF_EB  + n * G4 + typ * 128 + d_own];
        wih[typ]  = P[OFF_WIH + n * G4 + typ * 128 + d_own];
    }
    const float pwv  = P[OFF_PW + n * DD + d_own];
    const float pb_r = P[OFF_PB + n];

    float cst[4], hprev[4], Cacc[4], mR[4], lR[4];
    #pragma unroll
    for (int r = 0; r < 4; r++) {
        cst[r] = 0.f; hprev[r] = 0.f; Cacc[r] = 0.f; mR[r] = -1e30f; lR[r] = 0.f;
    }

    ushort4 xu = *(const ushort4*)&Xc[n * 128 + b0 + 4 * quad];   // t = 0

    for (int t = 0; t < 127; t++) {
        const int rb = t & 1, wb = rb ^ 1;
        __syncthreads();

        bf16x8 ah[4], al[4];
        #pragma unroll
        for (int kc = 0; kc < 4; kc++) {
            ah[kc] = *(const bf16x8*)&hSh[rb][l15 * 136 + 32 * kc + 8 * quad];
            al[kc] = *(const bf16x8*)&hSl[rb][l15 * 136 + 32 * kc + 8 * quad];
        }

        float xq[4] = { bf2f(xu.x), bf2f(xu.y), bf2f(xu.z), bf2f(xu.w) };
        f32x4 acc[4];
        #pragma unroll
        for (int typ = 0; typ < 4; typ++) {
            f32x4 a;
            a.x = bias[typ] + xq[0] * wih[typ];
            a.y = bias[typ] + xq[1] * wih[typ];
            a.z = bias[typ] + xq[2] * wih[typ];
            a.w = bias[typ] + xq[3] * wih[typ];
            acc[typ] = a;
        }

        if (t < 126)
            xu = *(const ushort4*)&Xc[(t + 1) * 4096 + n * 128 + b0 + 4 * quad];

        if (t > 0) {   // fold step t-1 into online softmax (hprev = h_{t-1})
            #pragma unroll
            for (int r = 0; r < 4; r++) {
                f32x4 v0 = *(const f32x4*)&wP[rb][4 * quad + r][0];
                f32x4 v1 = *(const f32x4*)&wP[rb][4 * quad + r][4];
                float s_b = v0.x + v0.y + v0.z + v0.w + v1.x + v1.y + v1.z + v1.w + pb_r;
                float mnew = fmaxf(mR[r], s_b);
                float sc = __expf(mR[r] - mnew);
                float e  = __expf(s_b - mnew);
                lR[r] = lR[r] * sc + e;
                Cacc[r] = Cacc[r] * sc + e * hprev[r];
                mR[r] = mnew;
            }
        }

        #pragma unroll
        for (int kc = 0; kc < 4; kc++)
            #pragma unroll
            for (int typ = 0; typ < 4; typ++) {
                acc[typ] = __builtin_amdgcn_mfma_f32_16x16x32_bf16(al[kc], bfrag[typ][kc], acc[typ], 0, 0, 0);
                acc[typ] = __builtin_amdgcn_mfma_f32_16x16x32_bf16(ah[kc], bfrag[typ][kc], acc[typ], 0, 0, 0);
            }

        float hn[4];
        #pragma unroll
        for (int r = 0; r < 4; r++) {
            float ii = sigmoid_f(acc[0][r]);
            float ff = sigmoid_f(acc[1][r]);
            float g2 = tanh_f(acc[2][r]);
            float oo = sigmoid_f(acc[3][r]);
            float cc = ff * cst[r] + ii * g2;
            cst[r] = cc;
            hn[r] = oo * tanh_f(cc);
        }

        #pragma unroll
        for (int r = 0; r < 4; r++) {   // truncation hi/lo split
            uint_t bits = f2u(hn[r]);
            float hi_f = u2f(bits & 0xffff0000u);
            int addr = (4 * quad + r) * 136 + d_own;
            hSh[wb][addr] = (ushort_t)(bits >> 16);
            hSl[wb][addr] = (ushort_t)(f2u(hn[r] - hi_f) >> 16);
        }

        float pr[4];
        #pragma unroll
        for (int r = 0; r < 4; r++) pr[r] = hn[r] * pwv;
        #pragma unroll
        for (int r = 0; r < 4; r++) {
            #pragma unroll
            for (int m = 1; m < 16; m <<= 1)
                pr[r] += __shfl_xor(pr[r], m, 16);
        }
        if (l15 == 0) {
            #pragma unroll
            for (int r = 0; r < 4; r++)
                wP[wb][4 * quad + r][w] = pr[r];
        }

        #pragma unroll
        for (int r = 0; r < 4; r++) hprev[r] = hn[r];
    }

    __syncthreads();
    #pragma unroll
    for (int r = 0; r < 4; r++) {   // fold final step (t=126 wrote wP[1])
        f32x4 v0 = *(const f32x4*)&wP[1][4 * quad + r][0];
        f32x4 v1 = *(const f32x4*)&wP[1][4 * quad + r][4];
        float s_b = v0.x + v0.y + v0.z + v0.w + v1.x + v1.y + v1.z + v1.w + pb_r;
        float mnew = fmaxf(mR[r], s_b);
        float sc = __expf(mR[r] - mnew);
        float e  = __expf(s_b - mnew);
        lR[r] = lR[r] * sc + e;
        Cacc[r] = Cacc[r] * sc + e * hprev[r];
    }
    #pragma unroll
    for (int r = 0; r < 4; r++)
        Cout[(b0 + 4 * quad + r) * (NV * DD) + n * DD + d_own] = Cacc[r] / lR[r];
}

// ---------------- QKV projection ----------------
__global__ __launch_bounds__(128) void qkv_kernel(
    const float* __restrict__ C, const float* __restrict__ P,
    float* __restrict__ q, float* __restrict__ k, float* __restrict__ v)
{
    int b = blockIdx.x, p = blockIdx.y, j = threadIdx.x;
    __shared__ float Cb[NV * DD];
    for (int i = j; i < NV * DD; i += 128) Cb[i] = C[b * (NV * DD) + i];
    __syncthreads();

    const float* wrow = P + OFF_INW + (p * DD + j) * DD;
    float bias = P[OFF_INB + p * DD + j];
    float acc[NV];
    #pragma unroll
    for (int nn = 0; nn < NV; nn++) acc[nn] = bias;

    for (int dc = 0; dc < DD; dc += 8) {
        float4 w0 = *(const float4*)&wrow[dc];
        float4 w1 = *(const float4*)&wrow[dc + 4];
        #pragma unroll
        for (int nn = 0; nn < NV; nn++) {
            float4 c0 = *(float4*)&Cb[nn * DD + dc];
            float4 c1 = *(float4*)&Cb[nn * DD + dc + 4];
            acc[nn] += c0.x * w0.x + c0.y * w0.y + c0.z * w0.z + c0.w * w0.w
                     + c1.x * w1.x + c1.y * w1.y + c1.z * w1.z + c1.w * w1.w;
        }
    }
    float* dst = (p == 0) ? q : (p == 1) ? k : v;
    for (int nn = 0; nn < NV; nn++) dst[b * (NV * DD) + nn * DD + j] = acc[nn];
}

// ---------------- cross-attention + out-proj + residual ----------------
__global__ __launch_bounds__(256) void attn_kernel(
    const float* __restrict__ q, const float* __restrict__ k, const float* __restrict__ v,
    const float* __restrict__ C, const float* __restrict__ P,
    const int* __restrict__ flags, float* __restrict__ Cstar, void* __restrict__ dout)
{
    int b = blockIdx.x, tid = threadIdx.x;
    int obf = flags[0];
    __shared__ float Qs[NV * DD], Ks[NV * DD], Vs[NV * DD];
    float* Os = Ks;
    for (int i = tid; i < NV * DD; i += 256) Qs[i] = q[b * (NV * DD) + i];
    __syncthreads();

    int hh = tid >> 5, qi = tid & 31;
    float qreg[16];
    #pragma unroll
    for (int u = 0; u < 4; u++) {
        float4 t4 = *(float4*)&Qs[qi * DD + hh * 16 + 4 * u];
        qreg[4*u] = t4.x; qreg[4*u+1] = t4.y; qreg[4*u+2] = t4.z; qreg[4*u+3] = t4.w;
    }

    float Oacc[16];
    #pragma unroll
    for (int u = 0; u < 16; u++) Oacc[u] = 0.f;
    float wsum = 0.f;
    int tmax = (b < 5) ? b : 5;

    for (int tau = 1; tau <= tmax; tau++) {
        __syncthreads();
        for (int i = tid; i < NV * DD; i += 256) {
            Ks[i] = k[(b - tau) * (NV * DD) + i];
            Vs[i] = v[(b - tau) * (NV * DD) + i];
        }
        __syncthreads();

        float s[NV];
        #pragma unroll
        for (int kk = 0; kk < NV; kk++) {
            float a = 0.f;
            #pragma unroll
            for (int u = 0; u < 4; u++) {
                float4 kv = *(float4*)&Ks[kk * DD + hh * 16 + 4 * u];
                a += qreg[4*u] * kv.x + qreg[4*u+1] * kv.y
                   + qreg[4*u+2] * kv.z + qreg[4*u+3] * kv.w;
            }
            s[kk] = a * 0.25f;
        }
        float mm = s[0];
        #pragma unroll
        for (int kk = 1; kk < NV; kk++) mm = fmaxf(mm, s[kk]);
        float ssum = 0.f;
        #pragma unroll
        for (int kk = 0; kk < NV; kk++) { s[kk] = __expf(s[kk] - mm); ssum += s[kk]; }
        float wdk = __expf(-0.7f * (float)(tau - 1));
        wsum += wdk;
        float wr = wdk / ssum;
        #pragma unroll
        for (int u = 0; u < 4; u++) {
            float ax = 0.f, ay = 0.f, az = 0.f, aw = 0.f;
            #pragma unroll
            for (int kk = 0; kk < NV; kk++) {
                float4 vv = *(float4*)&Vs[kk * DD + hh * 16 + 4 * u];
                ax += s[kk] * vv.x; ay += s[kk] * vv.y;
                az += s[kk] * vv.z; aw += s[kk] * vv.w;
            }
            Oacc[4*u] += wr * ax; Oacc[4*u+1] += wr * ay;
            Oacc[4*u+2] += wr * az; Oacc[4*u+3] += wr * aw;
        }
    }

    __syncthreads();
    float winv = (b > 0) ? 1.f / wsum : 0.f;
    #pragma unroll
    for (int u = 0; u < 16; u++)
        Os[qi * DD + hh * 16 + u] = Oacc[u] * winv;
    __syncthreads();

    int j = tid & 127, ng = tid >> 7;
    const float* wrow = P + OFF_OUTW + j * DD;
    float obias = P[OFF_OUTB + j];
    for (int nn = ng * 16; nn < ng * 16 + 16; nn++) {
        float a = (b > 0) ? obias : 0.f;
        for (int dc = 0; dc < DD; dc += 8) {
            float4 w0 = *(const float4*)&wrow[dc];
            float4 w1 = *(const float4*)&wrow[dc + 4];
            float4 o0 = *(float4*)&Os[nn * DD + dc];
            float4 o1 = *(float4*)&Os[nn * DD + dc + 4];
            a += o0.x*w0.x + o0.y*w0.y + o0.z*w0.z + o0.w*w0.w
               + o1.x*w1.x + o1.y*w1.y + o1.z*w1.z + o1.w*w1.w;
        }
        float cs = C[b * (NV * DD) + nn * DD + j] + a;
        Cstar[b * (NV * DD) + nn * DD + j] = cs;
        store_out(dout, 524288 + b * (NV * DD) + nn * DD + j, cs, obf);
    }
}

// ---------------- decoder init ----------------
__global__ __launch_bounds__(256) void dec_init(
    const float* __restrict__ Cstar,
    const void* __restrict__ iHw, const void* __restrict__ iCw,
    const int* __restrict__ flags, const float* __restrict__ P,
    float* __restrict__ h0, float* __restrict__ c0)
{
    int b = blockIdx.x, nn = blockIdx.y, tid = threadIdx.x;
    __shared__ float cs[DD];
    if (tid < DD) cs[tid] = Cstar[b * (NV * DD) + nn * DD + tid];
    __syncthreads();
    int e = tid & 127, mat = tid >> 7;
    const void* Wp = mat ? iCw : iHw;
    int wf = flags[mat ? 12 : 10];
    float acc = P[(mat ? OFF_ICB : OFF_IHB) + nn * DD + e];
    if (wf) {
        const uint_t* wrow = (const uint_t*)Wp + (((nn * DD + e) * DD) >> 1);
        for (int dc = 0; dc < DD; dc += 8) {
            float wf8[8];
            #pragma unroll
            for (int u = 0; u < 4; u++) {
                uint_t x = wrow[dc / 2 + u];
                wf8[2*u] = bflo(x); wf8[2*u+1] = bfhi(x);
            }
            float4 c0v = *(float4*)&cs[dc];
            float4 c1v = *(float4*)&cs[dc + 4];
            acc += c0v.x*wf8[0] + c0v.y*wf8[1] + c0v.z*wf8[2] + c0v.w*wf8[3]
                 + c1v.x*wf8[4] + c1v.y*wf8[5] + c1v.z*wf8[6] + c1v.w*wf8[7];
        }
    } else {
        const float* wrow = (const float*)Wp + (nn * DD + e) * DD;
        for (int dc = 0; dc < DD; dc += 8) {
            float4 w0 = *(const float4*)&wrow[dc];
            float4 w1 = *(const float4*)&wrow[dc + 4];
            float4 c0v = *(float4*)&cs[dc];
            float4 c1v = *(float4*)&cs[dc + 4];
            acc += c0v.x*w0.x + c0v.y*w0.y + c0v.z*w0.z + c0v.w*w0.w
                 + c1v.x*w1.x + c1v.y*w1.y + c1v.z*w1.z + c1v.w*w1.w;
        }
    }
    (mat ? c0 : h0)[(nn * NB + b) * DD + e] = tanh_f(acc);
}

// ===================== decoder: 8-wave MFMA recurrence -> recon/pred =====================
__global__ __launch_bounds__(512, 2) void dec_kernel(
    const float* __restrict__ h0, const float* __restrict__ c0,
    const void* __restrict__ Wraw, const int* __restrict__ flags,
    const float* __restrict__ P, void* __restrict__ out)
{
    const int n = blockIdx.y, b0 = blockIdx.x * BT;
    const int tid = threadIdx.x;
    const int w = tid >> 6, lane = tid & 63;
    const int l15 = lane & 15, quad = lane >> 4;
    const int wbf = flags[14], obf = flags[0];
    const int d_own = 16 * w + l15;

    __shared__ alignas(16) ushort_t hSh[2][16 * 136];
    __shared__ alignas(16) ushort_t hSl[2][16 * 136];
    __shared__ alignas(16) float wP[2][16][8];

    bf16x8 bfrag[4][4];
    #pragma unroll
    for (int typ = 0; typ < 4; typ++) {
        const int g = typ * 128 + d_own;
        #pragma unroll
        for (int kc = 0; kc < 4; kc++) {
            const int base = (n * G4 + g) * DD + 32 * kc + 8 * quad;
            if (wbf) {
                bfrag[typ][kc] = *(const bf16x8*)((const ushort_t*)Wraw + base);
            } else {
                const float* fp = (const float*)Wraw + base;
                bf16x8 tmp;
                #pragma unroll
                for (int j = 0; j < 8; j++) tmp[j] = (short)f2bf(fp[j]);
                bfrag[typ][kc] = tmp;
            }
        }
    }

    float bias[4];
    #pragma unroll
    for (int typ = 0; typ < 4; typ++) {
        int g = n * G4 + typ * 128 + d_own;
        bias[typ] = P[OFF_DBIH + g] + P[OFF_DBHH + g];
    }
    const float owv  = P[OFF_DOW + n * DD + d_own];
    const float ob_r = P[OFF_DOB + n];

    float cst[4];
    #pragma unroll
    for (int r = 0; r < 4; r++) {
        int b = b0 + 4 * quad + r;
        float hv = h0[(n * NB + b) * DD + d_own];
        cst[r]   = c0[(n * NB + b) * DD + d_own];
        uint_t bits = f2u(hv);
        float hi_f = u2f(bits & 0xffff0000u);
        int addr = (4 * quad + r) * 136 + d_own;
        hSh[0][addr] = (ushort_t)(bits >> 16);
        hSl[0][addr] = (ushort_t)(f2u(hv - hi_f) >> 16);
    }

    for (int t = 0; t < 128; t++) {
        const int rb = t & 1, wb = rb ^ 1;
        __syncthreads();

        bf16x8 ah[4], al[4];
        #pragma unroll
        for (int kc = 0; kc < 4; kc++) {
            ah[kc] = *(const bf16x8*)&hSh[rb][l15 * 136 + 32 * kc + 8 * quad];
            al[kc] = *(const bf16x8*)&hSl[rb][l15 * 136 + 32 * kc + 8 * quad];
        }

        f32x4 acc[4];
        #pragma unroll
        for (int typ = 0; typ < 4; typ++) {
            f32x4 a;
            a.x = bias[typ]; a.y = bias[typ]; a.z = bias[typ]; a.w = bias[typ];
            acc[typ] = a;
        }

        if (t > 0 && w == 0 && l15 == 0) {   // emit o(t-1)
            #pragma unroll
            for (int r = 0; r < 4; r++) {
                f32x4 v0 = *(const f32x4*)&wP[rb][4 * quad + r][0];
                f32x4 v1 = *(const f32x4*)&wP[rb][4 * quad + r][4];
                float o = v0.x + v0.y + v0.z + v0.w + v1.x + v1.y + v1.z + v1.w + ob_r;
                long b = b0 + 4 * quad + r;
                store_out(out, b * 4064 + (long)(t - 1) * NV + n, o, obf);
            }
        }

        #pragma unroll
        for (int kc = 0; kc < 4; kc++)
            #pragma unroll
            for (int typ = 0; typ < 4; typ++) {
                acc[typ] = __builtin_amdgcn_mfma_f32_16x16x32_bf16(al[kc], bfrag[typ][kc], acc[typ], 0, 0, 0);
                acc[typ] = __builtin_amdgcn_mfma_f32_16x16x32_bf16(ah[kc], bfrag[typ][kc], acc[typ], 0, 0, 0);
            }

        float hn[4];
        #pragma unroll
        for (int r = 0; r < 4; r++) {
            float ii = sigmoid_f(acc[0][r]);
            float ff = sigmoid_f(acc[1][r]);
            float g2 = tanh_f(acc[2][r]);
            float oo = sigmoid_f(acc[3][r]);
            float cc = ff * cst[r] + ii * g2;
            cst[r] = cc;
            hn[r] = oo * tanh_f(cc);
        }

        #pragma unroll
        for (int r = 0; r < 4; r++) {
            uint_t bits = f2u(hn[r]);
            float hi_f = u2f(bits & 0xffff0000u);
            int addr = (4 * quad + r) * 136 + d_own;
            hSh[wb][addr] = (ushort_t)(bits >> 16);
            hSl[wb][addr] = (ushort_t)(f2u(hn[r] - hi_f) >> 16);
        }

        float pr[4];
        #pragma unroll
        for (int r = 0; r < 4; r++) pr[r] = hn[r] * owv;
        #pragma unroll
        for (int r = 0; r < 4; r++) {
            #pragma unroll
            for (int m = 1; m < 16; m <<= 1)
                pr[r] += __shfl_xor(pr[r], m, 16);
        }
        if (l15 == 0) {
            #pragma unroll
            for (int r = 0; r < 4; r++)
                wP[wb][4 * quad + r][w] = pr[r];
        }
    }

    __syncthreads();
    if (w == 0 && l15 == 0) {   // emit pred o(127); t=127 wrote wP[0]
        #pragma unroll
        for (int r = 0; r < 4; r++) {
            f32x4 v0 = *(const f32x4*)&wP[0][4 * quad + r][0];
            f32x4 v1 = *(const f32x4*)&wP[0][4 * quad + r][4];
            float o = v0.x + v0.y + v0.z + v0.w + v1.x + v1.y + v1.z + v1.w + ob_r;
            long b = b0 + 4 * quad + r;
            store_out(out, 520192 + b * NV + n, o, obf);
        }
    }
}

extern "C" void kernel_launch(void* const* d_in, const int* in_sizes, int n_in,
                              void* d_out, int out_size, void* d_ws, size_t ws_size,
                              hipStream_t stream) {
    char* ws = (char*)d_ws;
    float*    P    = (float*)(ws + 0);              // 592 KB
    ushort_t* Xc   = (ushort_t*)(ws + (1u << 20));  // 1 MB
    float*    C    = (float*)(ws + (2u << 20));     // 2 MB
    float*    qb   = (float*)(ws + (4u << 20));
    float*    kb   = (float*)(ws + (6u << 20));
    float*    vb   = (float*)(ws + (8u << 20));
    float*    Cst  = (float*)(ws + (10u << 20));
    float*    h0   = (float*)(ws + (12u << 20));
    float*    c0   = (float*)(ws + (14u << 20));
    int*      flags = (int*)(ws + (16u << 20));

    Ptr19 a;
    for (int i = 0; i < 19; i++) { a.p[i] = d_in[i]; a.e[i] = in_sizes[i]; }
    probe_kernel<<<19, 64, 0, stream>>>(a, flags);
    conv_merged<<<(P_TOTAL + 255) / 256, 256, 0, stream>>>(a, flags, P);
    conv_X<<<(NB * 128 * NV + 255) / 256, 256, 0, stream>>>(d_in[0], flags, Xc);

    enc_kernel<<<dim3(8, 32), 512, 0, stream>>>(Xc, d_in[2], flags, P, C);
    qkv_kernel<<<dim3(128, 3), 128, 0, stream>>>(C, P, qb, kb, vb);
    attn_kernel<<<dim3(128), 256, 0, stream>>>(qb, kb, vb, C, P, flags, Cst, d_out);
    dec_init<<<dim3(128, 32), 256, 0, stream>>>(Cst, d_in[10], d_in[12], flags, P, h0, c0);
    dec_kernel<<<dim3(8, 32), 512, 0, stream>>>(h0, c0, d_in[14], flags, P, d_out);
}

// Round 5
// 777.914 us; speedup vs baseline: 11.7476x; 1.0759x over previous
//
#include <hip/hip_runtime.h>
#include <hip/hip_bf16.h>

typedef unsigned short ushort_t;
typedef unsigned int uint_t;

#define DD   128
#define G4   512
#define BT   16
#define NB   128
#define NV   32

// param block offsets (floats)
#define OFF_WIH   0
#define OFF_EB    16384
#define OFF_PW    32768
#define OFF_PB    36864
#define OFF_INW   36896
#define OFF_INB   86048
#define OFF_OUTW  86432
#define OFF_OUTB  102816
#define OFF_IHB   102944
#define OFF_ICB   107040
#define OFF_DBIH  111136
#define OFF_DBHH  127520
#define OFF_DOW   143904
#define OFF_DOB   148000
#define P_TOTAL   148032

typedef __attribute__((ext_vector_type(8))) short bf16x8;
typedef __attribute__((ext_vector_type(4))) float f32x4;

__device__ __forceinline__ float bf2f(ushort_t u) {
    union { uint_t i; float f; } x; x.i = ((uint_t)u) << 16; return x.f;
}
__device__ __forceinline__ float bflo(uint_t u) {
    union { uint_t i; float f; } x; x.i = u << 16; return x.f;
}
__device__ __forceinline__ float bfhi(uint_t u) {
    union { uint_t i; float f; } x; x.i = u & 0xffff0000u; return x.f;
}
__device__ __forceinline__ ushort_t f2bf(float f) {
    __hip_bfloat16 h = __float2bfloat16(f);
    return *(ushort_t*)&h;
}
__device__ __forceinline__ uint_t f2u(float f) {
    union { float f; uint_t i; } x; x.f = f; return x.i;
}
__device__ __forceinline__ float u2f(uint_t u) {
    union { uint_t i; float f; } x; x.i = u; return x.f;
}
__device__ __forceinline__ float sigmoid_f(float x) {
    return 1.f / (1.f + __expf(-x));
}
__device__ __forceinline__ float tanh_f(float x) {
    float e = __expf(2.f * x);
    return 1.f - 2.f / (e + 1.f);
}
__device__ __forceinline__ float swz_bcast16(float v) {
    // every lane reads lane (lane & 0x10) within its 32-lane group -> broadcast l15==0 of each quad-pair... 
    // BitMode offset = and=0x10: new_lane = lane & 0x10 (bits 0-3 zeroed, bit4 kept)
    return u2f((uint_t)__builtin_amdgcn_ds_swizzle((int)f2u(v), 0x0010));
}
__device__ __forceinline__ void store_out(void* out, long idx, float v, int bf) {
    if (bf) ((ushort_t*)out)[idx] = f2bf(v);
    else    ((float*)out)[idx]    = v;
}

// ---------------- dtype probe (one block per input) ----------------
struct Ptr19 { const void* p[19]; int e[19]; };

__global__ __launch_bounds__(64) void probe_kernel(Ptr19 a, int* __restrict__ flags) {
    int i = blockIdx.x;
    int t = threadIdx.x;
    int cap = a.e[i] < 2048 ? a.e[i] : 2048;
    int cnt = 0, tot = 0;
    const ushort_t* p = (const ushort_t*)a.p[i];
    for (int j = t; j < cap; j += 64) {
        ushort_t u = p[j];
        float af = fabsf(bf2f(u));
        tot++;
        if (u == 0 || (af > 1e-7f && af < 100.f)) cnt++;
    }
    #pragma unroll
    for (int off = 32; off >= 1; off >>= 1) {
        cnt += __shfl_xor(cnt, off);
        tot += __shfl_xor(tot, off);
    }
    if (t == 0) flags[i] = (cnt * 10 >= tot * 9) ? 1 : 0;
}

// ---------------- merged param canonicalizer -> fp32 block P ----------------
__global__ __launch_bounds__(256) void conv_merged(Ptr19 a, const int* __restrict__ flags,
                                                   float* __restrict__ P) {
    int i = blockIdx.x * 256 + threadIdx.x;
    if (i >= P_TOTAL) return;
    int src, off;
    if      (i < OFF_EB)   { src = 1;  off = i - OFF_WIH; }
    else if (i < OFF_PW)   { src = 3;  off = i - OFF_EB; }
    else if (i < OFF_PB)   { src = 4;  off = i - OFF_PW; }
    else if (i < OFF_INW)  { src = 5;  off = i - OFF_PB; }
    else if (i < OFF_INB)  { src = 6;  off = i - OFF_INW; }
    else if (i < OFF_OUTW) { src = 7;  off = i - OFF_INB; }
    else if (i < OFF_OUTB) { src = 8;  off = i - OFF_OUTW; }
    else if (i < OFF_IHB)  { src = 9;  off = i - OFF_OUTB; }
    else if (i < OFF_ICB)  { src = 11; off = i - OFF_IHB; }
    else if (i < OFF_DBIH) { src = 13; off = i - OFF_ICB; }
    else if (i < OFF_DBHH) { src = 15; off = i - OFF_DBIH; }
    else if (i < OFF_DOW)  { src = 16; off = i - OFF_DBHH; }
    else if (i < OFF_DOB)  { src = 17; off = i - OFF_DOW; }
    else                   { src = 18; off = i - OFF_DOB; }
    int bf = flags[src];
    P[i] = bf ? bf2f(((const ushort_t*)a.p[src])[off]) : ((const float*)a.p[src])[off];
}

// ---------------- X transpose: (B,L,N) -> bf16 [t][n][b] ----------------
__global__ __launch_bounds__(256) void conv_X(const void* __restrict__ src,
                                              const int* __restrict__ flags,
                                              ushort_t* __restrict__ Xc) {
    int i = blockIdx.x * 256 + threadIdx.x;   // output index [t][n][b]
    if (i >= NB * 128 * NV) return;
    int b = i & 127, nn = (i >> 7) & 31, t = i >> 12;
    int si = b * 4096 + t * 32 + nn;
    int bf = flags[0];
    Xc[i] = bf ? ((const ushort_t*)src)[si] : f2bf(((const float*)src)[si]);
}

// ===================== encoder: 8-wave MFMA recurrence, MFMA pool score =====================
// grid (8, 32), 512 threads. Wave w owns d-slice [16w,16w+16); pool projection as 5th MFMA chain.
__global__ __launch_bounds__(512, 2) void enc_kernel(
    const ushort_t* __restrict__ Xc, const void* __restrict__ Wraw,
    const int* __restrict__ flags, const float* __restrict__ P,
    float* __restrict__ Cout)
{
    const int n = blockIdx.y, b0 = blockIdx.x * BT;
    const int tid = threadIdx.x;
    const int w = tid >> 6, lane = tid & 63;
    const int l15 = lane & 15, quad = lane >> 4;
    const int wbf = flags[2];
    const int d_own = 16 * w + l15;

    __shared__ alignas(16) ushort_t hSh[2][16 * 136];
    __shared__ alignas(16) ushort_t hSl[2][16 * 136];

    for (int i = tid; i < 16 * 136; i += 512) { hSh[0][i] = 0; hSl[0][i] = 0; }

    // B-fragments: bfrag[typ][kc]; lane holds B[k=32kc+8quad+j][g = typ*128 + d_own]
    bf16x8 bfrag[4][4];
    #pragma unroll
    for (int typ = 0; typ < 4; typ++) {
        const int g = typ * 128 + d_own;
        #pragma unroll
        for (int kc = 0; kc < 4; kc++) {
            const int base = (n * G4 + g) * DD + 32 * kc + 8 * quad;
            if (wbf) {
                bfrag[typ][kc] = *(const bf16x8*)((const ushort_t*)Wraw + base);
            } else {
                const float* fp = (const float*)Wraw + base;
                bf16x8 tmp;
                #pragma unroll
                for (int j = 0; j < 8; j++) tmp[j] = (short)f2bf(fp[j]);
                bfrag[typ][kc] = tmp;
            }
        }
    }

    // pool B-fragment: column 0 = pw[k], other columns 0
    bf16x8 pfrag[4];
    #pragma unroll
    for (int kc = 0; kc < 4; kc++) {
        bf16x8 tmp;
        #pragma unroll
        for (int j = 0; j < 8; j++)
            tmp[j] = (l15 == 0) ? (short)f2bf(P[OFF_PW + n * DD + 32 * kc + 8 * quad + j]) : (short)0;
        pfrag[kc] = tmp;
    }

    float bias[4], wih[4];
    #pragma unroll
    for (int typ = 0; typ < 4; typ++) {
        bias[typ] = P[OFF_EB  + n * G4 + typ * 128 + d_own];
        wih[typ]  = P[OFF_WIH + n * G4 + typ * 128 + d_own];
    }
    const float pb_r = P[OFF_PB + n];

    float cst[4], hprev[4], Cacc[4], mR[4], lR[4];
    #pragma unroll
    for (int r = 0; r < 4; r++) {
        cst[r] = 0.f; hprev[r] = 0.f; Cacc[r] = 0.f; mR[r] = -1e30f; lR[r] = 0.f;
    }

    ushort4 xu = *(const ushort4*)&Xc[n * 128 + b0 + 4 * quad];   // t = 0

    for (int t = 0; t < 127; t++) {
        const int rb = t & 1, wb = rb ^ 1;
        __syncthreads();

        bf16x8 ah[4], al[4];
        #pragma unroll
        for (int kc = 0; kc < 4; kc++) {
            ah[kc] = *(const bf16x8*)&hSh[rb][l15 * 136 + 32 * kc + 8 * quad];
            al[kc] = *(const bf16x8*)&hSl[rb][l15 * 136 + 32 * kc + 8 * quad];
        }

        float xq[4] = { bf2f(xu.x), bf2f(xu.y), bf2f(xu.z), bf2f(xu.w) };
        f32x4 acc[4], accP;
        #pragma unroll
        for (int typ = 0; typ < 4; typ++) {
            f32x4 a;
            a.x = bias[typ] + xq[0] * wih[typ];
            a.y = bias[typ] + xq[1] * wih[typ];
            a.z = bias[typ] + xq[2] * wih[typ];
            a.w = bias[typ] + xq[3] * wih[typ];
            acc[typ] = a;
        }
        accP.x = 0.f; accP.y = 0.f; accP.z = 0.f; accP.w = 0.f;

        if (t < 126)
            xu = *(const ushort4*)&Xc[(t + 1) * 4096 + n * 128 + b0 + 4 * quad];

        #pragma unroll
        for (int kc = 0; kc < 4; kc++) {
            #pragma unroll
            for (int typ = 0; typ < 4; typ++) {
                acc[typ] = __builtin_amdgcn_mfma_f32_16x16x32_bf16(al[kc], bfrag[typ][kc], acc[typ], 0, 0, 0);
                acc[typ] = __builtin_amdgcn_mfma_f32_16x16x32_bf16(ah[kc], bfrag[typ][kc], acc[typ], 0, 0, 0);
            }
            accP = __builtin_amdgcn_mfma_f32_16x16x32_bf16(al[kc], pfrag[kc], accP, 0, 0, 0);
            accP = __builtin_amdgcn_mfma_f32_16x16x32_bf16(ah[kc], pfrag[kc], accP, 0, 0, 0);
        }

        if (t > 0) {   // fold h_{t-1} with score s_{t-1} = accP (this step's A = h_{t-1})
            #pragma unroll
            for (int r = 0; r < 4; r++) {
                float s_b = swz_bcast16(accP[r]) + pb_r;
                float mnew = fmaxf(mR[r], s_b);
                float sc = __expf(mR[r] - mnew);
                float e  = __expf(s_b - mnew);
                lR[r] = lR[r] * sc + e;
                Cacc[r] = Cacc[r] * sc + e * hprev[r];
                mR[r] = mnew;
            }
        }

        float hn[4];
        #pragma unroll
        for (int r = 0; r < 4; r++) {
            float ii = sigmoid_f(acc[0][r]);
            float ff = sigmoid_f(acc[1][r]);
            float g2 = tanh_f(acc[2][r]);
            float oo = sigmoid_f(acc[3][r]);
            float cc = ff * cst[r] + ii * g2;
            cst[r] = cc;
            hn[r] = oo * tanh_f(cc);
        }

        #pragma unroll
        for (int r = 0; r < 4; r++) {   // truncation hi/lo split
            uint_t bits = f2u(hn[r]);
            float hi_f = u2f(bits & 0xffff0000u);
            int addr = (4 * quad + r) * 136 + d_own;
            hSh[wb][addr] = (ushort_t)(bits >> 16);
            hSl[wb][addr] = (ushort_t)(f2u(hn[r] - hi_f) >> 16);
        }

        #pragma unroll
        for (int r = 0; r < 4; r++) hprev[r] = hn[r];
    }

    // final fold: score for h_126 (in hS[1]) via pool MFMAs only
    __syncthreads();
    {
        f32x4 accP;
        accP.x = 0.f; accP.y = 0.f; accP.z = 0.f; accP.w = 0.f;
        #pragma unroll
        for (int kc = 0; kc < 4; kc++) {
            bf16x8 ah = *(const bf16x8*)&hSh[1][l15 * 136 + 32 * kc + 8 * quad];
            bf16x8 al = *(const bf16x8*)&hSl[1][l15 * 136 + 32 * kc + 8 * quad];
            accP = __builtin_amdgcn_mfma_f32_16x16x32_bf16(al, pfrag[kc], accP, 0, 0, 0);
            accP = __builtin_amdgcn_mfma_f32_16x16x32_bf16(ah, pfrag[kc], accP, 0, 0, 0);
        }
        #pragma unroll
        for (int r = 0; r < 4; r++) {
            float s_b = swz_bcast16(accP[r]) + pb_r;
            float mnew = fmaxf(mR[r], s_b);
            float sc = __expf(mR[r] - mnew);
            float e  = __expf(s_b - mnew);
            lR[r] = lR[r] * sc + e;
            Cacc[r] = Cacc[r] * sc + e * hprev[r];
        }
    }
    #pragma unroll
    for (int r = 0; r < 4; r++)
        Cout[(b0 + 4 * quad + r) * (NV * DD) + n * DD + d_own] = Cacc[r] / lR[r];
}

// ---------------- QKV projection ----------------
__global__ __launch_bounds__(128) void qkv_kernel(
    const float* __restrict__ C, const float* __restrict__ P,
    float* __restrict__ q, float* __restrict__ k, float* __restrict__ v)
{
    int b = blockIdx.x, p = blockIdx.y, j = threadIdx.x;
    __shared__ float Cb[NV * DD];
    for (int i = j; i < NV * DD; i += 128) Cb[i] = C[b * (NV * DD) + i];
    __syncthreads();

    const float* wrow = P + OFF_INW + (p * DD + j) * DD;
    float bias = P[OFF_INB + p * DD + j];
    float acc[NV];
    #pragma unroll
    for (int nn = 0; nn < NV; nn++) acc[nn] = bias;

    for (int dc = 0; dc < DD; dc += 8) {
        float4 w0 = *(const float4*)&wrow[dc];
        float4 w1 = *(const float4*)&wrow[dc + 4];
        #pragma unroll
        for (int nn = 0; nn < NV; nn++) {
            float4 c0 = *(float4*)&Cb[nn * DD + dc];
            float4 c1 = *(float4*)&Cb[nn * DD + dc + 4];
            acc[nn] += c0.x * w0.x + c0.y * w0.y + c0.z * w0.z + c0.w * w0.w
                     + c1.x * w1.x + c1.y * w1.y + c1.z * w1.z + c1.w * w1.w;
        }
    }
    float* dst = (p == 0) ? q : (p == 1) ? k : v;
    for (int nn = 0; nn < NV; nn++) dst[b * (NV * DD) + nn * DD + j] = acc[nn];
}

// ---------------- cross-attention + out-proj + residual ----------------
__global__ __launch_bounds__(256) void attn_kernel(
    const float* __restrict__ q, const float* __restrict__ k, const float* __restrict__ v,
    const float* __restrict__ C, const float* __restrict__ P,
    const int* __restrict__ flags, float* __restrict__ Cstar, void* __restrict__ dout)
{
    int b = blockIdx.x, tid = threadIdx.x;
    int obf = flags[0];
    __shared__ float Qs[NV * DD], Ks[NV * DD], Vs[NV * DD];
    float* Os = Ks;
    for (int i = tid; i < NV * DD; i += 256) Qs[i] = q[b * (NV * DD) + i];
    __syncthreads();

    int hh = tid >> 5, qi = tid & 31;
    float qreg[16];
    #pragma unroll
    for (int u = 0; u < 4; u++) {
        float4 t4 = *(float4*)&Qs[qi * DD + hh * 16 + 4 * u];
        qreg[4*u] = t4.x; qreg[4*u+1] = t4.y; qreg[4*u+2] = t4.z; qreg[4*u+3] = t4.w;
    }

    float Oacc[16];
    #pragma unroll
    for (int u = 0; u < 16; u++) Oacc[u] = 0.f;
    float wsum = 0.f;
    int tmax = (b < 5) ? b : 5;

    for (int tau = 1; tau <= tmax; tau++) {
        __syncthreads();
        for (int i = tid; i < NV * DD; i += 256) {
            Ks[i] = k[(b - tau) * (NV * DD) + i];
            Vs[i] = v[(b - tau) * (NV * DD) + i];
        }
        __syncthreads();

        float s[NV];
        #pragma unroll
        for (int kk = 0; kk < NV; kk++) {
            float a = 0.f;
            #pragma unroll
            for (int u = 0; u < 4; u++) {
                float4 kv = *(float4*)&Ks[kk * DD + hh * 16 + 4 * u];
                a += qreg[4*u] * kv.x + qreg[4*u+1] * kv.y
                   + qreg[4*u+2] * kv.z + qreg[4*u+3] * kv.w;
            }
            s[kk] = a * 0.25f;
        }
        float mm = s[0];
        #pragma unroll
        for (int kk = 1; kk < NV; kk++) mm = fmaxf(mm, s[kk]);
        float ssum = 0.f;
        #pragma unroll
        for (int kk = 0; kk < NV; kk++) { s[kk] = __expf(s[kk] - mm); ssum += s[kk]; }
        float wdk = __expf(-0.7f * (float)(tau - 1));
        wsum += wdk;
        float wr = wdk / ssum;
        #pragma unroll
        for (int u = 0; u < 4; u++) {
            float ax = 0.f, ay = 0.f, az = 0.f, aw = 0.f;
            #pragma unroll
            for (int kk = 0; kk < NV; kk++) {
                float4 vv = *(float4*)&Vs[kk * DD + hh * 16 + 4 * u];
                ax += s[kk] * vv.x; ay += s[kk] * vv.y;
                az += s[kk] * vv.z; aw += s[kk] * vv.w;
            }
            Oacc[4*u] += wr * ax; Oacc[4*u+1] += wr * ay;
            Oacc[4*u+2] += wr * az; Oacc[4*u+3] += wr * aw;
        }
    }

    __syncthreads();
    float winv = (b > 0) ? 1.f / wsum : 0.f;
    #pragma unroll
    for (int u = 0; u < 16; u++)
        Os[qi * DD + hh * 16 + u] = Oacc[u] * winv;
    __syncthreads();

    int j = tid & 127, ng = tid >> 7;
    const float* wrow = P + OFF_OUTW + j * DD;
    float obias = P[OFF_OUTB + j];
    for (int nn = ng * 16; nn < ng * 16 + 16; nn++) {
        float a = (b > 0) ? obias : 0.f;
        for (int dc = 0; dc < DD; dc += 8) {
            float4 w0 = *(const float4*)&wrow[dc];
            float4 w1 = *(const float4*)&wrow[dc + 4];
            float4 o0 = *(float4*)&Os[nn * DD + dc];
            float4 o1 = *(float4*)&Os[nn * DD + dc + 4];
            a += o0.x*w0.x + o0.y*w0.y + o0.z*w0.z + o0.w*w0.w
               + o1.x*w1.x + o1.y*w1.y + o1.z*w1.z + o1.w*w1.w;
        }
        float cs = C[b * (NV * DD) + nn * DD + j] + a;
        Cstar[b * (NV * DD) + nn * DD + j] = cs;
        store_out(dout, 524288 + b * (NV * DD) + nn * DD + j, cs, obf);
    }
}

// ---------------- decoder init ----------------
__global__ __launch_bounds__(256) void dec_init(
    const float* __restrict__ Cstar,
    const void* __restrict__ iHw, const void* __restrict__ iCw,
    const int* __restrict__ flags, const float* __restrict__ P,
    float* __restrict__ h0, float* __restrict__ c0)
{
    int b = blockIdx.x, nn = blockIdx.y, tid = threadIdx.x;
    __shared__ float cs[DD];
    if (tid < DD) cs[tid] = Cstar[b * (NV * DD) + nn * DD + tid];
    __syncthreads();
    int e = tid & 127, mat = tid >> 7;
    const void* Wp = mat ? iCw : iHw;
    int wf = flags[mat ? 12 : 10];
    float acc = P[(mat ? OFF_ICB : OFF_IHB) + nn * DD + e];
    if (wf) {
        const uint_t* wrow = (const uint_t*)Wp + (((nn * DD + e) * DD) >> 1);
        for (int dc = 0; dc < DD; dc += 8) {
            float wf8[8];
            #pragma unroll
            for (int u = 0; u < 4; u++) {
                uint_t x = wrow[dc / 2 + u];
                wf8[2*u] = bflo(x); wf8[2*u+1] = bfhi(x);
            }
            float4 c0v = *(float4*)&cs[dc];
            float4 c1v = *(float4*)&cs[dc + 4];
            acc += c0v.x*wf8[0] + c0v.y*wf8[1] + c0v.z*wf8[2] + c0v.w*wf8[3]
                 + c1v.x*wf8[4] + c1v.y*wf8[5] + c1v.z*wf8[6] + c1v.w*wf8[7];
        }
    } else {
        const float* wrow = (const float*)Wp + (nn * DD + e) * DD;
        for (int dc = 0; dc < DD; dc += 8) {
            float4 w0 = *(const float4*)&wrow[dc];
            float4 w1 = *(const float4*)&wrow[dc + 4];
            float4 c0v = *(float4*)&cs[dc];
            float4 c1v = *(float4*)&cs[dc + 4];
            acc += c0v.x*w0.x + c0v.y*w0.y + c0v.z*w0.z + c0v.w*w0.w
                 + c1v.x*w1.x + c1v.y*w1.y + c1v.z*w1.z + c1v.w*w1.w;
        }
    }
    (mat ? c0 : h0)[(nn * NB + b) * DD + e] = tanh_f(acc);
}

// ===================== decoder: 8-wave MFMA recurrence, MFMA output proj =====================
__global__ __launch_bounds__(512, 2) void dec_kernel(
    const float* __restrict__ h0, const float* __restrict__ c0,
    const void* __restrict__ Wraw, const int* __restrict__ flags,
    const float* __restrict__ P, void* __restrict__ out)
{
    const int n = blockIdx.y, b0 = blockIdx.x * BT;
    const int tid = threadIdx.x;
    const int w = tid >> 6, lane = tid & 63;
    const int l15 = lane & 15, quad = lane >> 4;
    const int wbf = flags[14], obf = flags[0];
    const int d_own = 16 * w + l15;

    __shared__ alignas(16) ushort_t hSh[2][16 * 136];
    __shared__ alignas(16) ushort_t hSl[2][16 * 136];

    bf16x8 bfrag[4][4];
    #pragma unroll
    for (int typ = 0; typ < 4; typ++) {
        const int g = typ * 128 + d_own;
        #pragma unroll
        for (int kc = 0; kc < 4; kc++) {
            const int base = (n * G4 + g) * DD + 32 * kc + 8 * quad;
            if (wbf) {
                bfrag[typ][kc] = *(const bf16x8*)((const ushort_t*)Wraw + base);
            } else {
                const float* fp = (const float*)Wraw + base;
                bf16x8 tmp;
                #pragma unroll
                for (int j = 0; j < 8; j++) tmp[j] = (short)f2bf(fp[j]);
                bfrag[typ][kc] = tmp;
            }
        }
    }

    // output-projection B-fragment: column 0 = ow[k]
    bf16x8 pfrag[4];
    #pragma unroll
    for (int kc = 0; kc < 4; kc++) {
        bf16x8 tmp;
        #pragma unroll
        for (int j = 0; j < 8; j++)
            tmp[j] = (l15 == 0) ? (short)f2bf(P[OFF_DOW + n * DD + 32 * kc + 8 * quad + j]) : (short)0;
        pfrag[kc] = tmp;
    }

    float bias[4];
    #pragma unroll
    for (int typ = 0; typ < 4; typ++) {
        int g = n * G4 + typ * 128 + d_own;
        bias[typ] = P[OFF_DBIH + g] + P[OFF_DBHH + g];
    }
    const float ob_r = P[OFF_DOB + n];

    float cst[4];
    #pragma unroll
    for (int r = 0; r < 4; r++) {
        int b = b0 + 4 * quad + r;
        float hv = h0[(n * NB + b) * DD + d_own];
        cst[r]   = c0[(n * NB + b) * DD + d_own];
        uint_t bits = f2u(hv);
        float hi_f = u2f(bits & 0xffff0000u);
        int addr = (4 * quad + r) * 136 + d_own;
        hSh[0][addr] = (ushort_t)(bits >> 16);
        hSl[0][addr] = (ushort_t)(f2u(hv - hi_f) >> 16);
    }

    for (int t = 0; t < 128; t++) {
        const int rb = t & 1, wb = rb ^ 1;
        __syncthreads();

        bf16x8 ah[4], al[4];
        #pragma unroll
        for (int kc = 0; kc < 4; kc++) {
            ah[kc] = *(const bf16x8*)&hSh[rb][l15 * 136 + 32 * kc + 8 * quad];
            al[kc] = *(const bf16x8*)&hSl[rb][l15 * 136 + 32 * kc + 8 * quad];
        }

        f32x4 acc[4], accP;
        #pragma unroll
        for (int typ = 0; typ < 4; typ++) {
            f32x4 a;
            a.x = bias[typ]; a.y = bias[typ]; a.z = bias[typ]; a.w = bias[typ];
            acc[typ] = a;
        }
        accP.x = 0.f; accP.y = 0.f; accP.z = 0.f; accP.w = 0.f;

        #pragma unroll
        for (int kc = 0; kc < 4; kc++) {
            #pragma unroll
            for (int typ = 0; typ < 4; typ++) {
                acc[typ] = __builtin_amdgcn_mfma_f32_16x16x32_bf16(al[kc], bfrag[typ][kc], acc[typ], 0, 0, 0);
                acc[typ] = __builtin_amdgcn_mfma_f32_16x16x32_bf16(ah[kc], bfrag[typ][kc], acc[typ], 0, 0, 0);
            }
            accP = __builtin_amdgcn_mfma_f32_16x16x32_bf16(al[kc], pfrag[kc], accP, 0, 0, 0);
            accP = __builtin_amdgcn_mfma_f32_16x16x32_bf16(ah[kc], pfrag[kc], accP, 0, 0, 0);
        }

        if (t > 0 && w == 0 && l15 == 0) {   // accP = o_{t-1} (A was h_{t-1}); store recon
            #pragma unroll
            for (int r = 0; r < 4; r++) {
                float o = accP[r] + ob_r;
                long b = b0 + 4 * quad + r;
                store_out(out, b * 4064 + (long)(t - 1) * NV + n, o, obf);
            }
        }

        float hn[4];
        #pragma unroll
        for (int r = 0; r < 4; r++) {
            float ii = sigmoid_f(acc[0][r]);
            float ff = sigmoid_f(acc[1][r]);
            float g2 = tanh_f(acc[2][r]);
            float oo = sigmoid_f(acc[3][r]);
            float cc = ff * cst[r] + ii * g2;
            cst[r] = cc;
            hn[r] = oo * tanh_f(cc);
        }

        #pragma unroll
        for (int r = 0; r < 4; r++) {
            uint_t bits = f2u(hn[r]);
            float hi_f = u2f(bits & 0xffff0000u);
            int addr = (4 * quad + r) * 136 + d_own;
            hSh[wb][addr] = (ushort_t)(bits >> 16);
            hSl[wb][addr] = (ushort_t)(f2u(hn[r] - hi_f) >> 16);
        }
    }

    // o_127 from h_127 (in hS[0]: t=127 -> wb=0)
    __syncthreads();
    if (w == 0) {
        f32x4 accP;
        accP.x = 0.f; accP.y = 0.f; accP.z = 0.f; accP.w = 0.f;
        #pragma unroll
        for (int kc = 0; kc < 4; kc++) {
            bf16x8 ah = *(const bf16x8*)&hSh[0][l15 * 136 + 32 * kc + 8 * quad];
            bf16x8 al = *(const bf16x8*)&hSl[0][l15 * 136 + 32 * kc + 8 * quad];
            accP = __builtin_amdgcn_mfma_f32_16x16x32_bf16(al, pfrag[kc], accP, 0, 0, 0);
            accP = __builtin_amdgcn_mfma_f32_16x16x32_bf16(ah, pfrag[kc], accP, 0, 0, 0);
        }
        if (l15 == 0) {
            #pragma unroll
            for (int r = 0; r < 4; r++) {
                float o = accP[r] + ob_r;
                long b = b0 + 4 * quad + r;
                store_out(out, 520192 + b * NV + n, o, obf);
            }
        }
    }
}

extern "C" void kernel_launch(void* const* d_in, const int* in_sizes, int n_in,
                              void* d_out, int out_size, void* d_ws, size_t ws_size,
                              hipStream_t stream) {
    char* ws = (char*)d_ws;
    float*    P    = (float*)(ws + 0);              // 592 KB
    ushort_t* Xc   = (ushort_t*)(ws + (1u << 20));  // 1 MB
    float*    C    = (float*)(ws + (2u << 20));     // 2 MB
    float*    qb   = (float*)(ws + (4u << 20));
    float*    kb   = (float*)(ws + (6u << 20));
    float*    vb   = (float*)(ws + (8u << 20));
    float*    Cst  = (float*)(ws + (10u << 20));
    float*    h0   = (float*)(ws + (12u << 20));
    float*    c0   = (float*)(ws + (14u << 20));
    int*      flags = (int*)(ws + (16u << 20));

    Ptr19 a;
    for (int i = 0; i < 19; i++) { a.p[i] = d_in[i]; a.e[i] = in_sizes[i]; }
    probe_kernel<<<19, 64, 0, stream>>>(a, flags);
    conv_merged<<<(P_TOTAL + 255) / 256, 256, 0, stream>>>(a, flags, P);
    conv_X<<<(NB * 128 * NV + 255) / 256, 256, 0, stream>>>(d_in[0], flags, Xc);

    enc_kernel<<<dim3(8, 32), 512, 0, stream>>>(Xc, d_in[2], flags, P, C);
    qkv_kernel<<<dim3(128, 3), 128, 0, stream>>>(C, P, qb, kb, vb);
    attn_kernel<<<dim3(128), 256, 0, stream>>>(qb, kb, vb, C, P, flags, Cst, d_out);
    dec_init<<<dim3(128, 32), 256, 0, stream>>>(Cst, d_in[10], d_in[12], flags, P, h0, c0);
    dec_kernel<<<dim3(8, 32), 512, 0, stream>>>(h0, c0, d_in[14], flags, P, d_out);
}

// Round 6
// 597.581 us; speedup vs baseline: 15.2927x; 1.3018x over previous
//
#include <hip/hip_runtime.h>
#include <hip/hip_bf16.h>

typedef unsigned short ushort_t;
typedef unsigned int uint_t;

#define DD   128
#define G4   512
#define BT   16
#define NB   128
#define NV   32

// param block offsets (floats)
#define OFF_WIH   0
#define OFF_EB    16384
#define OFF_PW    32768
#define OFF_PB    36864
#define OFF_INW   36896
#define OFF_INB   86048
#define OFF_OUTW  86432
#define OFF_OUTB  102816
#define OFF_IHB   102944
#define OFF_ICB   107040
#define OFF_DBIH  111136
#define OFF_DBHH  127520
#define OFF_DOW   143904
#define OFF_DOB   148000
#define P_TOTAL   148032

typedef __attribute__((ext_vector_type(8))) short bf16x8;
typedef __attribute__((ext_vector_type(4))) float f32x4;

__device__ __forceinline__ float bf2f(ushort_t u) {
    union { uint_t i; float f; } x; x.i = ((uint_t)u) << 16; return x.f;
}
__device__ __forceinline__ float bflo(uint_t u) {
    union { uint_t i; float f; } x; x.i = u << 16; return x.f;
}
__device__ __forceinline__ float bfhi(uint_t u) {
    union { uint_t i; float f; } x; x.i = u & 0xffff0000u; return x.f;
}
__device__ __forceinline__ ushort_t f2bf(float f) {
    __hip_bfloat16 h = __float2bfloat16(f);
    return *(ushort_t*)&h;
}
__device__ __forceinline__ uint_t f2u(float f) {
    union { float f; uint_t i; } x; x.f = f; return x.i;
}
__device__ __forceinline__ float u2f(uint_t u) {
    union { uint_t i; float f; } x; x.i = u; return x.f;
}
// rcp-based activations: v_rcp_f32 (~1ulp) instead of IEEE division (~9 inst)
__device__ __forceinline__ float sigmoid_f(float x) {
    return __builtin_amdgcn_rcpf(1.f + __expf(-x));
}
__device__ __forceinline__ float tanh_f(float x) {
    float e = __expf(2.f * x);
    return 1.f - 2.f * __builtin_amdgcn_rcpf(e + 1.f);
}
__device__ __forceinline__ float swz_bcast16(float v) {
    // BitMode offset and=0x10: new_lane = lane & 0x10 (per 32-lane half)
    return u2f((uint_t)__builtin_amdgcn_ds_swizzle((int)f2u(v), 0x0010));
}
__device__ __forceinline__ void store_out(void* out, long idx, float v, int bf) {
    if (bf) ((ushort_t*)out)[idx] = f2bf(v);
    else    ((float*)out)[idx]    = v;
}

// ---------------- dtype probe (one block per input) ----------------
struct Ptr19 { const void* p[19]; int e[19]; };

__global__ __launch_bounds__(64) void probe_kernel(Ptr19 a, int* __restrict__ flags) {
    int i = blockIdx.x;
    int t = threadIdx.x;
    int cap = a.e[i] < 2048 ? a.e[i] : 2048;
    int cnt = 0, tot = 0;
    const ushort_t* p = (const ushort_t*)a.p[i];
    for (int j = t; j < cap; j += 64) {
        ushort_t u = p[j];
        float af = fabsf(bf2f(u));
        tot++;
        if (u == 0 || (af > 1e-7f && af < 100.f)) cnt++;
    }
    #pragma unroll
    for (int off = 32; off >= 1; off >>= 1) {
        cnt += __shfl_xor(cnt, off);
        tot += __shfl_xor(tot, off);
    }
    if (t == 0) flags[i] = (cnt * 10 >= tot * 9) ? 1 : 0;
}

// ---------------- merged param canonicalizer -> fp32 block P ----------------
__global__ __launch_bounds__(256) void conv_merged(Ptr19 a, const int* __restrict__ flags,
                                                   float* __restrict__ P) {
    int i = blockIdx.x * 256 + threadIdx.x;
    if (i >= P_TOTAL) return;
    int src, off;
    if      (i < OFF_EB)   { src = 1;  off = i - OFF_WIH; }
    else if (i < OFF_PW)   { src = 3;  off = i - OFF_EB; }
    else if (i < OFF_PB)   { src = 4;  off = i - OFF_PW; }
    else if (i < OFF_INW)  { src = 5;  off = i - OFF_PB; }
    else if (i < OFF_INB)  { src = 6;  off = i - OFF_INW; }
    else if (i < OFF_OUTW) { src = 7;  off = i - OFF_INB; }
    else if (i < OFF_OUTB) { src = 8;  off = i - OFF_OUTW; }
    else if (i < OFF_IHB)  { src = 9;  off = i - OFF_OUTB; }
    else if (i < OFF_ICB)  { src = 11; off = i - OFF_IHB; }
    else if (i < OFF_DBIH) { src = 13; off = i - OFF_ICB; }
    else if (i < OFF_DBHH) { src = 15; off = i - OFF_DBIH; }
    else if (i < OFF_DOW)  { src = 16; off = i - OFF_DBHH; }
    else if (i < OFF_DOB)  { src = 17; off = i - OFF_DOW; }
    else                   { src = 18; off = i - OFF_DOB; }
    int bf = flags[src];
    P[i] = bf ? bf2f(((const ushort_t*)a.p[src])[off]) : ((const float*)a.p[src])[off];
}

// ---------------- X transpose: (B,L,N) -> bf16 [t][n][b] ----------------
__global__ __launch_bounds__(256) void conv_X(const void* __restrict__ src,
                                              const int* __restrict__ flags,
                                              ushort_t* __restrict__ Xc) {
    int i = blockIdx.x * 256 + threadIdx.x;   // output index [t][n][b]
    if (i >= NB * 128 * NV) return;
    int b = i & 127, nn = (i >> 7) & 31, t = i >> 12;
    int si = b * 4096 + t * 32 + nn;
    int bf = flags[0];
    Xc[i] = bf ? ((const ushort_t*)src)[si] : f2bf(((const float*)src)[si]);
}

// ===================== encoder: 8-wave MFMA recurrence, MFMA pool score =====================
// grid (8, 32), 512 threads. Wave w owns d-slice [16w,16w+16); pool projection as 5th MFMA chain.
// Pool softmax: un-normalized exp accumulation (scores bounded |s|<~13 -> fp32 safe).
__global__ __launch_bounds__(512, 2) void enc_kernel(
    const ushort_t* __restrict__ Xc, const void* __restrict__ Wraw,
    const int* __restrict__ flags, const float* __restrict__ P,
    float* __restrict__ Cout)
{
    const int n = blockIdx.y, b0 = blockIdx.x * BT;
    const int tid = threadIdx.x;
    const int w = tid >> 6, lane = tid & 63;
    const int l15 = lane & 15, quad = lane >> 4;
    const int wbf = flags[2];
    const int d_own = 16 * w + l15;

    __shared__ alignas(16) ushort_t hSh[2][16 * 136];
    __shared__ alignas(16) ushort_t hSl[2][16 * 136];

    for (int i = tid; i < 16 * 136; i += 512) { hSh[0][i] = 0; hSl[0][i] = 0; }

    // B-fragments: bfrag[typ][kc]; lane holds B[k=32kc+8quad+j][g = typ*128 + d_own]
    bf16x8 bfrag[4][4];
    #pragma unroll
    for (int typ = 0; typ < 4; typ++) {
        const int g = typ * 128 + d_own;
        #pragma unroll
        for (int kc = 0; kc < 4; kc++) {
            const int base = (n * G4 + g) * DD + 32 * kc + 8 * quad;
            if (wbf) {
                bfrag[typ][kc] = *(const bf16x8*)((const ushort_t*)Wraw + base);
            } else {
                const float* fp = (const float*)Wraw + base;
                bf16x8 tmp;
                #pragma unroll
                for (int j = 0; j < 8; j++) tmp[j] = (short)f2bf(fp[j]);
                bfrag[typ][kc] = tmp;
            }
        }
    }

    // pool B-fragment: column 0 = pw[k], other columns 0
    bf16x8 pfrag[4];
    #pragma unroll
    for (int kc = 0; kc < 4; kc++) {
        bf16x8 tmp;
        #pragma unroll
        for (int j = 0; j < 8; j++)
            tmp[j] = (l15 == 0) ? (short)f2bf(P[OFF_PW + n * DD + 32 * kc + 8 * quad + j]) : (short)0;
        pfrag[kc] = tmp;
    }

    float bias[4], wih[4];
    #pragma unroll
    for (int typ = 0; typ < 4; typ++) {
        bias[typ] = P[OFF_EB  + n * G4 + typ * 128 + d_own];
        wih[typ]  = P[OFF_WIH + n * G4 + typ * 128 + d_own];
    }
    const float pb_r = P[OFF_PB + n];

    float cst[4], hprev[4], Cacc[4], lR[4];
    #pragma unroll
    for (int r = 0; r < 4; r++) {
        cst[r] = 0.f; hprev[r] = 0.f; Cacc[r] = 0.f; lR[r] = 0.f;
    }

    ushort4 xu = *(const ushort4*)&Xc[n * 128 + b0 + 4 * quad];   // t = 0

    for (int t = 0; t < 127; t++) {
        const int rb = t & 1, wb = rb ^ 1;
        __syncthreads();

        bf16x8 ah[4], al[4];
        #pragma unroll
        for (int kc = 0; kc < 4; kc++) {
            ah[kc] = *(const bf16x8*)&hSh[rb][l15 * 136 + 32 * kc + 8 * quad];
            al[kc] = *(const bf16x8*)&hSl[rb][l15 * 136 + 32 * kc + 8 * quad];
        }

        float xq[4] = { bf2f(xu.x), bf2f(xu.y), bf2f(xu.z), bf2f(xu.w) };
        f32x4 acc[4], accP;
        #pragma unroll
        for (int typ = 0; typ < 4; typ++) {
            f32x4 a;
            a.x = bias[typ] + xq[0] * wih[typ];
            a.y = bias[typ] + xq[1] * wih[typ];
            a.z = bias[typ] + xq[2] * wih[typ];
            a.w = bias[typ] + xq[3] * wih[typ];
            acc[typ] = a;
        }
        accP.x = 0.f; accP.y = 0.f; accP.z = 0.f; accP.w = 0.f;

        if (t < 126)
            xu = *(const ushort4*)&Xc[(t + 1) * 4096 + n * 128 + b0 + 4 * quad];

        #pragma unroll
        for (int kc = 0; kc < 4; kc++) {
            #pragma unroll
            for (int typ = 0; typ < 4; typ++) {
                acc[typ] = __builtin_amdgcn_mfma_f32_16x16x32_bf16(al[kc], bfrag[typ][kc], acc[typ], 0, 0, 0);
                acc[typ] = __builtin_amdgcn_mfma_f32_16x16x32_bf16(ah[kc], bfrag[typ][kc], acc[typ], 0, 0, 0);
            }
            accP = __builtin_amdgcn_mfma_f32_16x16x32_bf16(al[kc], pfrag[kc], accP, 0, 0, 0);
            accP = __builtin_amdgcn_mfma_f32_16x16x32_bf16(ah[kc], pfrag[kc], accP, 0, 0, 0);
        }

        if (t > 0) {   // fold h_{t-1}: e = exp(s_{t-1}), un-normalized accumulate
            #pragma unroll
            for (int r = 0; r < 4; r++) {
                float e = __expf(swz_bcast16(accP[r]) + pb_r);
                lR[r] += e;
                Cacc[r] = fmaf(e, hprev[r], Cacc[r]);
            }
        }

        float hn[4];
        #pragma unroll
        for (int r = 0; r < 4; r++) {
            float ii = sigmoid_f(acc[0][r]);
            float ff = sigmoid_f(acc[1][r]);
            float g2 = tanh_f(acc[2][r]);
            float oo = sigmoid_f(acc[3][r]);
            float cc = ff * cst[r] + ii * g2;
            cst[r] = cc;
            hn[r] = oo * tanh_f(cc);
        }

        #pragma unroll
        for (int r = 0; r < 4; r++) {   // truncation hi/lo split
            uint_t bits = f2u(hn[r]);
            float hi_f = u2f(bits & 0xffff0000u);
            int addr = (4 * quad + r) * 136 + d_own;
            hSh[wb][addr] = (ushort_t)(bits >> 16);
            hSl[wb][addr] = (ushort_t)(f2u(hn[r] - hi_f) >> 16);
        }

        #pragma unroll
        for (int r = 0; r < 4; r++) hprev[r] = hn[r];
    }

    // final fold: score for h_126 (in hS[1]) via pool MFMAs only
    __syncthreads();
    {
        f32x4 accP;
        accP.x = 0.f; accP.y = 0.f; accP.z = 0.f; accP.w = 0.f;
        #pragma unroll
        for (int kc = 0; kc < 4; kc++) {
            bf16x8 ah = *(const bf16x8*)&hSh[1][l15 * 136 + 32 * kc + 8 * quad];
            bf16x8 al = *(const bf16x8*)&hSl[1][l15 * 136 + 32 * kc + 8 * quad];
            accP = __builtin_amdgcn_mfma_f32_16x16x32_bf16(al, pfrag[kc], accP, 0, 0, 0);
            accP = __builtin_amdgcn_mfma_f32_16x16x32_bf16(ah, pfrag[kc], accP, 0, 0, 0);
        }
        #pragma unroll
        for (int r = 0; r < 4; r++) {
            float e = __expf(swz_bcast16(accP[r]) + pb_r);
            lR[r] += e;
            Cacc[r] = fmaf(e, hprev[r], Cacc[r]);
        }
    }
    #pragma unroll
    for (int r = 0; r < 4; r++)
        Cout[(b0 + 4 * quad + r) * (NV * DD) + n * DD + d_own] = Cacc[r] / lR[r];
}

// ---------------- QKV projection ----------------
__global__ __launch_bounds__(128) void qkv_kernel(
    const float* __restrict__ C, const float* __restrict__ P,
    float* __restrict__ q, float* __restrict__ k, float* __restrict__ v)
{
    int b = blockIdx.x, p = blockIdx.y, j = threadIdx.x;
    __shared__ float Cb[NV * DD];
    for (int i = j; i < NV * DD; i += 128) Cb[i] = C[b * (NV * DD) + i];
    __syncthreads();

    const float* wrow = P + OFF_INW + (p * DD + j) * DD;
    float bias = P[OFF_INB + p * DD + j];
    float acc[NV];
    #pragma unroll
    for (int nn = 0; nn < NV; nn++) acc[nn] = bias;

    for (int dc = 0; dc < DD; dc += 8) {
        float4 w0 = *(const float4*)&wrow[dc];
        float4 w1 = *(const float4*)&wrow[dc + 4];
        #pragma unroll
        for (int nn = 0; nn < NV; nn++) {
            float4 c0 = *(float4*)&Cb[nn * DD + dc];
            float4 c1 = *(float4*)&Cb[nn * DD + dc + 4];
            acc[nn] += c0.x * w0.x + c0.y * w0.y + c0.z * w0.z + c0.w * w0.w
                     + c1.x * w1.x + c1.y * w1.y + c1.z * w1.z + c1.w * w1.w;
        }
    }
    float* dst = (p == 0) ? q : (p == 1) ? k : v;
    for (int nn = 0; nn < NV; nn++) dst[b * (NV * DD) + nn * DD + j] = acc[nn];
}

// ---------------- cross-attention + out-proj + residual ----------------
__global__ __launch_bounds__(256) void attn_kernel(
    const float* __restrict__ q, const float* __restrict__ k, const float* __restrict__ v,
    const float* __restrict__ C, const float* __restrict__ P,
    const int* __restrict__ flags, float* __restrict__ Cstar, void* __restrict__ dout)
{
    int b = blockIdx.x, tid = threadIdx.x;
    int obf = flags[0];
    __shared__ float Qs[NV * DD], Ks[NV * DD], Vs[NV * DD];
    float* Os = Ks;
    for (int i = tid; i < NV * DD; i += 256) Qs[i] = q[b * (NV * DD) + i];
    __syncthreads();

    int hh = tid >> 5, qi = tid & 31;
    float qreg[16];
    #pragma unroll
    for (int u = 0; u < 4; u++) {
        float4 t4 = *(float4*)&Qs[qi * DD + hh * 16 + 4 * u];
        qreg[4*u] = t4.x; qreg[4*u+1] = t4.y; qreg[4*u+2] = t4.z; qreg[4*u+3] = t4.w;
    }

    float Oacc[16];
    #pragma unroll
    for (int u = 0; u < 16; u++) Oacc[u] = 0.f;
    float wsum = 0.f;
    int tmax = (b < 5) ? b : 5;

    for (int tau = 1; tau <= tmax; tau++) {
        __syncthreads();
        for (int i = tid; i < NV * DD; i += 256) {
            Ks[i] = k[(b - tau) * (NV * DD) + i];
            Vs[i] = v[(b - tau) * (NV * DD) + i];
        }
        __syncthreads();

        float s[NV];
        #pragma unroll
        for (int kk = 0; kk < NV; kk++) {
            float a = 0.f;
            #pragma unroll
            for (int u = 0; u < 4; u++) {
                float4 kv = *(float4*)&Ks[kk * DD + hh * 16 + 4 * u];
                a += qreg[4*u] * kv.x + qreg[4*u+1] * kv.y
                   + qreg[4*u+2] * kv.z + qreg[4*u+3] * kv.w;
            }
            s[kk] = a * 0.25f;
        }
        float mm = s[0];
        #pragma unroll
        for (int kk = 1; kk < NV; kk++) mm = fmaxf(mm, s[kk]);
        float ssum = 0.f;
        #pragma unroll
        for (int kk = 0; kk < NV; kk++) { s[kk] = __expf(s[kk] - mm); ssum += s[kk]; }
        float wdk = __expf(-0.7f * (float)(tau - 1));
        wsum += wdk;
        float wr = wdk / ssum;
        #pragma unroll
        for (int u = 0; u < 4; u++) {
            float ax = 0.f, ay = 0.f, az = 0.f, aw = 0.f;
            #pragma unroll
            for (int kk = 0; kk < NV; kk++) {
                float4 vv = *(float4*)&Vs[kk * DD + hh * 16 + 4 * u];
                ax += s[kk] * vv.x; ay += s[kk] * vv.y;
                az += s[kk] * vv.z; aw += s[kk] * vv.w;
            }
            Oacc[4*u] += wr * ax; Oacc[4*u+1] += wr * ay;
            Oacc[4*u+2] += wr * az; Oacc[4*u+3] += wr * aw;
        }
    }

    __syncthreads();
    float winv = (b > 0) ? 1.f / wsum : 0.f;
    #pragma unroll
    for (int u = 0; u < 16; u++)
        Os[qi * DD + hh * 16 + u] = Oacc[u] * winv;
    __syncthreads();

    int j = tid & 127, ng = tid >> 7;
    const float* wrow = P + OFF_OUTW + j * DD;
    float obias = P[OFF_OUTB + j];
    for (int nn = ng * 16; nn < ng * 16 + 16; nn++) {
        float a = (b > 0) ? obias : 0.f;
        for (int dc = 0; dc < DD; dc += 8) {
            float4 w0 = *(const float4*)&wrow[dc];
            float4 w1 = *(const float4*)&wrow[dc + 4];
            float4 o0 = *(float4*)&Os[nn * DD + dc];
            float4 o1 = *(float4*)&Os[nn * DD + dc + 4];
            a += o0.x*w0.x + o0.y*w0.y + o0.z*w0.z + o0.w*w0.w
               + o1.x*w1.x + o1.y*w1.y + o1.z*w1.z + o1.w*w1.w;
        }
        float cs = C[b * (NV * DD) + nn * DD + j] + a;
        Cstar[b * (NV * DD) + nn * DD + j] = cs;
        store_out(dout, 524288 + b * (NV * DD) + nn * DD + j, cs, obf);
    }
}

// ---------------- decoder init ----------------
__global__ __launch_bounds__(256) void dec_init(
    const float* __restrict__ Cstar,
    const void* __restrict__ iHw, const void* __restrict__ iCw,
    const int* __restrict__ flags, const float* __restrict__ P,
    float* __restrict__ h0, float* __restrict__ c0)
{
    int b = blockIdx.x, nn = blockIdx.y, tid = threadIdx.x;
    __shared__ float cs[DD];
    if (tid < DD) cs[tid] = Cstar[b * (NV * DD) + nn * DD + tid];
    __syncthreads();
    int e = tid & 127, mat = tid >> 7;
    const void* Wp = mat ? iCw : iHw;
    int wf = flags[mat ? 12 : 10];
    float acc = P[(mat ? OFF_ICB : OFF_IHB) + nn * DD + e];
    if (wf) {
        const uint_t* wrow = (const uint_t*)Wp + (((nn * DD + e) * DD) >> 1);
        for (int dc = 0; dc < DD; dc += 8) {
            float wf8[8];
            #pragma unroll
            for (int u = 0; u < 4; u++) {
                uint_t x = wrow[dc / 2 + u];
                wf8[2*u] = bflo(x); wf8[2*u+1] = bfhi(x);
            }
            float4 c0v = *(float4*)&cs[dc];
            float4 c1v = *(float4*)&cs[dc + 4];
            acc += c0v.x*wf8[0] + c0v.y*wf8[1] + c0v.z*wf8[2] + c0v.w*wf8[3]
                 + c1v.x*wf8[4] + c1v.y*wf8[5] + c1v.z*wf8[6] + c1v.w*wf8[7];
        }
    } else {
        const float* wrow = (const float*)Wp + (nn * DD + e) * DD;
        for (int dc = 0; dc < DD; dc += 8) {
            float4 w0 = *(const float4*)&wrow[dc];
            float4 w1 = *(const float4*)&wrow[dc + 4];
            float4 c0v = *(float4*)&cs[dc];
            float4 c1v = *(float4*)&cs[dc + 4];
            acc += c0v.x*w0.x + c0v.y*w0.y + c0v.z*w0.z + c0v.w*w0.w
                 + c1v.x*w1.x + c1v.y*w1.y + c1v.z*w1.z + c1v.w*w1.w;
        }
    }
    (mat ? c0 : h0)[(nn * NB + b) * DD + e] = tanh_f(acc);
}

// ===================== decoder: 8-wave MFMA recurrence, MFMA output proj =====================
__global__ __launch_bounds__(512, 2) void dec_kernel(
    const float* __restrict__ h0, const float* __restrict__ c0,
    const void* __restrict__ Wraw, const int* __restrict__ flags,
    const float* __restrict__ P, void* __restrict__ out)
{
    const int n = blockIdx.y, b0 = blockIdx.x * BT;
    const int tid = threadIdx.x;
    const int w = tid >> 6, lane = tid & 63;
    const int l15 = lane & 15, quad = lane >> 4;
    const int wbf = flags[14], obf = flags[0];
    const int d_own = 16 * w + l15;

    __shared__ alignas(16) ushort_t hSh[2][16 * 136];
    __shared__ alignas(16) ushort_t hSl[2][16 * 136];

    bf16x8 bfrag[4][4];
    #pragma unroll
    for (int typ = 0; typ < 4; typ++) {
        const int g = typ * 128 + d_own;
        #pragma unroll
        for (int kc = 0; kc < 4; kc++) {
            const int base = (n * G4 + g) * DD + 32 * kc + 8 * quad;
            if (wbf) {
                bfrag[typ][kc] = *(const bf16x8*)((const ushort_t*)Wraw + base);
            } else {
                const float* fp = (const float*)Wraw + base;
                bf16x8 tmp;
                #pragma unroll
                for (int j = 0; j < 8; j++) tmp[j] = (short)f2bf(fp[j]);
                bfrag[typ][kc] = tmp;
            }
        }
    }

    // output-projection B-fragment: column 0 = ow[k] (only wave 0 uses it)
    bf16x8 pfrag[4];
    #pragma unroll
    for (int kc = 0; kc < 4; kc++) {
        bf16x8 tmp;
        #pragma unroll
        for (int j = 0; j < 8; j++)
            tmp[j] = (l15 == 0) ? (short)f2bf(P[OFF_DOW + n * DD + 32 * kc + 8 * quad + j]) : (short)0;
        pfrag[kc] = tmp;
    }

    float bias[4];
    #pragma unroll
    for (int typ = 0; typ < 4; typ++) {
        int g = n * G4 + typ * 128 + d_own;
        bias[typ] = P[OFF_DBIH + g] + P[OFF_DBHH + g];
    }
    const float ob_r = P[OFF_DOB + n];

    float cst[4];
    #pragma unroll
    for (int r = 0; r < 4; r++) {
        int b = b0 + 4 * quad + r;
        float hv = h0[(n * NB + b) * DD + d_own];
        cst[r]   = c0[(n * NB + b) * DD + d_own];
        uint_t bits = f2u(hv);
        float hi_f = u2f(bits & 0xffff0000u);
        int addr = (4 * quad + r) * 136 + d_own;
        hSh[0][addr] = (ushort_t)(bits >> 16);
        hSl[0][addr] = (ushort_t)(f2u(hv - hi_f) >> 16);
    }

    for (int t = 0; t < 128; t++) {
        const int rb = t & 1, wb = rb ^ 1;
        __syncthreads();

        bf16x8 ah[4], al[4];
        #pragma unroll
        for (int kc = 0; kc < 4; kc++) {
            ah[kc] = *(const bf16x8*)&hSh[rb][l15 * 136 + 32 * kc + 8 * quad];
            al[kc] = *(const bf16x8*)&hSl[rb][l15 * 136 + 32 * kc + 8 * quad];
        }

        f32x4 acc[4];
        #pragma unroll
        for (int typ = 0; typ < 4; typ++) {
            f32x4 a;
            a.x = bias[typ]; a.y = bias[typ]; a.z = bias[typ]; a.w = bias[typ];
            acc[typ] = a;
        }

        #pragma unroll
        for (int kc = 0; kc < 4; kc++)
            #pragma unroll
            for (int typ = 0; typ < 4; typ++) {
                acc[typ] = __builtin_amdgcn_mfma_f32_16x16x32_bf16(al[kc], bfrag[typ][kc], acc[typ], 0, 0, 0);
                acc[typ] = __builtin_amdgcn_mfma_f32_16x16x32_bf16(ah[kc], bfrag[typ][kc], acc[typ], 0, 0, 0);
            }

        if (w == 0) {   // output projection: only wave 0 computes/stores o_{t-1}
            f32x4 accP;
            accP.x = 0.f; accP.y = 0.f; accP.z = 0.f; accP.w = 0.f;
            #pragma unroll
            for (int kc = 0; kc < 4; kc++) {
                accP = __builtin_amdgcn_mfma_f32_16x16x32_bf16(al[kc], pfrag[kc], accP, 0, 0, 0);
                accP = __builtin_amdgcn_mfma_f32_16x16x32_bf16(ah[kc], pfrag[kc], accP, 0, 0, 0);
            }
            if (t > 0 && l15 == 0) {
                #pragma unroll
                for (int r = 0; r < 4; r++) {
                    float o = accP[r] + ob_r;
                    long b = b0 + 4 * quad + r;
                    store_out(out, b * 4064 + (long)(t - 1) * NV + n, o, obf);
                }
            }
        }

        float hn[4];
        #pragma unroll
        for (int r = 0; r < 4; r++) {
            float ii = sigmoid_f(acc[0][r]);
            float ff = sigmoid_f(acc[1][r]);
            float g2 = tanh_f(acc[2][r]);
            float oo = sigmoid_f(acc[3][r]);
            float cc = ff * cst[r] + ii * g2;
            cst[r] = cc;
            hn[r] = oo * tanh_f(cc);
        }

        #pragma unroll
        for (int r = 0; r < 4; r++) {
            uint_t bits = f2u(hn[r]);
            float hi_f = u2f(bits & 0xffff0000u);
            int addr = (4 * quad + r) * 136 + d_own;
            hSh[wb][addr] = (ushort_t)(bits >> 16);
            hSl[wb][addr] = (ushort_t)(f2u(hn[r] - hi_f) >> 16);
        }
    }

    // o_127 from h_127 (in hS[0]: t=127 -> wb=0)
    __syncthreads();
    if (w == 0) {
        f32x4 accP;
        accP.x = 0.f; accP.y = 0.f; accP.z = 0.f; accP.w = 0.f;
        #pragma unroll
        for (int kc = 0; kc < 4; kc++) {
            bf16x8 ah = *(const bf16x8*)&hSh[0][l15 * 136 + 32 * kc + 8 * quad];
            bf16x8 al = *(const bf16x8*)&hSl[0][l15 * 136 + 32 * kc + 8 * quad];
            accP = __builtin_amdgcn_mfma_f32_16x16x32_bf16(al, pfrag[kc], accP, 0, 0, 0);
            accP = __builtin_amdgcn_mfma_f32_16x16x32_bf16(ah, pfrag[kc], accP, 0, 0, 0);
        }
        if (l15 == 0) {
            #pragma unroll
            for (int r = 0; r < 4; r++) {
                float o = accP[r] + ob_r;
                long b = b0 + 4 * quad + r;
                store_out(out, 520192 + b * NV + n, o, obf);
            }
        }
    }
}

extern "C" void kernel_launch(void* const* d_in, const int* in_sizes, int n_in,
                              void* d_out, int out_size, void* d_ws, size_t ws_size,
                              hipStream_t stream) {
    char* ws = (char*)d_ws;
    float*    P    = (float*)(ws + 0);              // 592 KB
    ushort_t* Xc   = (ushort_t*)(ws + (1u << 20));  // 1 MB
    float*    C    = (float*)(ws + (2u << 20));     // 2 MB
    float*    qb   = (float*)(ws + (4u << 20));
    float*    kb   = (float*)(ws + (6u << 20));
    float*    vb   = (float*)(ws + (8u << 20));
    float*    Cst  = (float*)(ws + (10u << 20));
    float*    h0   = (float*)(ws + (12u << 20));
    float*    c0   = (float*)(ws + (14u << 20));
    int*      flags = (int*)(ws + (16u << 20));

    Ptr19 a;
    for (int i = 0; i < 19; i++) { a.p[i] = d_in[i]; a.e[i] = in_sizes[i]; }
    probe_kernel<<<19, 64, 0, stream>>>(a, flags);
    conv_merged<<<(P_TOTAL + 255) / 256, 256, 0, stream>>>(a, flags, P);
    conv_X<<<(NB * 128 * NV + 255) / 256, 256, 0, stream>>>(d_in[0], flags, Xc);

    enc_kernel<<<dim3(8, 32), 512, 0, stream>>>(Xc, d_in[2], flags, P, C);
    qkv_kernel<<<dim3(128, 3), 128, 0, stream>>>(C, P, qb, kb, vb);
    attn_kernel<<<dim3(128), 256, 0, stream>>>(qb, kb, vb, C, P, flags, Cst, d_out);
    dec_init<<<dim3(128, 32), 256, 0, stream>>>(Cst, d_in[10], d_in[12], flags, P, h0, c0);
    dec_kernel<<<dim3(8, 32), 512, 0, stream>>>(h0, c0, d_in[14], flags, P, d_out);
}

// Round 7
// 441.860 us; speedup vs baseline: 20.6821x; 1.3524x over previous
//
#include <hip/hip_runtime.h>
#include <hip/hip_bf16.h>

typedef unsigned short ushort_t;
typedef unsigned int uint_t;

#define DD   128
#define G4   512
#define BT   16
#define NB   128
#define NV   32

// param block offsets (floats)
#define OFF_WIH   0
#define OFF_EB    16384
#define OFF_PW    32768
#define OFF_PB    36864
#define OFF_INW   36896
#define OFF_INB   86048
#define OFF_OUTW  86432
#define OFF_OUTB  102816
#define OFF_IHB   102944
#define OFF_ICB   107040
#define OFF_DBIH  111136
#define OFF_DBHH  127520
#define OFF_DOW   143904
#define OFF_DOB   148000
#define P_TOTAL   148032
#define X_TOTAL   (NB * 128 * NV)

typedef __attribute__((ext_vector_type(8))) short bf16x8;
typedef __attribute__((ext_vector_type(4))) float f32x4;

__device__ __forceinline__ float bf2f(ushort_t u) {
    union { uint_t i; float f; } x; x.i = ((uint_t)u) << 16; return x.f;
}
__device__ __forceinline__ float bflo(uint_t u) {
    union { uint_t i; float f; } x; x.i = u << 16; return x.f;
}
__device__ __forceinline__ float bfhi(uint_t u) {
    union { uint_t i; float f; } x; x.i = u & 0xffff0000u; return x.f;
}
__device__ __forceinline__ ushort_t f2bf(float f) {
    __hip_bfloat16 h = __float2bfloat16(f);   // RNE
    return *(ushort_t*)&h;
}
__device__ __forceinline__ uint_t f2u(float f) {
    union { float f; uint_t i; } x; x.f = f; return x.i;
}
__device__ __forceinline__ float u2f(uint_t u) {
    union { uint_t i; float f; } x; x.i = u; return x.f;
}
__device__ __forceinline__ float sigmoid_f(float x) {
    return __builtin_amdgcn_rcpf(1.f + __expf(-x));
}
__device__ __forceinline__ float tanh_f(float x) {
    float e = __expf(2.f * x);
    return 1.f - 2.f * __builtin_amdgcn_rcpf(e + 1.f);
}
__device__ __forceinline__ float swz_bcast16(float v) {
    // BitMode offset and=0x10: new_lane = lane & 0x10 (per 32-lane half)
    return u2f((uint_t)__builtin_amdgcn_ds_swizzle((int)f2u(v), 0x0010));
}
__device__ __forceinline__ void store_out(void* out, long idx, float v, int bf) {
    if (bf) ((ushort_t*)out)[idx] = f2bf(v);
    else    ((float*)out)[idx]    = v;
}

// ---------------- dtype probe (one block per input) ----------------
struct Ptr19 { const void* p[19]; int e[19]; };

__global__ __launch_bounds__(64) void probe_kernel(Ptr19 a, int* __restrict__ flags) {
    int i = blockIdx.x;
    int t = threadIdx.x;
    int cap = a.e[i] < 2048 ? a.e[i] : 2048;
    int cnt = 0, tot = 0;
    const ushort_t* p = (const ushort_t*)a.p[i];
    for (int j = t; j < cap; j += 64) {
        ushort_t u = p[j];
        float af = fabsf(bf2f(u));
        tot++;
        if (u == 0 || (af > 1e-7f && af < 100.f)) cnt++;
    }
    #pragma unroll
    for (int off = 32; off >= 1; off >>= 1) {
        cnt += __shfl_xor(cnt, off);
        tot += __shfl_xor(tot, off);
    }
    if (t == 0) flags[i] = (cnt * 10 >= tot * 9) ? 1 : 0;
}

// ---------------- merged canonicalizer: params -> fp32 P, X -> fp32 [t][n][b] ----------------
__global__ __launch_bounds__(256) void conv_all(Ptr19 a, const int* __restrict__ flags,
                                                float* __restrict__ P, float* __restrict__ Xc) {
    int i = blockIdx.x * 256 + threadIdx.x;
    if (i < P_TOTAL) {
        int src, off;
        if      (i < OFF_EB)   { src = 1;  off = i - OFF_WIH; }
        else if (i < OFF_PW)   { src = 3;  off = i - OFF_EB; }
        else if (i < OFF_PB)   { src = 4;  off = i - OFF_PW; }
        else if (i < OFF_INW)  { src = 5;  off = i - OFF_PB; }
        else if (i < OFF_INB)  { src = 6;  off = i - OFF_INW; }
        else if (i < OFF_OUTW) { src = 7;  off = i - OFF_INB; }
        else if (i < OFF_OUTB) { src = 8;  off = i - OFF_OUTW; }
        else if (i < OFF_IHB)  { src = 9;  off = i - OFF_OUTB; }
        else if (i < OFF_ICB)  { src = 11; off = i - OFF_IHB; }
        else if (i < OFF_DBIH) { src = 13; off = i - OFF_ICB; }
        else if (i < OFF_DBHH) { src = 15; off = i - OFF_DBIH; }
        else if (i < OFF_DOW)  { src = 16; off = i - OFF_DBHH; }
        else if (i < OFF_DOB)  { src = 17; off = i - OFF_DOW; }
        else                   { src = 18; off = i - OFF_DOB; }
        int bf = flags[src];
        P[i] = bf ? bf2f(((const ushort_t*)a.p[src])[off]) : ((const float*)a.p[src])[off];
    } else if (i < P_TOTAL + X_TOTAL) {
        int j = i - P_TOTAL;               // [t][n][b]
        int b = j & 127, nn = (j >> 7) & 31, t = j >> 12;
        int si = b * 4096 + t * 32 + nn;
        int bf = flags[0];
        Xc[j] = bf ? bf2f(((const ushort_t*)a.p[0])[si]) : ((const float*)a.p[0])[si];
    }
}

// ===================== encoder: 8-wave MFMA recurrence (bf16 h), MFMA pool score =====================
__global__ __launch_bounds__(512, 2) void enc_kernel(
    const float* __restrict__ Xc, const void* __restrict__ Wraw,
    const int* __restrict__ flags, const float* __restrict__ P,
    float* __restrict__ Cout)
{
    const int n = blockIdx.y, b0 = blockIdx.x * BT;
    const int tid = threadIdx.x;
    const int w = tid >> 6, lane = tid & 63;
    const int l15 = lane & 15, quad = lane >> 4;
    const int wbf = flags[2];
    const int d_own = 16 * w + l15;

    __shared__ alignas(16) ushort_t hS[2][16 * 136];

    for (int i = tid; i < 16 * 136; i += 512) hS[0][i] = 0;

    // B-fragments: bfrag[typ][kc]; lane holds B[k=32kc+8quad+j][g = typ*128 + d_own]
    bf16x8 bfrag[4][4];
    #pragma unroll
    for (int typ = 0; typ < 4; typ++) {
        const int g = typ * 128 + d_own;
        #pragma unroll
        for (int kc = 0; kc < 4; kc++) {
            const int base = (n * G4 + g) * DD + 32 * kc + 8 * quad;
            if (wbf) {
                bfrag[typ][kc] = *(const bf16x8*)((const ushort_t*)Wraw + base);
            } else {
                const float* fp = (const float*)Wraw + base;
                bf16x8 tmp;
                #pragma unroll
                for (int j = 0; j < 8; j++) tmp[j] = (short)f2bf(fp[j]);
                bfrag[typ][kc] = tmp;
            }
        }
    }

    // pool B-fragment: column 0 = pw[k], other columns 0
    bf16x8 pfrag[4];
    #pragma unroll
    for (int kc = 0; kc < 4; kc++) {
        bf16x8 tmp;
        #pragma unroll
        for (int j = 0; j < 8; j++)
            tmp[j] = (l15 == 0) ? (short)f2bf(P[OFF_PW + n * DD + 32 * kc + 8 * quad + j]) : (short)0;
        pfrag[kc] = tmp;
    }

    float bias[4], wih[4];
    #pragma unroll
    for (int typ = 0; typ < 4; typ++) {
        bias[typ] = P[OFF_EB  + n * G4 + typ * 128 + d_own];
        wih[typ]  = P[OFF_WIH + n * G4 + typ * 128 + d_own];
    }
    const float pb_r = P[OFF_PB + n];

    float cst[4], hprev[4], Cacc[4], lR[4];
    #pragma unroll
    for (int r = 0; r < 4; r++) {
        cst[r] = 0.f; hprev[r] = 0.f; Cacc[r] = 0.f; lR[r] = 0.f;
    }

    float4 xq = *(const float4*)&Xc[n * 128 + b0 + 4 * quad];   // t = 0

    for (int t = 0; t < 127; t++) {
        const int rb = t & 1, wb = rb ^ 1;
        __syncthreads();

        bf16x8 ah[4];
        #pragma unroll
        for (int kc = 0; kc < 4; kc++)
            ah[kc] = *(const bf16x8*)&hS[rb][l15 * 136 + 32 * kc + 8 * quad];

        f32x4 acc[4], accP;
        #pragma unroll
        for (int typ = 0; typ < 4; typ++) {
            f32x4 a;
            a.x = bias[typ] + xq.x * wih[typ];
            a.y = bias[typ] + xq.y * wih[typ];
            a.z = bias[typ] + xq.z * wih[typ];
            a.w = bias[typ] + xq.w * wih[typ];
            acc[typ] = a;
        }
        accP.x = pb_r; accP.y = pb_r; accP.z = pb_r; accP.w = pb_r;

        if (t < 126)
            xq = *(const float4*)&Xc[(t + 1) * 4096 + n * 128 + b0 + 4 * quad];

        #pragma unroll
        for (int kc = 0; kc < 4; kc++) {
            #pragma unroll
            for (int typ = 0; typ < 4; typ++)
                acc[typ] = __builtin_amdgcn_mfma_f32_16x16x32_bf16(ah[kc], bfrag[typ][kc], acc[typ], 0, 0, 0);
            accP = __builtin_amdgcn_mfma_f32_16x16x32_bf16(ah[kc], pfrag[kc], accP, 0, 0, 0);
        }

        if (t > 0) {   // fold h_{t-1}: e = exp(s_{t-1}), un-normalized accumulate
            #pragma unroll
            for (int r = 0; r < 4; r++) {
                float e = __expf(swz_bcast16(accP[r]));
                lR[r] += e;
                Cacc[r] = fmaf(e, hprev[r], Cacc[r]);
            }
        }

        float hn[4];
        #pragma unroll
        for (int r = 0; r < 4; r++) {
            float ii = sigmoid_f(acc[0][r]);
            float ff = sigmoid_f(acc[1][r]);
            float g2 = tanh_f(acc[2][r]);
            float oo = sigmoid_f(acc[3][r]);
            float cc = ff * cst[r] + ii * g2;
            cst[r] = cc;
            hn[r] = oo * tanh_f(cc);
        }

        #pragma unroll
        for (int r = 0; r < 4; r++)
            hS[wb][(4 * quad + r) * 136 + d_own] = f2bf(hn[r]);

        #pragma unroll
        for (int r = 0; r < 4; r++) hprev[r] = hn[r];
    }

    // final fold: score for h_126 (in hS[1]) via pool MFMAs only
    __syncthreads();
    {
        f32x4 accP;
        accP.x = pb_r; accP.y = pb_r; accP.z = pb_r; accP.w = pb_r;
        #pragma unroll
        for (int kc = 0; kc < 4; kc++) {
            bf16x8 ah = *(const bf16x8*)&hS[1][l15 * 136 + 32 * kc + 8 * quad];
            accP = __builtin_amdgcn_mfma_f32_16x16x32_bf16(ah, pfrag[kc], accP, 0, 0, 0);
        }
        #pragma unroll
        for (int r = 0; r < 4; r++) {
            float e = __expf(swz_bcast16(accP[r]));
            lR[r] += e;
            Cacc[r] = fmaf(e, hprev[r], Cacc[r]);
        }
    }
    #pragma unroll
    for (int r = 0; r < 4; r++)
        Cout[(b0 + 4 * quad + r) * (NV * DD) + n * DD + d_own] = Cacc[r] / lR[r];
}

// ---------------- QKV projection (256 thr: j = tid&127, n-half = tid>>7) ----------------
__global__ __launch_bounds__(256) void qkv_kernel(
    const float* __restrict__ C, const float* __restrict__ P,
    float* __restrict__ q, float* __restrict__ k, float* __restrict__ v)
{
    int b = blockIdx.x, p = blockIdx.y, tid = threadIdx.x;
    int j = tid & 127, half = tid >> 7;
    __shared__ float Cb[NV * DD];
    for (int i = tid; i < NV * DD; i += 256) Cb[i] = C[b * (NV * DD) + i];
    __syncthreads();

    const float* wrow = P + OFF_INW + (p * DD + j) * DD;
    float bias = P[OFF_INB + p * DD + j];
    float acc[16];
    #pragma unroll
    for (int nn = 0; nn < 16; nn++) acc[nn] = bias;

    for (int dc = 0; dc < DD; dc += 8) {
        float4 w0 = *(const float4*)&wrow[dc];
        float4 w1 = *(const float4*)&wrow[dc + 4];
        #pragma unroll
        for (int nn = 0; nn < 16; nn++) {
            const float* cb = &Cb[(half * 16 + nn) * DD + dc];
            float4 c0 = *(float4*)&cb[0];
            float4 c1 = *(float4*)&cb[4];
            acc[nn] += c0.x * w0.x + c0.y * w0.y + c0.z * w0.z + c0.w * w0.w
                     + c1.x * w1.x + c1.y * w1.y + c1.z * w1.z + c1.w * w1.w;
        }
    }
    float* dst = (p == 0) ? q : (p == 1) ? k : v;
    for (int nn = 0; nn < 16; nn++)
        dst[b * (NV * DD) + (half * 16 + nn) * DD + j] = acc[nn];
}

// ---------------- cross-attention + out-proj + residual ----------------
__global__ __launch_bounds__(256) void attn_kernel(
    const float* __restrict__ q, const float* __restrict__ k, const float* __restrict__ v,
    const float* __restrict__ C, const float* __restrict__ P,
    const int* __restrict__ flags, float* __restrict__ Cstar, void* __restrict__ dout)
{
    int b = blockIdx.x, tid = threadIdx.x;
    int obf = flags[0];
    __shared__ float Qs[NV * DD], Ks[NV * DD], Vs[NV * DD];
    float* Os = Ks;
    for (int i = tid; i < NV * DD; i += 256) Qs[i] = q[b * (NV * DD) + i];
    __syncthreads();

    int hh = tid >> 5, qi = tid & 31;
    float qreg[16];
    #pragma unroll
    for (int u = 0; u < 4; u++) {
        float4 t4 = *(float4*)&Qs[qi * DD + hh * 16 + 4 * u];
        qreg[4*u] = t4.x; qreg[4*u+1] = t4.y; qreg[4*u+2] = t4.z; qreg[4*u+3] = t4.w;
    }

    float Oacc[16];
    #pragma unroll
    for (int u = 0; u < 16; u++) Oacc[u] = 0.f;
    float wsum = 0.f;
    int tmax = (b < 5) ? b : 5;

    for (int tau = 1; tau <= tmax; tau++) {
        __syncthreads();
        for (int i = tid; i < NV * DD; i += 256) {
            Ks[i] = k[(b - tau) * (NV * DD) + i];
            Vs[i] = v[(b - tau) * (NV * DD) + i];
        }
        __syncthreads();

        float s[NV];
        #pragma unroll
        for (int kk = 0; kk < NV; kk++) {
            float a = 0.f;
            #pragma unroll
            for (int u = 0; u < 4; u++) {
                float4 kv = *(float4*)&Ks[kk * DD + hh * 16 + 4 * u];
                a += qreg[4*u] * kv.x + qreg[4*u+1] * kv.y
                   + qreg[4*u+2] * kv.z + qreg[4*u+3] * kv.w;
            }
            s[kk] = a * 0.25f;
        }
        float mm = s[0];
        #pragma unroll
        for (int kk = 1; kk < NV; kk++) mm = fmaxf(mm, s[kk]);
        float ssum = 0.f;
        #pragma unroll
        for (int kk = 0; kk < NV; kk++) { s[kk] = __expf(s[kk] - mm); ssum += s[kk]; }
        float wdk = __expf(-0.7f * (float)(tau - 1));
        wsum += wdk;
        float wr = wdk / ssum;
        #pragma unroll
        for (int u = 0; u < 4; u++) {
            float ax = 0.f, ay = 0.f, az = 0.f, aw = 0.f;
            #pragma unroll
            for (int kk = 0; kk < NV; kk++) {
                float4 vv = *(float4*)&Vs[kk * DD + hh * 16 + 4 * u];
                ax += s[kk] * vv.x; ay += s[kk] * vv.y;
                az += s[kk] * vv.z; aw += s[kk] * vv.w;
            }
            Oacc[4*u] += wr * ax; Oacc[4*u+1] += wr * ay;
            Oacc[4*u+2] += wr * az; Oacc[4*u+3] += wr * aw;
        }
    }

    __syncthreads();
    float winv = (b > 0) ? 1.f / wsum : 0.f;
    #pragma unroll
    for (int u = 0; u < 16; u++)
        Os[qi * DD + hh * 16 + u] = Oacc[u] * winv;
    __syncthreads();

    int j = tid & 127, ng = tid >> 7;
    const float* wrow = P + OFF_OUTW + j * DD;
    float obias = P[OFF_OUTB + j];
    for (int nn = ng * 16; nn < ng * 16 + 16; nn++) {
        float a = (b > 0) ? obias : 0.f;
        for (int dc = 0; dc < DD; dc += 8) {
            float4 w0 = *(const float4*)&wrow[dc];
            float4 w1 = *(const float4*)&wrow[dc + 4];
            float4 o0 = *(float4*)&Os[nn * DD + dc];
            float4 o1 = *(float4*)&Os[nn * DD + dc + 4];
            a += o0.x*w0.x + o0.y*w0.y + o0.z*w0.z + o0.w*w0.w
               + o1.x*w1.x + o1.y*w1.y + o1.z*w1.z + o1.w*w1.w;
        }
        float cs = C[b * (NV * DD) + nn * DD + j] + a;
        Cstar[b * (NV * DD) + nn * DD + j] = cs;
        store_out(dout, 524288 + b * (NV * DD) + nn * DD + j, cs, obf);
    }
}

// ===================== decoder: fused init (MFMA) + 8-wave MFMA recurrence =====================
__global__ __launch_bounds__(512, 2) void dec_kernel(
    const float* __restrict__ Cstar,
    const void* __restrict__ iHw, const void* __restrict__ iCw,
    const void* __restrict__ Wraw, const int* __restrict__ flags,
    const float* __restrict__ P, void* __restrict__ out)
{
    const int n = blockIdx.y, b0 = blockIdx.x * BT;
    const int tid = threadIdx.x;
    const int w = tid >> 6, lane = tid & 63;
    const int l15 = lane & 15, quad = lane >> 4;
    const int wbf = flags[14], obf = flags[0];
    const int d_own = 16 * w + l15;

    __shared__ alignas(16) ushort_t hS[2][16 * 136];

    // ---- fused decoder init: h0/c0 = tanh(Cstar · W^T + b) via MFMA ----
    // A-fragment from Cstar rows b0..b0+15 (RNE bf16)
    bf16x8 af[4];
    #pragma unroll
    for (int kc = 0; kc < 4; kc++) {
        const float* cp = &Cstar[(b0 + l15) * (NV * DD) + n * DD + 32 * kc + 8 * quad];
        float4 c0v = *(const float4*)&cp[0];
        float4 c1v = *(const float4*)&cp[4];
        bf16x8 tmp;
        tmp[0] = (short)f2bf(c0v.x); tmp[1] = (short)f2bf(c0v.y);
        tmp[2] = (short)f2bf(c0v.z); tmp[3] = (short)f2bf(c0v.w);
        tmp[4] = (short)f2bf(c1v.x); tmp[5] = (short)f2bf(c1v.y);
        tmp[6] = (short)f2bf(c1v.z); tmp[7] = (short)f2bf(c1v.w);
        af[kc] = tmp;
    }
    float cst[4];
    {
        const int hbf = flags[10], cbf = flags[12];
        f32x4 hAcc, cAcc;
        float hb = P[OFF_IHB + n * DD + d_own];
        float cb = P[OFF_ICB + n * DD + d_own];
        hAcc.x = hb; hAcc.y = hb; hAcc.z = hb; hAcc.w = hb;
        cAcc.x = cb; cAcc.y = cb; cAcc.z = cb; cAcc.w = cb;
        #pragma unroll
        for (int kc = 0; kc < 4; kc++) {
            const int base = (n * DD + d_own) * DD + 32 * kc + 8 * quad;
            bf16x8 wB;
            if (hbf) wB = *(const bf16x8*)((const ushort_t*)iHw + base);
            else {
                const float* fp = (const float*)iHw + base;
                #pragma unroll
                for (int j = 0; j < 8; j++) wB[j] = (short)f2bf(fp[j]);
            }
            hAcc = __builtin_amdgcn_mfma_f32_16x16x32_bf16(af[kc], wB, hAcc, 0, 0, 0);
            if (cbf) wB = *(const bf16x8*)((const ushort_t*)iCw + base);
            else {
                const float* fp = (const float*)iCw + base;
                #pragma unroll
                for (int j = 0; j < 8; j++) wB[j] = (short)f2bf(fp[j]);
            }
            cAcc = __builtin_amdgcn_mfma_f32_16x16x32_bf16(af[kc], wB, cAcc, 0, 0, 0);
        }
        #pragma unroll
        for (int r = 0; r < 4; r++) {
            float hv = tanh_f(hAcc[r]);
            cst[r]   = tanh_f(cAcc[r]);
            hS[0][(4 * quad + r) * 136 + d_own] = f2bf(hv);
        }
    }

    // ---- recurrence weights ----
    bf16x8 bfrag[4][4];
    #pragma unroll
    for (int typ = 0; typ < 4; typ++) {
        const int g = typ * 128 + d_own;
        #pragma unroll
        for (int kc = 0; kc < 4; kc++) {
            const int base = (n * G4 + g) * DD + 32 * kc + 8 * quad;
            if (wbf) {
                bfrag[typ][kc] = *(const bf16x8*)((const ushort_t*)Wraw + base);
            } else {
                const float* fp = (const float*)Wraw + base;
                bf16x8 tmp;
                #pragma unroll
                for (int j = 0; j < 8; j++) tmp[j] = (short)f2bf(fp[j]);
                bfrag[typ][kc] = tmp;
            }
        }
    }

    // output-projection B-fragment: column 0 = ow[k] (only wave 0 uses it)
    bf16x8 pfrag[4];
    #pragma unroll
    for (int kc = 0; kc < 4; kc++) {
        bf16x8 tmp;
        #pragma unroll
        for (int j = 0; j < 8; j++)
            tmp[j] = (l15 == 0) ? (short)f2bf(P[OFF_DOW + n * DD + 32 * kc + 8 * quad + j]) : (short)0;
        pfrag[kc] = tmp;
    }

    float bias[4];
    #pragma unroll
    for (int typ = 0; typ < 4; typ++) {
        int g = n * G4 + typ * 128 + d_own;
        bias[typ] = P[OFF_DBIH + g] + P[OFF_DBHH + g];
    }
    const float ob_r = P[OFF_DOB + n];

    for (int t = 0; t < 128; t++) {
        const int rb = t & 1, wb = rb ^ 1;
        __syncthreads();

        bf16x8 ah[4];
        #pragma unroll
        for (int kc = 0; kc < 4; kc++)
            ah[kc] = *(const bf16x8*)&hS[rb][l15 * 136 + 32 * kc + 8 * quad];

        f32x4 acc[4];
        #pragma unroll
        for (int typ = 0; typ < 4; typ++) {
            f32x4 a;
            a.x = bias[typ]; a.y = bias[typ]; a.z = bias[typ]; a.w = bias[typ];
            acc[typ] = a;
        }

        #pragma unroll
        for (int kc = 0; kc < 4; kc++)
            #pragma unroll
            for (int typ = 0; typ < 4; typ++)
                acc[typ] = __builtin_amdgcn_mfma_f32_16x16x32_bf16(ah[kc], bfrag[typ][kc], acc[typ], 0, 0, 0);

        if (w == 0) {   // output projection: o_{t-1} from A = h_{t-1}
            f32x4 accP;
            accP.x = ob_r; accP.y = ob_r; accP.z = ob_r; accP.w = ob_r;
            #pragma unroll
            for (int kc = 0; kc < 4; kc++)
                accP = __builtin_amdgcn_mfma_f32_16x16x32_bf16(ah[kc], pfrag[kc], accP, 0, 0, 0);
            if (t > 0 && l15 == 0) {
                #pragma unroll
                for (int r = 0; r < 4; r++) {
                    long b = b0 + 4 * quad + r;
                    store_out(out, b * 4064 + (long)(t - 1) * NV + n, accP[r], obf);
                }
            }
        }

        float hn[4];
        #pragma unroll
        for (int r = 0; r < 4; r++) {
            float ii = sigmoid_f(acc[0][r]);
            float ff = sigmoid_f(acc[1][r]);
            float g2 = tanh_f(acc[2][r]);
            float oo = sigmoid_f(acc[3][r]);
            float cc = ff * cst[r] + ii * g2;
            cst[r] = cc;
            hn[r] = oo * tanh_f(cc);
        }

        #pragma unroll
        for (int r = 0; r < 4; r++)
            hS[wb][(4 * quad + r) * 136 + d_own] = f2bf(hn[r]);
    }

    // o_127 from h_127 (in hS[0]: t=127 -> wb=0)
    __syncthreads();
    if (w == 0) {
        f32x4 accP;
        accP.x = ob_r; accP.y = ob_r; accP.z = ob_r; accP.w = ob_r;
        #pragma unroll
        for (int kc = 0; kc < 4; kc++) {
            bf16x8 ah = *(const bf16x8*)&hS[0][l15 * 136 + 32 * kc + 8 * quad];
            accP = __builtin_amdgcn_mfma_f32_16x16x32_bf16(ah, pfrag[kc], accP, 0, 0, 0);
        }
        if (l15 == 0) {
            #pragma unroll
            for (int r = 0; r < 4; r++) {
                long b = b0 + 4 * quad + r;
                store_out(out, 520192 + b * NV + n, accP[r], obf);
            }
        }
    }
}

extern "C" void kernel_launch(void* const* d_in, const int* in_sizes, int n_in,
                              void* d_out, int out_size, void* d_ws, size_t ws_size,
                              hipStream_t stream) {
    char* ws = (char*)d_ws;
    float*    P    = (float*)(ws + 0);              // 592 KB
    float*    Xc   = (float*)(ws + (1u << 20));     // 2 MB
    float*    C    = (float*)(ws + (3u << 20));     // 2 MB
    float*    qb   = (float*)(ws + (5u << 20));
    float*    kb   = (float*)(ws + (7u << 20));
    float*    vb   = (float*)(ws + (9u << 20));
    float*    Cst  = (float*)(ws + (11u << 20));
    int*      flags = (int*)(ws + (13u << 20));

    Ptr19 a;
    for (int i = 0; i < 19; i++) { a.p[i] = d_in[i]; a.e[i] = in_sizes[i]; }
    probe_kernel<<<19, 64, 0, stream>>>(a, flags);
    conv_all<<<(P_TOTAL + X_TOTAL + 255) / 256, 256, 0, stream>>>(a, flags, P, Xc);

    enc_kernel<<<dim3(8, 32), 512, 0, stream>>>(Xc, d_in[2], flags, P, C);
    qkv_kernel<<<dim3(128, 3), 256, 0, stream>>>(C, P, qb, kb, vb);
    attn_kernel<<<dim3(128), 256, 0, stream>>>(qb, kb, vb, C, P, flags, Cst, d_out);
    dec_kernel<<<dim3(8, 32), 512, 0, stream>>>(Cst, d_in[10], d_in[12], d_in[14], flags, P, d_out);
}

// Round 8
// 435.316 us; speedup vs baseline: 20.9930x; 1.0150x over previous
//
#include <hip/hip_runtime.h>
#include <hip/hip_bf16.h>

typedef unsigned short ushort_t;
typedef unsigned int uint_t;

#define DD   128
#define G4   512
#define BT   16
#define NB   128
#define NV   32

// param block offsets (floats)
#define OFF_WIH   0
#define OFF_EB    16384
#define OFF_PW    32768
#define OFF_PB    36864
#define OFF_INW   36896
#define OFF_INB   86048
#define OFF_OUTW  86432
#define OFF_OUTB  102816
#define OFF_IHB   102944
#define OFF_ICB   107040
#define OFF_DBIH  111136
#define OFF_DBHH  127520
#define OFF_DOW   143904
#define OFF_DOB   148000
#define P_TOTAL   148032

typedef __attribute__((ext_vector_type(8))) short bf16x8;
typedef __attribute__((ext_vector_type(4))) float f32x4;

__device__ __forceinline__ float bf2f(ushort_t u) {
    union { uint_t i; float f; } x; x.i = ((uint_t)u) << 16; return x.f;
}
__device__ __forceinline__ ushort_t f2bf(float f) {
    __hip_bfloat16 h = __float2bfloat16(f);   // RNE
    return *(ushort_t*)&h;
}
__device__ __forceinline__ uint_t f2u(float f) {
    union { float f; uint_t i; } x; x.f = f; return x.i;
}
__device__ __forceinline__ float u2f(uint_t u) {
    union { uint_t i; float f; } x; x.i = u; return x.f;
}
__device__ __forceinline__ float sigmoid_f(float x) {
    return __builtin_amdgcn_rcpf(1.f + __expf(-x));
}
__device__ __forceinline__ float tanh_f(float x) {
    float e = __expf(2.f * x);
    return 1.f - 2.f * __builtin_amdgcn_rcpf(e + 1.f);
}
__device__ __forceinline__ float swz_bcast_l15(float v) {
    // BitMode and=0x0F: new_lane = lane & 15 (within each 32-lane half)
    return u2f((uint_t)__builtin_amdgcn_ds_swizzle((int)f2u(v), 0x000F));
}
__device__ __forceinline__ void store_out(void* out, long idx, float v, int bf) {
    if (bf) ((ushort_t*)out)[idx] = f2bf(v);
    else    ((float*)out)[idx]    = v;
}

// ---------------- dtype probe (one block per input) ----------------
struct Ptr19 { const void* p[19]; int e[19]; };

__global__ __launch_bounds__(64) void probe_kernel(Ptr19 a, int* __restrict__ flags) {
    int i = blockIdx.x;
    int t = threadIdx.x;
    int cap = a.e[i] < 2048 ? a.e[i] : 2048;
    int cnt = 0, tot = 0;
    const ushort_t* p = (const ushort_t*)a.p[i];
    for (int j = t; j < cap; j += 64) {
        ushort_t u = p[j];
        float af = fabsf(bf2f(u));
        tot++;
        if (u == 0 || (af > 1e-7f && af < 100.f)) cnt++;
    }
    #pragma unroll
    for (int off = 32; off >= 1; off >>= 1) {
        cnt += __shfl_xor(cnt, off);
        tot += __shfl_xor(tot, off);
    }
    if (t == 0) flags[i] = (cnt * 10 >= tot * 9) ? 1 : 0;
}

// ---------------- param canonicalizer -> fp32 block P ----------------
__global__ __launch_bounds__(256) void conv_all(Ptr19 a, const int* __restrict__ flags,
                                                float* __restrict__ P) {
    int i = blockIdx.x * 256 + threadIdx.x;
    if (i >= P_TOTAL) return;
    int src, off;
    if      (i < OFF_EB)   { src = 1;  off = i - OFF_WIH; }
    else if (i < OFF_PW)   { src = 3;  off = i - OFF_EB; }
    else if (i < OFF_PB)   { src = 4;  off = i - OFF_PW; }
    else if (i < OFF_INW)  { src = 5;  off = i - OFF_PB; }
    else if (i < OFF_INB)  { src = 6;  off = i - OFF_INW; }
    else if (i < OFF_OUTW) { src = 7;  off = i - OFF_INB; }
    else if (i < OFF_OUTB) { src = 8;  off = i - OFF_OUTW; }
    else if (i < OFF_IHB)  { src = 9;  off = i - OFF_OUTB; }
    else if (i < OFF_ICB)  { src = 11; off = i - OFF_IHB; }
    else if (i < OFF_DBIH) { src = 13; off = i - OFF_ICB; }
    else if (i < OFF_DBHH) { src = 15; off = i - OFF_DBIH; }
    else if (i < OFF_DOW)  { src = 16; off = i - OFF_DBHH; }
    else if (i < OFF_DOB)  { src = 17; off = i - OFF_DOW; }
    else                   { src = 18; off = i - OFF_DOB; }
    int bf = flags[src];
    P[i] = bf ? bf2f(((const ushort_t*)a.p[src])[off]) : ((const float*)a.p[src])[off];
}

// ---------------- X transpose: (B,L,N)->fp32 [t][n][b], LDS-tiled coalesced ----------------
__global__ __launch_bounds__(256) void transpose_X(const void* __restrict__ src,
                                                   const int* __restrict__ flags,
                                                   float* __restrict__ Xc) {
    __shared__ float tile[32][65];
    int bt  = blockIdx.x * 32;     // b tile
    int tn0 = blockIdx.y * 64;     // (t*32+n) tile
    int bf = flags[0];
    int tx = threadIdx.x & 63, ty = threadIdx.x >> 6;
    #pragma unroll
    for (int k = 0; k < 8; k++) {
        int row = ty * 8 + k;                       // b offset
        int idx = (bt + row) * 4096 + tn0 + tx;     // coalesced along tn
        tile[row][tx] = bf ? bf2f(((const ushort_t*)src)[idx]) : ((const float*)src)[idx];
    }
    __syncthreads();
    int bx = threadIdx.x & 31, tyy = threadIdx.x >> 5;
    #pragma unroll
    for (int k = 0; k < 8; k++) {
        int tn = tn0 + tyy * 8 + k;
        int t = tn >> 5, nn = tn & 31;
        Xc[t * 4096 + nn * 128 + bt + bx] = tile[bx][tyy * 8 + k];   // coalesced along b
    }
}

// ===================== encoder: operand-swapped MFMA recurrence =====================
// D[g-row][b-col]: thread owns (b = l15, d = 16w + 4quad + r, r=0..3).
__global__ __launch_bounds__(512, 2) void enc_kernel(
    const float* __restrict__ Xc, const void* __restrict__ Wraw,
    const int* __restrict__ flags, const float* __restrict__ P,
    float* __restrict__ Cout)
{
    const int n = blockIdx.y, b0 = blockIdx.x * BT;
    const int tid = threadIdx.x;
    const int w = tid >> 6, lane = tid & 63;
    const int l15 = lane & 15, quad = lane >> 4;
    const int wbf = flags[2];
    const int bown = b0 + l15;

    __shared__ alignas(16) ushort_t hS[2][16 * 136];
    for (int i = tid; i < 16 * 136; i += 512) hS[0][i] = 0;

    // A-fragments (weights): lane holds W[g = typ*128 + 16w + l15][k = 32kc+8quad+j]
    bf16x8 afrag[4][4];
    #pragma unroll
    for (int typ = 0; typ < 4; typ++) {
        const int g = typ * 128 + 16 * w + l15;
        #pragma unroll
        for (int kc = 0; kc < 4; kc++) {
            const int base = (n * G4 + g) * DD + 32 * kc + 8 * quad;
            if (wbf) {
                afrag[typ][kc] = *(const bf16x8*)((const ushort_t*)Wraw + base);
            } else {
                const float* fp = (const float*)Wraw + base;
                bf16x8 tmp;
                #pragma unroll
                for (int j = 0; j < 8; j++) tmp[j] = (short)f2bf(fp[j]);
                afrag[typ][kc] = tmp;
            }
        }
    }

    // pool A-fragment: rows 0 and 8 carry pw (so both 32-lane halves get s)
    bf16x8 pfrag[4];
    #pragma unroll
    for (int kc = 0; kc < 4; kc++) {
        bf16x8 tmp;
        #pragma unroll
        for (int j = 0; j < 8; j++)
            tmp[j] = (l15 == 0 || l15 == 8)
                   ? (short)f2bf(P[OFF_PW + n * DD + 32 * kc + 8 * quad + j]) : (short)0;
        pfrag[kc] = tmp;
    }

    f32x4 bias4[4], wih4[4];
    #pragma unroll
    for (int typ = 0; typ < 4; typ++) {
        int base = n * G4 + typ * 128 + 16 * w + 4 * quad;
        bias4[typ] = *(const f32x4*)&P[OFF_EB + base];
        wih4[typ]  = *(const f32x4*)&P[OFF_WIH + base];
    }
    const float pb_r = P[OFF_PB + n];

    float cst[4], hprev[4], Cacc[4], lR = 0.f;
    #pragma unroll
    for (int r = 0; r < 4; r++) { cst[r] = 0.f; hprev[r] = 0.f; Cacc[r] = 0.f; }

    float xq = Xc[n * 128 + bown];   // t = 0

#define ENC_STEP(T, RB)                                                              \
    do {                                                                             \
        __syncthreads();                                                             \
        bf16x8 bh[4];                                                                \
        _Pragma("unroll")                                                            \
        for (int kc = 0; kc < 4; kc++)                                               \
            bh[kc] = *(const bf16x8*)&hS[RB][l15 * 136 + 32 * kc + 8 * quad];        \
        f32x4 acc[4], accP;                                                          \
        _Pragma("unroll")                                                            \
        for (int typ = 0; typ < 4; typ++) {                                          \
            f32x4 a;                                                                 \
            a.x = bias4[typ].x + xq * wih4[typ].x;                                   \
            a.y = bias4[typ].y + xq * wih4[typ].y;                                   \
            a.z = bias4[typ].z + xq * wih4[typ].z;                                   \
            a.w = bias4[typ].w + xq * wih4[typ].w;                                   \
            acc[typ] = a;                                                            \
        }                                                                            \
        accP.x = pb_r; accP.y = pb_r; accP.z = pb_r; accP.w = pb_r;                  \
        if ((T) < 126) xq = Xc[((T) + 1) * 4096 + n * 128 + bown];                   \
        _Pragma("unroll")                                                            \
        for (int kc = 0; kc < 4; kc++) {                                             \
            accP = __builtin_amdgcn_mfma_f32_16x16x32_bf16(pfrag[kc], bh[kc], accP, 0, 0, 0); \
            _Pragma("unroll")                                                        \
            for (int typ = 0; typ < 4; typ++)                                        \
                acc[typ] = __builtin_amdgcn_mfma_f32_16x16x32_bf16(afrag[typ][kc], bh[kc], acc[typ], 0, 0, 0); \
        }                                                                            \
        if ((T) > 0) {                                                               \
            float e = __expf(swz_bcast_l15(accP[0]));                                \
            lR += e;                                                                 \
            _Pragma("unroll")                                                        \
            for (int r = 0; r < 4; r++) Cacc[r] = fmaf(e, hprev[r], Cacc[r]);        \
        }                                                                            \
        ushort4 hw;                                                                  \
        _Pragma("unroll")                                                            \
        for (int r = 0; r < 4; r++) {                                                \
            float ii = sigmoid_f(acc[0][r]);                                         \
            float ff = sigmoid_f(acc[1][r]);                                         \
            float g2 = tanh_f(acc[2][r]);                                            \
            float oo = sigmoid_f(acc[3][r]);                                         \
            float cc = ff * cst[r] + ii * g2;                                        \
            cst[r] = cc;                                                             \
            float hh = oo * tanh_f(cc);                                              \
            hprev[r] = hh;                                                           \
            ((ushort_t*)&hw)[r] = f2bf(hh);                                          \
        }                                                                            \
        *(ushort4*)&hS[(RB) ^ 1][l15 * 136 + 16 * w + 4 * quad] = hw;                \
    } while (0)

    for (int tp = 0; tp < 63; tp++) {
        ENC_STEP(2 * tp, 0);
        ENC_STEP(2 * tp + 1, 1);
    }
    ENC_STEP(126, 0);
#undef ENC_STEP

    // final fold: score of h_126 (in hS[1])
    __syncthreads();
    {
        f32x4 accP;
        accP.x = pb_r; accP.y = pb_r; accP.z = pb_r; accP.w = pb_r;
        #pragma unroll
        for (int kc = 0; kc < 4; kc++) {
            bf16x8 bh = *(const bf16x8*)&hS[1][l15 * 136 + 32 * kc + 8 * quad];
            accP = __builtin_amdgcn_mfma_f32_16x16x32_bf16(pfrag[kc], bh, accP, 0, 0, 0);
        }
        float e = __expf(swz_bcast_l15(accP[0]));
        lR += e;
        #pragma unroll
        for (int r = 0; r < 4; r++) Cacc[r] = fmaf(e, hprev[r], Cacc[r]);
    }
    float inv = 1.f / lR;
    f32x4 cv;
    cv.x = Cacc[0] * inv; cv.y = Cacc[1] * inv; cv.z = Cacc[2] * inv; cv.w = Cacc[3] * inv;
    *(f32x4*)&Cout[bown * (NV * DD) + n * DD + 16 * w + 4 * quad] = cv;
}

// ---------------- QKV projection ----------------
__global__ __launch_bounds__(256) void qkv_kernel(
    const float* __restrict__ C, const float* __restrict__ P,
    float* __restrict__ q, float* __restrict__ k, float* __restrict__ v)
{
    int b = blockIdx.x, p = blockIdx.y, tid = threadIdx.x;
    int j = tid & 127, half = tid >> 7;
    __shared__ float Cb[NV * DD];
    for (int i = tid; i < NV * DD; i += 256) Cb[i] = C[b * (NV * DD) + i];
    __syncthreads();

    const float* wrow = P + OFF_INW + (p * DD + j) * DD;
    float bias = P[OFF_INB + p * DD + j];
    float acc[16];
    #pragma unroll
    for (int nn = 0; nn < 16; nn++) acc[nn] = bias;

    for (int dc = 0; dc < DD; dc += 8) {
        float4 w0 = *(const float4*)&wrow[dc];
        float4 w1 = *(const float4*)&wrow[dc + 4];
        #pragma unroll
        for (int nn = 0; nn < 16; nn++) {
            const float* cb = &Cb[(half * 16 + nn) * DD + dc];
            float4 c0 = *(float4*)&cb[0];
            float4 c1 = *(float4*)&cb[4];
            acc[nn] += c0.x * w0.x + c0.y * w0.y + c0.z * w0.z + c0.w * w0.w
                     + c1.x * w1.x + c1.y * w1.y + c1.z * w1.z + c1.w * w1.w;
        }
    }
    float* dst = (p == 0) ? q : (p == 1) ? k : v;
    for (int nn = 0; nn < 16; nn++)
        dst[b * (NV * DD) + (half * 16 + nn) * DD + j] = acc[nn];
}

// ---------------- cross-attention + out-proj + residual ----------------
__global__ __launch_bounds__(256) void attn_kernel(
    const float* __restrict__ q, const float* __restrict__ k, const float* __restrict__ v,
    const float* __restrict__ C, const float* __restrict__ P,
    const int* __restrict__ flags, float* __restrict__ Cstar, void* __restrict__ dout)
{
    int b = blockIdx.x, tid = threadIdx.x;
    int obf = flags[0];
    __shared__ float Qs[NV * DD], Ks[NV * DD], Vs[NV * DD];
    float* Os = Ks;
    for (int i = tid; i < NV * DD; i += 256) Qs[i] = q[b * (NV * DD) + i];
    __syncthreads();

    int hh = tid >> 5, qi = tid & 31;
    float qreg[16];
    #pragma unroll
    for (int u = 0; u < 4; u++) {
        float4 t4 = *(float4*)&Qs[qi * DD + hh * 16 + 4 * u];
        qreg[4*u] = t4.x; qreg[4*u+1] = t4.y; qreg[4*u+2] = t4.z; qreg[4*u+3] = t4.w;
    }

    float Oacc[16];
    #pragma unroll
    for (int u = 0; u < 16; u++) Oacc[u] = 0.f;
    float wsum = 0.f;
    int tmax = (b < 5) ? b : 5;

    for (int tau = 1; tau <= tmax; tau++) {
        __syncthreads();
        for (int i = tid; i < NV * DD; i += 256) {
            Ks[i] = k[(b - tau) * (NV * DD) + i];
            Vs[i] = v[(b - tau) * (NV * DD) + i];
        }
        __syncthreads();

        float s[NV];
        #pragma unroll
        for (int kk = 0; kk < NV; kk++) {
            float a = 0.f;
            #pragma unroll
            for (int u = 0; u < 4; u++) {
                float4 kv = *(float4*)&Ks[kk * DD + hh * 16 + 4 * u];
                a += qreg[4*u] * kv.x + qreg[4*u+1] * kv.y
                   + qreg[4*u+2] * kv.z + qreg[4*u+3] * kv.w;
            }
            s[kk] = a * 0.25f;
        }
        float mm = s[0];
        #pragma unroll
        for (int kk = 1; kk < NV; kk++) mm = fmaxf(mm, s[kk]);
        float ssum = 0.f;
        #pragma unroll
        for (int kk = 0; kk < NV; kk++) { s[kk] = __expf(s[kk] - mm); ssum += s[kk]; }
        float wdk = __expf(-0.7f * (float)(tau - 1));
        wsum += wdk;
        float wr = wdk / ssum;
        #pragma unroll
        for (int u = 0; u < 4; u++) {
            float ax = 0.f, ay = 0.f, az = 0.f, aw = 0.f;
            #pragma unroll
            for (int kk = 0; kk < NV; kk++) {
                float4 vv = *(float4*)&Vs[kk * DD + hh * 16 + 4 * u];
                ax += s[kk] * vv.x; ay += s[kk] * vv.y;
                az += s[kk] * vv.z; aw += s[kk] * vv.w;
            }
            Oacc[4*u] += wr * ax; Oacc[4*u+1] += wr * ay;
            Oacc[4*u+2] += wr * az; Oacc[4*u+3] += wr * aw;
        }
    }

    __syncthreads();
    float winv = (b > 0) ? 1.f / wsum : 0.f;
    #pragma unroll
    for (int u = 0; u < 16; u++)
        Os[qi * DD + hh * 16 + u] = Oacc[u] * winv;
    __syncthreads();

    int j = tid & 127, ng = tid >> 7;
    const float* wrow = P + OFF_OUTW + j * DD;
    float obias = P[OFF_OUTB + j];
    for (int nn = ng * 16; nn < ng * 16 + 16; nn++) {
        float a = (b > 0) ? obias : 0.f;
        for (int dc = 0; dc < DD; dc += 8) {
            float4 w0 = *(const float4*)&wrow[dc];
            float4 w1 = *(const float4*)&wrow[dc + 4];
            float4 o0 = *(float4*)&Os[nn * DD + dc];
            float4 o1 = *(float4*)&Os[nn * DD + dc + 4];
            a += o0.x*w0.x + o0.y*w0.y + o0.z*w0.z + o0.w*w0.w
               + o1.x*w1.x + o1.y*w1.y + o1.z*w1.z + o1.w*w1.w;
        }
        float cs = C[b * (NV * DD) + nn * DD + j] + a;
        Cstar[b * (NV * DD) + nn * DD + j] = cs;
        store_out(dout, 524288 + b * (NV * DD) + nn * DD + j, cs, obf);
    }
}

// ===================== decoder: fused init + operand-swapped MFMA recurrence =====================
__global__ __launch_bounds__(512, 2) void dec_kernel(
    const float* __restrict__ Cstar,
    const void* __restrict__ iHw, const void* __restrict__ iCw,
    const void* __restrict__ Wraw, const int* __restrict__ flags,
    const float* __restrict__ P, void* __restrict__ out)
{
    const int n = blockIdx.y, b0 = blockIdx.x * BT;
    const int tid = threadIdx.x;
    const int w = tid >> 6, lane = tid & 63;
    const int l15 = lane & 15, quad = lane >> 4;
    const int wbf = flags[14], obf = flags[0];
    const int bown = b0 + l15;

    __shared__ alignas(16) ushort_t hS[2][16 * 136];

    // ---- fused init: D[e-row][b-col] = Cst·W^T + b ----
    bf16x8 cstB[4];
    #pragma unroll
    for (int kc = 0; kc < 4; kc++) {
        const float* cp = &Cstar[bown * (NV * DD) + n * DD + 32 * kc + 8 * quad];
        f32x4 c0v = *(const f32x4*)&cp[0];
        f32x4 c1v = *(const f32x4*)&cp[4];
        bf16x8 tmp;
        tmp[0] = (short)f2bf(c0v.x); tmp[1] = (short)f2bf(c0v.y);
        tmp[2] = (short)f2bf(c0v.z); tmp[3] = (short)f2bf(c0v.w);
        tmp[4] = (short)f2bf(c1v.x); tmp[5] = (short)f2bf(c1v.y);
        tmp[6] = (short)f2bf(c1v.z); tmp[7] = (short)f2bf(c1v.w);
        cstB[kc] = tmp;
    }
    float cst[4];
    {
        const int hbf = flags[10], cbf = flags[12];
        f32x4 hAcc = *(const f32x4*)&P[OFF_IHB + n * DD + 16 * w + 4 * quad];
        f32x4 cAcc = *(const f32x4*)&P[OFF_ICB + n * DD + 16 * w + 4 * quad];
        #pragma unroll
        for (int kc = 0; kc < 4; kc++) {
            const int base = (n * DD + 16 * w + l15) * DD + 32 * kc + 8 * quad;
            bf16x8 wA;
            if (hbf) wA = *(const bf16x8*)((const ushort_t*)iHw + base);
            else {
                const float* fp = (const float*)iHw + base;
                #pragma unroll
                for (int j = 0; j < 8; j++) wA[j] = (short)f2bf(fp[j]);
            }
            hAcc = __builtin_amdgcn_mfma_f32_16x16x32_bf16(wA, cstB[kc], hAcc, 0, 0, 0);
            if (cbf) wA = *(const bf16x8*)((const ushort_t*)iCw + base);
            else {
                const float* fp = (const float*)iCw + base;
                #pragma unroll
                for (int j = 0; j < 8; j++) wA[j] = (short)f2bf(fp[j]);
            }
            cAcc = __builtin_amdgcn_mfma_f32_16x16x32_bf16(wA, cstB[kc], cAcc, 0, 0, 0);
        }
        ushort4 hw;
        #pragma unroll
        for (int r = 0; r < 4; r++) {
            ((ushort_t*)&hw)[r] = f2bf(tanh_f(hAcc[r]));
            cst[r] = tanh_f(cAcc[r]);
        }
        *(ushort4*)&hS[0][l15 * 136 + 16 * w + 4 * quad] = hw;
    }

    // ---- recurrence weights (A-operand) ----
    bf16x8 afrag[4][4];
    #pragma unroll
    for (int typ = 0; typ < 4; typ++) {
        const int g = typ * 128 + 16 * w + l15;
        #pragma unroll
        for (int kc = 0; kc < 4; kc++) {
            const int base = (n * G4 + g) * DD + 32 * kc + 8 * quad;
            if (wbf) {
                afrag[typ][kc] = *(const bf16x8*)((const ushort_t*)Wraw + base);
            } else {
                const float* fp = (const float*)Wraw + base;
                bf16x8 tmp;
                #pragma unroll
                for (int j = 0; j < 8; j++) tmp[j] = (short)f2bf(fp[j]);
                afrag[typ][kc] = tmp;
            }
        }
    }

    // out-proj A-fragment: row 0 = ow (only wave 0 computes it)
    bf16x8 pfrag[4];
    #pragma unroll
    for (int kc = 0; kc < 4; kc++) {
        bf16x8 tmp;
        #pragma unroll
        for (int j = 0; j < 8; j++)
            tmp[j] = (l15 == 0) ? (short)f2bf(P[OFF_DOW + n * DD + 32 * kc + 8 * quad + j]) : (short)0;
        pfrag[kc] = tmp;
    }

    f32x4 bias4[4];
    #pragma unroll
    for (int typ = 0; typ < 4; typ++) {
        int base = n * G4 + typ * 128 + 16 * w + 4 * quad;
        f32x4 b1 = *(const f32x4*)&P[OFF_DBIH + base];
        f32x4 b2 = *(const f32x4*)&P[OFF_DBHH + base];
        bias4[typ].x = b1.x + b2.x; bias4[typ].y = b1.y + b2.y;
        bias4[typ].z = b1.z + b2.z; bias4[typ].w = b1.w + b2.w;
    }
    const float ob_r = P[OFF_DOB + n];

#define DEC_STEP(T, RB)                                                              \
    do {                                                                             \
        __syncthreads();                                                             \
        bf16x8 bh[4];                                                                \
        _Pragma("unroll")                                                            \
        for (int kc = 0; kc < 4; kc++)                                               \
            bh[kc] = *(const bf16x8*)&hS[RB][l15 * 136 + 32 * kc + 8 * quad];        \
        f32x4 acc[4];                                                                \
        _Pragma("unroll")                                                            \
        for (int typ = 0; typ < 4; typ++) acc[typ] = bias4[typ];                     \
        _Pragma("unroll")                                                            \
        for (int kc = 0; kc < 4; kc++)                                               \
            _Pragma("unroll")                                                        \
            for (int typ = 0; typ < 4; typ++)                                        \
                acc[typ] = __builtin_amdgcn_mfma_f32_16x16x32_bf16(afrag[typ][kc], bh[kc], acc[typ], 0, 0, 0); \
        if (w == 0) {                                                                \
            f32x4 accP;                                                              \
            accP.x = ob_r; accP.y = ob_r; accP.z = ob_r; accP.w = ob_r;              \
            _Pragma("unroll")                                                        \
            for (int kc = 0; kc < 4; kc++)                                           \
                accP = __builtin_amdgcn_mfma_f32_16x16x32_bf16(pfrag[kc], bh[kc], accP, 0, 0, 0); \
            if ((T) > 0 && quad == 0)                                                \
                store_out(out, (long)bown * 4064 + (long)((T) - 1) * NV + n, accP[0], obf); \
        }                                                                            \
        ushort4 hw;                                                                  \
        _Pragma("unroll")                                                            \
        for (int r = 0; r < 4; r++) {                                                \
            float ii = sigmoid_f(acc[0][r]);                                         \
            float ff = sigmoid_f(acc[1][r]);                                         \
            float g2 = tanh_f(acc[2][r]);                                            \
            float oo = sigmoid_f(acc[3][r]);                                         \
            float cc = ff * cst[r] + ii * g2;                                        \
            cst[r] = cc;                                                             \
            ((ushort_t*)&hw)[r] = f2bf(oo * tanh_f(cc));                             \
        }                                                                            \
        *(ushort4*)&hS[(RB) ^ 1][l15 * 136 + 16 * w + 4 * quad] = hw;                \
    } while (0)

    for (int tp = 0; tp < 64; tp++) {
        DEC_STEP(2 * tp, 0);
        DEC_STEP(2 * tp + 1, 1);
    }
#undef DEC_STEP

    // o_127 from h_127 (t=127 wrote hS[0])
    __syncthreads();
    if (w == 0) {
        f32x4 accP;
        accP.x = ob_r; accP.y = ob_r; accP.z = ob_r; accP.w = ob_r;
        #pragma unroll
        for (int kc = 0; kc < 4; kc++) {
            bf16x8 bh = *(const bf16x8*)&hS[0][l15 * 136 + 32 * kc + 8 * quad];
            accP = __builtin_amdgcn_mfma_f32_16x16x32_bf16(pfrag[kc], bh, accP, 0, 0, 0);
        }
        if (quad == 0)
            store_out(out, 520192 + (long)bown * NV + n, accP[0], obf);
    }
}

extern "C" void kernel_launch(void* const* d_in, const int* in_sizes, int n_in,
                              void* d_out, int out_size, void* d_ws, size_t ws_size,
                              hipStream_t stream) {
    char* ws = (char*)d_ws;
    float*    P    = (float*)(ws + 0);              // 592 KB
    float*    Xc   = (float*)(ws + (1u << 20));     // 2 MB
    float*    C    = (float*)(ws + (3u << 20));     // 2 MB
    float*    qb   = (float*)(ws + (5u << 20));
    float*    kb   = (float*)(ws + (7u << 20));
    float*    vb   = (float*)(ws + (9u << 20));
    float*    Cst  = (float*)(ws + (11u << 20));
    int*      flags = (int*)(ws + (13u << 20));

    Ptr19 a;
    for (int i = 0; i < 19; i++) { a.p[i] = d_in[i]; a.e[i] = in_sizes[i]; }
    probe_kernel<<<19, 64, 0, stream>>>(a, flags);
    conv_all<<<(P_TOTAL + 255) / 256, 256, 0, stream>>>(a, flags, P);
    transpose_X<<<dim3(4, 64), 256, 0, stream>>>(d_in[0], flags, Xc);

    enc_kernel<<<dim3(8, 32), 512, 0, stream>>>(Xc, d_in[2], flags, P, C);
    qkv_kernel<<<dim3(128, 3), 256, 0, stream>>>(C, P, qb, kb, vb);
    attn_kernel<<<dim3(128), 256, 0, stream>>>(qb, kb, vb, C, P, flags, Cst, d_out);
    dec_kernel<<<dim3(8, 32), 512, 0, stream>>>(Cst, d_in[10], d_in[12], d_in[14], flags, P, d_out);
}